// Round 16
// baseline (1180.166 us; speedup 1.0000x reference)
//
#include <hip/hip_runtime.h>

#define Tt 4096
#define Bb 2
#define Ss 2048
#define Dd 1024
#define Hh 16
#define KVHn 4
#define HDn 64
#define En 8
#define Fn 4096

#define BM 128
#define BN 128

typedef unsigned short u16;
typedef __attribute__((ext_vector_type(4))) float f32x4;
typedef __attribute__((ext_vector_type(8))) short bfrag;
typedef __attribute__((ext_vector_type(4))) short s16x4;

#define WAITV(N) asm volatile("s_waitcnt vmcnt(" #N ")" ::: "memory")
#define BARRIER() asm volatile("s_barrier" ::: "memory")

__device__ __forceinline__ u16 f2bf(float f) {
    unsigned u = __builtin_bit_cast(unsigned, f);
    u = (u + 0x7fffu + ((u >> 16) & 1u)) >> 16;
    return (u16)u;
}
__device__ __forceinline__ float bf2f(u16 b) {
    unsigned u = ((unsigned)b) << 16;
    return __builtin_bit_cast(float, u);
}
__device__ __forceinline__ void split8a(const float* va, bfrag* ph, bfrag* pl) {
    bfrag th, tl;
#pragma unroll
    for (int j = 0; j < 8; j++) {
        u16 hu = f2bf(va[j]);
        th[j] = (short)hu;
        tl[j] = (short)f2bf(va[j] - bf2f(hu));
    }
    *ph = th; *pl = tl;
}
// async global->LDS, 16B per lane; LDS dest = wave-uniform base + lane*16, global src per-lane
__device__ __forceinline__ void glds16(const void* g, void* l) {
    __builtin_amdgcn_global_load_lds(
        (const __attribute__((address_space(1))) unsigned int*)g,
        (__attribute__((address_space(3))) unsigned int*)l, 16, 0, 0);
}

// ---------- transpose + bf16 convert (hi/lo split) for QKV/WO weights: [K][N] -> [N][K] ----------
template<bool SPL>
__global__ __launch_bounds__(256)
void tconv_k(const float* __restrict__ src, u16* __restrict__ dhi, u16* __restrict__ dlo,
             const int K, const int N, const int rowOff, const int nTilesN)
{
    const int tid = threadIdx.x;
    const int ty = blockIdx.x / nTilesN, tx = blockIdx.x % nTilesN;
    const int k0 = ty * 64, n0 = tx * 64;
    __shared__ float tl[64][65];
#pragma unroll
    for (int it = 0; it < 16; it++) {
        int idx = tid + it * 256;
        int kk = idx >> 6, nn = idx & 63;
        tl[kk][nn] = src[(size_t)(k0 + kk) * N + n0 + nn];
    }
    __syncthreads();
#pragma unroll
    for (int it = 0; it < 8; it++) {
        int idx = tid + it * 256;
        int n = idx >> 5, k2 = (idx & 31) * 2;
        float v0 = tl[k2][n], v1 = tl[k2 + 1][n];
        u16 h0 = f2bf(v0), h1v = f2bf(v1);
        size_t o = (size_t)(rowOff + n0 + n) * K + k0 + k2;
        *(unsigned*)&dhi[o] = (unsigned)h0 | ((unsigned)h1v << 16);
        if (SPL) {
            u16 l0 = f2bf(v0 - bf2f(h0)), l1 = f2bf(v1 - bf2f(h1v));
            *(unsigned*)&dlo[o] = (unsigned)l0 | ((unsigned)l1 << 16);
        }
    }
}

// ---------- MoE weight prep: f32 [K][N] -> tiled bf16 blocks [nt][kt][128n x TBK k] ----------
template<int TBK, bool SWZ>
__global__ __launch_bounds__(256)
void tprep_k(const float* __restrict__ src, u16* __restrict__ dst,
             const int K, const int N, const int nTilesN)
{
    const int tid = threadIdx.x;
    const int e = blockIdx.y;
    const int ntl = blockIdx.x % nTilesN, kt = blockIdx.x / nTilesN;
    const int nTK = K / TBK;
    src += (size_t)e * K * N + (size_t)(kt * TBK) * N + ntl * 128;
    u16* dblk = dst + (((size_t)e * nTilesN + ntl) * nTK + kt) * (size_t)(128 * TBK);
    __shared__ float tl[TBK][132];
#pragma unroll
    for (int it = 0; it < TBK / 8; it++) {
        int i4 = tid + it * 256;
        int kk = i4 >> 5, n = (i4 & 31) * 4;
        f32x4 v = *(const f32x4*)(src + (size_t)kk * N + n);
        tl[kk][n] = v.x; tl[kk][n + 1] = v.y; tl[kk][n + 2] = v.z; tl[kk][n + 3] = v.w;
    }
    __syncthreads();
#pragma unroll
    for (int it = 0; it < TBK / 16; it++) {
        int idx = tid + it * 256;
        int n = (TBK == 32) ? (idx >> 2) : (idx >> 3);
        int c = (TBK == 32) ? (idx & 3) : (idx & 7);
        bfrag v;
#pragma unroll
        for (int j = 0; j < 8; j++) v[j] = (short)f2bf(tl[c * 8 + j][n]);
        int boff = n * (TBK * 2) + ((c * 16) ^ (SWZ ? ((n & 7) << 4) : 0));
        *(bfrag*)((char*)dblk + boff) = v;
    }
}

// ---------- RMSNorm -> split bf16 (hi/lo) ----------
__global__ __launch_bounds__(256)
void rmsnorm_split_k(const float* __restrict__ x, const float* __restrict__ w,
                     u16* __restrict__ ohi, u16* __restrict__ olo)
{
    const int row = blockIdx.x;
    const int tid = threadIdx.x;
    const int lane = tid & 63, wid = tid >> 6;
    f32x4 t4 = *(const f32x4*)(x + (size_t)row * Dd + tid * 4);
    float s = t4.x*t4.x + t4.y*t4.y + t4.z*t4.z + t4.w*t4.w;
#pragma unroll
    for (int o = 1; o < 64; o <<= 1) s += __shfl_xor(s, o, 64);
    __shared__ float red[4];
    if (lane == 0) red[wid] = s;
    __syncthreads();
    float inv = rsqrtf((red[0] + red[1] + red[2] + red[3]) * (1.0f / Dd) + 1e-6f);
    f32x4 w4 = *(const f32x4*)(w + tid * 4);
    float va[4] = { t4.x*inv*w4.x, t4.y*inv*w4.y, t4.z*inv*w4.z, t4.w*inv*w4.w };
    s16x4 hi, lo;
#pragma unroll
    for (int j = 0; j < 4; j++) {
        u16 hu = f2bf(va[j]);
        hi[j] = (short)hu;
        lo[j] = (short)f2bf(va[j] - bf2f(hu));
    }
    *(s16x4*)&ohi[(size_t)row * Dd + tid * 4] = hi;
    *(s16x4*)&olo[(size_t)row * Dd + tid * 4] = lo;
}

// ---------- RMSNorm -> f32 (router) + rounded bf16 (MoE A) ----------
__global__ __launch_bounds__(256)
void rmsnorm2_k(const float* __restrict__ x, const float* __restrict__ w,
                float* __restrict__ of, u16* __restrict__ ob)
{
    const int row = blockIdx.x;
    const int tid = threadIdx.x;
    const int lane = tid & 63, wid = tid >> 6;
    f32x4 t4 = *(const f32x4*)(x + (size_t)row * Dd + tid * 4);
    float s = t4.x*t4.x + t4.y*t4.y + t4.z*t4.z + t4.w*t4.w;
#pragma unroll
    for (int o = 1; o < 64; o <<= 1) s += __shfl_xor(s, o, 64);
    __shared__ float red[4];
    if (lane == 0) red[wid] = s;
    __syncthreads();
    float inv = rsqrtf((red[0] + red[1] + red[2] + red[3]) * (1.0f / Dd) + 1e-6f);
    f32x4 w4 = *(const f32x4*)(w + tid * 4);
    f32x4 o4;
    o4.x = t4.x*inv*w4.x; o4.y = t4.y*inv*w4.y; o4.z = t4.z*inv*w4.z; o4.w = t4.w*inv*w4.w;
    *(f32x4*)&of[(size_t)row * Dd + tid * 4] = o4;
    s16x4 hb;
    hb[0] = (short)f2bf(o4.x); hb[1] = (short)f2bf(o4.y);
    hb[2] = (short)f2bf(o4.z); hb[3] = (short)f2bf(o4.w);
    *(s16x4*)&ob[(size_t)row * Dd + tid * 4] = hb;
}

// ---------- RoPE tables (f64) ----------
__global__ __launch_bounds__(256)
void rope_tab_k(float* __restrict__ ct, float* __restrict__ st)
{
    int idx = blockIdx.x * 256 + threadIdx.x;
    if (idx < Ss * 32) {
        int s = idx >> 5, i = idx & 31;
        double inv = pow(10000.0, -((double)(2 * i)) / 64.0);
        double a = (double)s * inv;
        double sn, cs;
        sincos(a, &sn, &cs);
        ct[idx] = (float)cs;
        st[idx] = (float)sn;
    }
}

// ---------- RoPE on Q (in-place, qkv stride 1536) ----------
__global__ __launch_bounds__(256)
void rope_q_k(float* __restrict__ qkv, const float* __restrict__ ct, const float* __restrict__ st)
{
    int idx = blockIdx.x * 256 + threadIdx.x;
    int i = idx & 31, hh = (idx >> 5) & (Hh - 1), t = idx >> 9;
    int s = t & (Ss - 1);
    float cs = ct[s * 32 + i], sn = st[s * 32 + i];
    float* base = qkv + (size_t)t * 1536 + hh * 64 + i;
    float x1 = base[0], x2 = base[32];
    base[0]  = x1 * cs - x2 * sn;
    base[32] = x2 * cs + x1 * sn;
}

// ---------- K: RoPE + split bf16 ----------
__global__ __launch_bounds__(256)
void kprep_k(const float* __restrict__ qkv, const float* __restrict__ ct,
             const float* __restrict__ st, u16* __restrict__ khi, u16* __restrict__ klo)
{
    int idx = blockIdx.x * 256 + threadIdx.x;
    int i = idx & 31, hh = (idx >> 5) & (KVHn - 1), t = idx >> 7;
    int s = t & (Ss - 1);
    float cs = ct[s * 32 + i], sn = st[s * 32 + i];
    const float* base = qkv + (size_t)t * 1536 + 1024 + hh * 64 + i;
    float x1 = base[0], x2 = base[32];
    float r1 = x1 * cs - x2 * sn, r2 = x2 * cs + x1 * sn;
    size_t o = (size_t)t * (KVHn * HDn) + hh * 64 + i;
    u16 h1v = f2bf(r1), h2v = f2bf(r2);
    khi[o] = h1v;       khi[o + 32] = h2v;
    klo[o] = f2bf(r1 - bf2f(h1v));
    klo[o + 32] = f2bf(r2 - bf2f(h2v));
}

// ---------- V: transpose + split ----------
__global__ __launch_bounds__(256)
void vprep_k(const float* __restrict__ qkv, u16* __restrict__ vthi, u16* __restrict__ vtlo)
{
    const int st0 = blockIdx.x * 64;
    const int g = blockIdx.y;
    const int b = g >> 2, kvh = g & 3;
    const int tid = threadIdx.x;
    __shared__ float tl[64][65];
#pragma unroll
    for (int it = 0; it < 16; it++) {
        int idx = tid + it * 256;
        int sl = idx >> 6, d = idx & 63;
        tl[sl][d] = qkv[(size_t)(b * Ss + st0 + sl) * 1536 + 1280 + kvh * 64 + d];
    }
    __syncthreads();
#pragma unroll
    for (int it = 0; it < 8; it++) {
        int idx = tid + it * 256;
        int d = idx >> 5, s2 = (idx & 31) * 2;
        float v0 = tl[s2][d], v1 = tl[s2 + 1][d];
        u16 h0 = f2bf(v0), h1v = f2bf(v1);
        size_t o = ((size_t)g * 64 + d) * Ss + st0 + s2;
        *(unsigned*)&vthi[o] = (unsigned)h0 | ((unsigned)h1v << 16);
        u16 l0 = f2bf(v0 - bf2f(h0)), l1 = f2bf(v1 - bf2f(h1v));
        *(unsigned*)&vtlo[o] = (unsigned)l0 | ((unsigned)l1 << 16);
    }
}

// ---------- split-bf16x3 GEMM (glds + dbuf + counted vmcnt): C = A@B^T(+resid) ----------
template<bool RESID>
__global__ __launch_bounds__(256)
void gemm_split_k(const u16* __restrict__ Ahi_g, const u16* __restrict__ Alo_g,
                  const u16* __restrict__ Bhi_g, const u16* __restrict__ Blo_g,
                  float* __restrict__ C, const float* __restrict__ resid,
                  const int M, const int N, const int K, const int ntiles)
{
    const int bid = blockIdx.x;
    const int nt = bid % ntiles, mt = bid / ntiles;
    __shared__ __align__(16) u16 Ah[2][128 * 32], Al[2][128 * 32];
    __shared__ __align__(16) u16 Bh[2][128 * 32], Bl[2][128 * 32];   // 64 KB
    const int tid = threadIdx.x, lane = tid & 63, wid = tid >> 6;
    const int wrow = (wid >> 1) * 64, wcol = (wid & 1) * 64;
    const int l15 = lane & 15, lhi = lane >> 4;
    const int row0 = mt * BM, col0 = nt * BN;

    const u16 *ah_s[2], *al_s[2], *bh_s[2], *bl_s[2];
#pragma unroll
    for (int j = 0; j < 2; j++) {
        int r = (wid * 2 + j) * 16 + (lane >> 2);
        size_t ca = (size_t)(row0 + r) * K + (lane & 3) * 8;
        size_t cb = (size_t)(col0 + r) * K + (lane & 3) * 8;
        ah_s[j] = Ahi_g + ca; al_s[j] = Alo_g + ca;
        bh_s[j] = Bhi_g + cb; bl_s[j] = Blo_g + cb;
    }
    f32x4 acc[4][4];
#pragma unroll
    for (int i = 0; i < 4; i++)
#pragma unroll
        for (int j = 0; j < 4; j++) { acc[i][j].x = 0.f; acc[i][j].y = 0.f; acc[i][j].z = 0.f; acc[i][j].w = 0.f; }

    auto stage = [&](int buf, int k0) {
#pragma unroll
        for (int j = 0; j < 2; j++) {
            int d = (wid * 2 + j) * 512;
            glds16(ah_s[j] + k0, &Ah[buf][d]);
            glds16(al_s[j] + k0, &Al[buf][d]);
            glds16(bh_s[j] + k0, &Bh[buf][d]);
            glds16(bl_s[j] + k0, &Bl[buf][d]);
        }
    };
    auto compute = [&](int cur) {
        bfrag ah[4], al[4], bh[4], bl[4];
#pragma unroll
        for (int mi = 0; mi < 4; mi++) {
            int rb = (wrow + mi * 16 + l15) * 32 + lhi * 8;
            ah[mi] = *(const bfrag*)&Ah[cur][rb];
            al[mi] = *(const bfrag*)&Al[cur][rb];
        }
#pragma unroll
        for (int ni = 0; ni < 4; ni++) {
            int rb = (wcol + ni * 16 + l15) * 32 + lhi * 8;
            bh[ni] = *(const bfrag*)&Bh[cur][rb];
            bl[ni] = *(const bfrag*)&Bl[cur][rb];
        }
#pragma unroll
        for (int mi = 0; mi < 4; mi++)
#pragma unroll
            for (int ni = 0; ni < 4; ni++) {
                acc[mi][ni] = __builtin_amdgcn_mfma_f32_16x16x32_bf16(ah[mi], bh[ni], acc[mi][ni], 0, 0, 0);
                acc[mi][ni] = __builtin_amdgcn_mfma_f32_16x16x32_bf16(ah[mi], bl[ni], acc[mi][ni], 0, 0, 0);
                acc[mi][ni] = __builtin_amdgcn_mfma_f32_16x16x32_bf16(al[mi], bh[ni], acc[mi][ni], 0, 0, 0);
            }
    };
    const int nkt = K / 32;
    stage(0, 0);
    stage(1, 32);
    int cur = 0;
    for (int kt = 0; kt < nkt - 1; kt++) {
        WAITV(8);       // own tile-kt loads done; kt+1 still in flight
        BARRIER();
        compute(cur);
        BARRIER();
        if (kt + 2 < nkt) stage(cur, (kt + 2) * 32);
        cur ^= 1;
    }
    WAITV(0);
    BARRIER();
    compute(cur);
#pragma unroll
    for (int mi = 0; mi < 4; mi++) {
#pragma unroll
        for (int t = 0; t < 4; t++) {
            int pr = row0 + wrow + mi * 16 + lhi * 4 + t;
#pragma unroll
            for (int ni = 0; ni < 4; ni++) {
                int gc = col0 + wcol + ni * 16 + l15;
                float vv = acc[mi][ni][t];
                if (RESID) vv += resid[(size_t)pr * N + gc];
                C[(size_t)pr * N + gc] = vv;
            }
        }
    }
}

// ---------- MoE expert GEMM (single output): glds + dbuf + counted vmcnt, BK=32 ----------
// MODE 0 (gate): act[ix] = bf16(acc)
// MODE 1 (up):   g = act[ix]; act[ix] = bf16(silu(g) * acc * gw)   [in-place, same thread owns ix]
template<int MODE>
__global__ __launch_bounds__(256, 4)
void gemm_expert_k(const u16* __restrict__ A_g, const u16* __restrict__ Bt,
                   u16* __restrict__ act,
                   const int* __restrict__ toklist, const float* __restrict__ gwlist,
                   const int* __restrict__ counts, const int* __restrict__ offsets)
{
    const int e = blockIdx.y;
    const int Meff = counts[e];
    const int nt = blockIdx.x & 31, mt = blockIdx.x >> 5;
    if (mt * BM >= Meff) return;
    const int* tok = toklist + e * Tt;
    const float* gw = gwlist + e * Tt;
    const int rowoff = offsets[e];
    __shared__ __align__(16) u16 As[2][128 * 32], Bs[2][128 * 32];   // 32 KB
    const int tid = threadIdx.x, lane = tid & 63, wid = tid >> 6;
    const int wrow = (wid >> 1) * 64, wcol = (wid & 1) * 64;
    const int l15 = lane & 15, lhi = lane >> 4;
    const int row0 = mt * BM, col0 = nt * BN;

    const u16* asrc[2];
#pragma unroll
    for (int j = 0; j < 2; j++) {
        int row = (wid * 2 + j) * 16 + (lane >> 2);
        int pr = row0 + row;
        int tr = (pr < Meff) ? tok[pr] : tok[0];
        asrc[j] = A_g + (size_t)tr * Dd + (lane & 3) * 8;
    }
    const size_t bblk = (size_t)(e * 32 + nt) * (32 * 4096);
    const u16* bsrc = Bt + bblk + (size_t)(wid * 2) * 512 + lane * 8;

    f32x4 acc[4][4];
#pragma unroll
    for (int i = 0; i < 4; i++)
#pragma unroll
        for (int j = 0; j < 4; j++) { acc[i][j].x = 0.f; acc[i][j].y = 0.f; acc[i][j].z = 0.f; acc[i][j].w = 0.f; }

    auto stage = [&](int buf, int kt) {
#pragma unroll
        for (int j = 0; j < 2; j++) {
            int d = (wid * 2 + j) * 512;
            glds16(asrc[j] + kt * 32,                  &As[buf][d]);
            glds16(bsrc + j * 512 + (size_t)kt * 4096, &Bs[buf][d]);
        }
    };
    auto compute = [&](int cur) {
        bfrag a[4];
#pragma unroll
        for (int mi = 0; mi < 4; mi++)
            a[mi] = *(const bfrag*)&As[cur][(wrow + mi * 16 + l15) * 32 + lhi * 8];
#pragma unroll
        for (int ni = 0; ni < 4; ni++) {
            bfrag b = *(const bfrag*)&Bs[cur][(wcol + ni * 16 + l15) * 32 + lhi * 8];
#pragma unroll
            for (int mi = 0; mi < 4; mi++)
                acc[mi][ni] = __builtin_amdgcn_mfma_f32_16x16x32_bf16(a[mi], b, acc[mi][ni], 0, 0, 0);
        }
    };
    stage(0, 0);
    stage(1, 1);
    int cur = 0;
    for (int kt = 0; kt < 31; kt++) {
        WAITV(4);
        BARRIER();
        compute(cur);
        BARRIER();
        if (kt + 2 < 32) stage(cur, kt + 2);
        cur ^= 1;
    }
    WAITV(0);
    BARRIER();
    compute(cur);
#pragma unroll
    for (int mi = 0; mi < 4; mi++) {
#pragma unroll
        for (int t = 0; t < 4; t++) {
            int pr = row0 + wrow + mi * 16 + lhi * 4 + t;
            if (pr < Meff) {
                float gwv = (MODE == 1) ? gw[pr] : 0.f;
#pragma unroll
                for (int ni = 0; ni < 4; ni++) {
                    int gc = col0 + wcol + ni * 16 + l15;
                    size_t ix = (size_t)(rowoff + pr) * Fn + gc;
                    if (MODE == 0) {
                        act[ix] = f2bf(acc[mi][ni][t]);
                    } else {
                        float g = bf2f(act[ix]);
                        float sg = g / (1.0f + expf(-g));
                        act[ix] = f2bf(sg * acc[mi][ni][t] * gwv);
                    }
                }
            }
        }
    }
}

// ---------- MoE down (glds + dbuf + counted vmcnt, BK=32): out[tok] += act @ Wd^T ----------
__global__ __launch_bounds__(256, 4)
void gemm_down_k(const u16* __restrict__ act, const u16* __restrict__ Bt,
                 float* __restrict__ C, const int* __restrict__ toklist,
                 const int* __restrict__ counts, const int* __restrict__ offsets)
{
    const int e = blockIdx.y;
    const int Meff = counts[e];
    const int nt = blockIdx.x & 7, mt = blockIdx.x >> 3;
    if (mt * BM >= Meff) return;
    const int* tok = toklist + e * Tt;
    const int rowoff = offsets[e];
    __shared__ __align__(16) u16 As[2][128 * 32], Bs[2][128 * 32];   // 32 KB
    const int tid = threadIdx.x, lane = tid & 63, wid = tid >> 6;
    const int wrow = (wid >> 1) * 64, wcol = (wid & 1) * 64;
    const int l15 = lane & 15, lhi = lane >> 4;
    const int row0 = mt * BM;

    const u16* asrc[2];
#pragma unroll
    for (int j = 0; j < 2; j++) {
        int row = (wid * 2 + j) * 16 + (lane >> 2);
        int pr = row0 + row;
        int rr = (pr < Meff) ? pr : 0;
        asrc[j] = act + (size_t)(rowoff + rr) * Fn + (lane & 3) * 8;
    }
    const size_t bblk = (size_t)(e * 8 + nt) * ((size_t)128 * 4096);
    const u16* bsrc = Bt + bblk + (size_t)(wid * 2) * 512 + lane * 8;

    f32x4 acc[4][4];
#pragma unroll
    for (int i = 0; i < 4; i++)
#pragma unroll
        for (int j = 0; j < 4; j++) { acc[i][j].x = 0.f; acc[i][j].y = 0.f; acc[i][j].z = 0.f; acc[i][j].w = 0.f; }

    auto stage = [&](int buf, int kt) {
#pragma unroll
        for (int j = 0; j < 2; j++) {
            int d = (wid * 2 + j) * 512;
            glds16(asrc[j] + kt * 32,                  &As[buf][d]);
            glds16(bsrc + j * 512 + (size_t)kt * 4096, &Bs[buf][d]);
        }
    };
    auto compute = [&](int cur) {
        bfrag a[4];
#pragma unroll
        for (int mi = 0; mi < 4; mi++)
            a[mi] = *(const bfrag*)&As[cur][(wrow + mi * 16 + l15) * 32 + lhi * 8];
#pragma unroll
        for (int ni = 0; ni < 4; ni++) {
            bfrag b = *(const bfrag*)&Bs[cur][(wcol + ni * 16 + l15) * 32 + lhi * 8];
#pragma unroll
            for (int mi = 0; mi < 4; mi++)
                acc[mi][ni] = __builtin_amdgcn_mfma_f32_16x16x32_bf16(a[mi], b, acc[mi][ni], 0, 0, 0);
        }
    };
    stage(0, 0);
    stage(1, 1);
    int cur = 0;
    const int nkt = Fn / 32;   // 128
    for (int kt = 0; kt < nkt - 1; kt++) {
        WAITV(4);
        BARRIER();
        compute(cur);
        BARRIER();
        if (kt + 2 < nkt) stage(cur, kt + 2);
        cur ^= 1;
    }
    WAITV(0);
    BARRIER();
    compute(cur);
#pragma unroll
    for (int mi = 0; mi < 4; mi++) {
#pragma unroll
        for (int t = 0; t < 4; t++) {
            int pr = row0 + wrow + mi * 16 + lhi * 4 + t;
            if (pr < Meff) {
                int trow = tok[pr];
#pragma unroll
                for (int ni = 0; ni < 4; ni++) {
                    int gc = nt * BN + wcol + ni * 16 + l15;
                    atomicAdd(&C[(size_t)trow * Dd + gc], acc[mi][ni][t]);
                }
            }
        }
    }
}

// ---------- Flash attention (causal GQA), split-bf16x3, swapped ops, K/V direct from L2 ----------
// K/V (8 MB total) are L2-resident; no LDS staging, no barriers — only per-wave P round-trip.
__global__ __launch_bounds__(256)
void attn_k(const float* __restrict__ qkv, const u16* __restrict__ khi,
            const u16* __restrict__ klo, const u16* __restrict__ vthi,
            const u16* __restrict__ vtlo, u16* __restrict__ chi, u16* __restrict__ clo)
{
    const int qt = (int)gridDim.x - 1 - (int)blockIdx.x;
    const int h = blockIdx.y, b = blockIdx.z;
    const int kvh = h >> 2;
    const int g = b * KVHn + kvh;
    const int tid = threadIdx.x;
    const int lane = tid & 63, wid = tid >> 6;
    const int l15 = lane & 15, lhi = lane >> 4;

    __shared__ __align__(16) u16 Phi[4 * 16 * 72];
    __shared__ __align__(16) u16 Plo[4 * 16 * 72];

    bfrag qh[2], ql[2];
    {
        const int qrow = qt * 64 + wid * 16 + l15;
        const float* qb = qkv + (size_t)(b * Ss + qrow) * 1536 + h * 64;
#pragma unroll
        for (int ks = 0; ks < 2; ks++) {
            const float* p = qb + ks * 32 + lhi * 8;
            f32x4 u0 = *(const f32x4*)p;
            f32x4 u1 = *(const f32x4*)(p + 4);
            float va[8] = { u0.x * 0.125f, u0.y * 0.125f, u0.z * 0.125f, u0.w * 0.125f,
                            u1.x * 0.125f, u1.y * 0.125f, u1.z * 0.125f, u1.w * 0.125f };
            split8a(va, &qh[ks], &ql[ks]);
        }
    }
    // per-lane global bases: K row = kv = ni*16+l15, col slice = ks*32+lhi*8
    //                        V row = d  = ni*16+l15, col slice = kt*64 + ks*32+lhi*8
    const u16* kbase = khi;  // indexed per-use
    f32x4 O[4];   // O^T: O[ni][t] = O^T[d = ni*16+lhi*4+t][q = l15]
#pragma unroll
    for (int ni = 0; ni < 4; ni++) { O[ni].x = 0.f; O[ni].y = 0.f; O[ni].z = 0.f; O[ni].w = 0.f; }
    float m_s = -1e30f;
    float l_s = 0.f;
    (void)kbase;

    for (int kt = 0; kt <= qt; kt++) {
        // ---- S^T = K Q^T (3-pass split), K fragments direct from global (L2-hot) ----
        f32x4 sf[4];
#pragma unroll
        for (int ni = 0; ni < 4; ni++) { sf[ni].x = 0.f; sf[ni].y = 0.f; sf[ni].z = 0.f; sf[ni].w = 0.f; }
        __builtin_amdgcn_s_setprio(1);
#pragma unroll
        for (int ks = 0; ks < 2; ks++) {
#pragma unroll
            for (int ni = 0; ni < 4; ni++) {
                int kv = ni * 16 + l15;
                size_t ka = (size_t)(b * Ss + kt * 64 + kv) * (KVHn * HDn) + kvh * 64 + ks * 32 + lhi * 8;
                bfrag kfh = *(const bfrag*)&khi[ka];
                bfrag kfl = *(const bfrag*)&klo[ka];
                sf[ni] = __builtin_amdgcn_mfma_f32_16x16x32_bf16(kfh, qh[ks], sf[ni], 0, 0, 0);
                sf[ni] = __builtin_amdgcn_mfma_f32_16x16x32_bf16(kfl, qh[ks], sf[ni], 0, 0, 0);
                sf[ni] = __builtin_amdgcn_mfma_f32_16x16x32_bf16(kfh, ql[ks], sf[ni], 0, 0, 0);
            }
        }
        __builtin_amdgcn_s_setprio(0);
        // ---- causal mask (kv = ni*16+lhi*4+t, q = wid*16+l15) ----
        if (kt == qt) {
#pragma unroll
            for (int ni = 0; ni < 4; ni++)
#pragma unroll
                for (int t = 0; t < 4; t++)
                    if (ni * 16 + lhi * 4 + t > wid * 16 + l15) sf[ni][t] = -1e30f;
        }
        // ---- lane-local softmax ----
        float mx = -1e30f;
#pragma unroll
        for (int ni = 0; ni < 4; ni++)
#pragma unroll
            for (int t = 0; t < 4; t++) mx = fmaxf(mx, sf[ni][t]);
        mx = fmaxf(mx, __shfl_xor(mx, 16, 64));
        mx = fmaxf(mx, __shfl_xor(mx, 32, 64));
        float mn = fmaxf(m_s, mx);
        float sc = expf(m_s - mn);
        m_s = mn;
        float rs = 0.f;
#pragma unroll
        for (int ni = 0; ni < 4; ni++)
#pragma unroll
            for (int t = 0; t < 4; t++) {
                float p = expf(sf[ni][t] - mn);
                sf[ni][t] = p;
                rs += p;
            }
        rs += __shfl_xor(rs, 16, 64);
        rs += __shfl_xor(rs, 32, 64);
        l_s = l_s * sc + rs;
        // ---- O^T rescale (lane-local) ----
#pragma unroll
        for (int ni = 0; ni < 4; ni++)
#pragma unroll
            for (int t = 0; t < 4; t++) O[ni][t] *= sc;
        // ---- P write (same-wave region; in-order DS queue handles WAR across iterations) ----
#pragma unroll
        for (int ni = 0; ni < 4; ni++)
#pragma unroll
            for (int t = 0; t < 4; t++) {
                float p = sf[ni][t];
                u16 hu = f2bf(p);
                int ix = (wid * 16 + l15) * 72 + ni * 16 + lhi * 4 + t;
                Phi[ix] = hu;
                Plo[ix] = f2bf(p - bf2f(hu));
            }
        asm volatile("s_waitcnt lgkmcnt(0)" ::: "memory");
        __builtin_amdgcn_sched_barrier(0);
        // ---- O^T += V^T P^T, V fragments direct from global (L2-hot) ----
        __builtin_amdgcn_s_setprio(1);
#pragma unroll
        for (int ks = 0; ks < 2; ks++) {
            int pb = (wid * 16 + l15) * 72 + ks * 32 + lhi * 8;
            bfrag pfh = *(const bfrag*)&Phi[pb];
            bfrag pfl = *(const bfrag*)&Plo[pb];
#pragma unroll
            for (int ni = 0; ni < 4; ni++) {
                int d = ni * 16 + l15;
                size_t va = ((size_t)g * 64 + d) * Ss + kt * 64 + ks * 32 + lhi * 8;
                bfrag vfh = *(const bfrag*)&vthi[va];
                bfrag vfl = *(const bfrag*)&vtlo[va];
                O[ni] = __builtin_amdgcn_mfma_f32_16x16x32_bf16(vfh, pfh, O[ni], 0, 0, 0);
                O[ni] = __builtin_amdgcn_mfma_f32_16x16x32_bf16(vfl, pfh, O[ni], 0, 0, 0);
                O[ni] = __builtin_amdgcn_mfma_f32_16x16x32_bf16(vfh, pfl, O[ni], 0, 0, 0);
            }
        }
        __builtin_amdgcn_s_setprio(0);
        // no __syncthreads: waves fully independent
    }
    // ---- epilogue: denom lane-local; write O^T[d][q] -> ctx[q][d] ----
    {
        float inv = 1.0f / l_s;
        int qrow = qt * 64 + wid * 16 + l15;
        size_t base = (size_t)(b * Ss + qrow) * Dd + h * 64;
#pragma unroll
        for (int ni = 0; ni < 4; ni++)
#pragma unroll
            for (int t = 0; t < 4; t++) {
                float val = O[ni][t] * inv;
                u16 hv = f2bf(val);
                int d = ni * 16 + lhi * 4 + t;
                chi[base + d] = hv;
                clo[base + d] = f2bf(val - bf2f(hv));
            }
    }
}

// ---------- Router ----------
__global__ __launch_bounds__(256)
void router_k(const float* __restrict__ h2, const float* __restrict__ rw,
              float* __restrict__ probs, int* __restrict__ counts,
              int* __restrict__ toklist, float* __restrict__ gwlist)
{
    const int t = blockIdx.x;
    const int tid = threadIdx.x;
    const int lane = tid & 63, wid = tid >> 6;
    f32x4 x4 = *(const f32x4*)(h2 + (size_t)t * Dd + tid * 4);
    float part[En];
#pragma unroll
    for (int e = 0; e < En; e++) {
        f32x4 w4 = *(const f32x4*)(rw + (size_t)e * Dd + tid * 4);
        part[e] = x4.x * w4.x + x4.y * w4.y + x4.z * w4.z + x4.w * w4.w;
    }
#pragma unroll
    for (int e = 0; e < En; e++)
#pragma unroll
        for (int o = 1; o < 64; o <<= 1) part[e] += __shfl_xor(part[e], o, 64);
    __shared__ float red[4][En];
    if (lane == 0) {
#pragma unroll
        for (int e = 0; e < En; e++) red[wid][e] = part[e];
    }
    __syncthreads();
    if (tid == 0) {
        float lg[En];
        float mx = -1e30f;
#pragma unroll
        for (int e = 0; e < En; e++) {
            lg[e] = red[0][e] + red[1][e] + red[2][e] + red[3][e];
            mx = fmaxf(mx, lg[e]);
        }
        float pe[En], ssum = 0.f;
#pragma unroll
        for (int e = 0; e < En; e++) { pe[e] = expf(lg[e] - mx); ssum += pe[e]; }
        float inv = 1.0f / ssum;
#pragma unroll
        for (int e = 0; e < En; e++) { pe[e] *= inv; probs[(size_t)t * En + e] = pe[e]; }
        int i0 = 0;
#pragma unroll
        for (int e = 1; e < En; e++) if (pe[e] > pe[i0]) i0 = e;
        int i1 = (i0 == 0) ? 1 : 0;
#pragma unroll
        for (int e = 0; e < En; e++) if (e != i0 && pe[e] > pe[i1]) i1 = e;
        float s2 = pe[i0] + pe[i1];
        int s0 = atomicAdd(&counts[i0], 1);
        toklist[i0 * Tt + s0] = t; gwlist[i0 * Tt + s0] = pe[i0] / s2;
        int s1 = atomicAdd(&counts[i1], 1);
        toklist[i1 * Tt + s1] = t; gwlist[i1 * Tt + s1] = pe[i1] / s2;
    }
}

// ---------- offsets + balance loss ----------
__global__ __launch_bounds__(256)
void finalize_k(const float* __restrict__ probs, const int* __restrict__ counts,
                int* __restrict__ offsets, float* __restrict__ loss_out)
{
    const int tid = threadIdx.x, lane = tid & 63, wid = tid >> 6;
    float ps[En];
#pragma unroll
    for (int e = 0; e < En; e++) ps[e] = 0.f;
    for (int t = tid; t < Tt; t += 256) {
#pragma unroll
        for (int e = 0; e < En; e++) ps[e] += probs[(size_t)t * En + e];
    }
#pragma unroll
    for (int e = 0; e < En; e++)
#pragma unroll
        for (int o = 1; o < 64; o <<= 1) ps[e] += __shfl_xor(ps[e], o, 64);
    __shared__ float red[4][En];
    if (lane == 0) {
#pragma unroll
        for (int e = 0; e < En; e++) red[wid][e] = ps[e];
    }
    __syncthreads();
    if (tid == 0) {
        int o = 0;
        float bl = 0.f;
#pragma unroll
        for (int e = 0; e < En; e++) {
            offsets[e] = o; o += counts[e];
            float pm = (red[0][e] + red[1][e] + red[2][e] + red[3][e]) * (1.0f / Tt);
            float fr = (float)counts[e] * (1.0f / (Tt * 2));
            bl += fr * pm;
        }
        loss_out[0] = 0.01f * (float)En * bl;
    }
}

extern "C" void kernel_launch(void* const* d_in, const int* in_sizes, int n_in,
                              void* d_out, int out_size, void* d_ws, size_t ws_size,
                              hipStream_t stream)
{
    (void)in_sizes; (void)n_in; (void)out_size; (void)ws_size;
    const float* hs  = (const float*)d_in[0];
    const float* ln1 = (const float*)d_in[1];
    const float* wq  = (const float*)d_in[2];
    const float* wk  = (const float*)d_in[3];
    const float* wv  = (const float*)d_in[4];
    const float* wo  = (const float*)d_in[5];
    const float* ln2 = (const float*)d_in[6];
    const float* rw  = (const float*)d_in[7];
    const float* wg  = (const float*)d_in[8];
    const float* wu  = (const float*)d_in[9];
    const float* wd  = (const float*)d_in[10];
    float* out = (float*)d_out;

    char* ws = (char*)d_ws;
    size_t off = 0;
    auto nxt = [&](size_t bytes) { char* p = ws + off; off += (bytes + 255) & ~(size_t)255; return p; };
    // ---- persistent (MoE-era) region ----
    u16* wgt  = (u16*)nxt((size_t)En * Fn * Dd * 2);
    u16* wut  = (u16*)nxt((size_t)En * Fn * Dd * 2);
    u16* wdt  = (u16*)nxt((size_t)En * Dd * Fn * 2);
    float* h2 = (float*)nxt((size_t)Tt * Dd * 4);
    u16* h2b  = (u16*)nxt((size_t)Tt * Dd * 2);
    float* probs = (float*)nxt((size_t)Tt * En * 4);
    int*   tokl  = (int*)nxt((size_t)En * Tt * 4);
    float* gwl   = (float*)nxt((size_t)En * Tt * 4);
    float* ctab  = (float*)nxt((size_t)Ss * 32 * 4);
    float* stab  = (float*)nxt((size_t)Ss * 32 * 4);
    int* counts  = (int*)nxt(256);
    int* offs    = (int*)nxt(256);
    // ---- transient (pre-MoE) region; `act` aliases it ----
    u16* act = (u16*)(ws + off);
    float* qkv = (float*)nxt((size_t)Tt * 1536 * 4);
    u16* h1hi = (u16*)nxt((size_t)Tt * Dd * 2);
    u16* h1lo = (u16*)nxt((size_t)Tt * Dd * 2);
    u16* khi  = (u16*)nxt((size_t)Tt * KVHn * HDn * 2);
    u16* klo  = (u16*)nxt((size_t)Tt * KVHn * HDn * 2);
    u16* vthi = (u16*)nxt((size_t)Tt * KVHn * HDn * 2);
    u16* vtlo = (u16*)nxt((size_t)Tt * KVHn * HDn * 2);
    u16* chi  = (u16*)nxt((size_t)Tt * Dd * 2);
    u16* clo  = (u16*)nxt((size_t)Tt * Dd * 2);
    u16* wqkvthi = (u16*)nxt((size_t)1536 * Dd * 2);
    u16* wqkvtlo = (u16*)nxt((size_t)1536 * Dd * 2);
    u16* wothi = (u16*)nxt((size_t)Dd * Dd * 2);
    u16* wotlo = (u16*)nxt((size_t)Dd * Dd * 2);

    rope_tab_k<<<dim3(256), 256, 0, stream>>>(ctab, stab);
    // weight prep
    tconv_k<true ><<<dim3(16 * 16), 256, 0, stream>>>(wq, wqkvthi, wqkvtlo, 1024, 1024,    0, 16);
    tconv_k<true ><<<dim3(16 *  4), 256, 0, stream>>>(wk, wqkvthi, wqkvtlo, 1024,  256, 1024,  4);
    tconv_k<true ><<<dim3(16 *  4), 256, 0, stream>>>(wv, wqkvthi, wqkvtlo, 1024,  256, 1280,  4);
    tconv_k<true ><<<dim3(16 * 16), 256, 0, stream>>>(wo, wothi, wotlo, 1024, 1024, 0, 16);
    tprep_k<32, false><<<dim3(32 * 32, En), 256, 0, stream>>>(wg, wgt, 1024, 4096, 32);
    tprep_k<32, false><<<dim3(32 * 32, En), 256, 0, stream>>>(wu, wut, 1024, 4096, 32);
    tprep_k<32, false><<<dim3(8 * 128, En), 256, 0, stream>>>(wd, wdt, 4096, 1024, 8);

    rmsnorm_split_k<<<dim3(Tt), 256, 0, stream>>>(hs, ln1, h1hi, h1lo);
    gemm_split_k<false><<<dim3(12 * 32), 256, 0, stream>>>(h1hi, h1lo, wqkvthi, wqkvtlo,
                                                           qkv, nullptr, Tt, 1536, Dd, 12);
    rope_q_k<<<dim3(Tt * Hh * 32 / 256), 256, 0, stream>>>(qkv, ctab, stab);
    kprep_k<<<dim3(Tt * KVHn * 32 / 256), 256, 0, stream>>>(qkv, ctab, stab, khi, klo);
    vprep_k<<<dim3(Ss / 64, Bb * KVHn), 256, 0, stream>>>(qkv, vthi, vtlo);
    attn_k<<<dim3(Ss / 64, Hh, Bb), 256, 0, stream>>>(qkv, khi, klo, vthi, vtlo, chi, clo);
    gemm_split_k<true><<<dim3(8 * 32), 256, 0, stream>>>(chi, clo, wothi, wotlo,
                                                         out, hs, Tt, Dd, Dd, 8);
    rmsnorm2_k<<<dim3(Tt), 256, 0, stream>>>(out, ln2, h2, h2b);
    (void)hipMemsetAsync(counts, 0, 64, stream);
    router_k<<<dim3(Tt), 256, 0, stream>>>(h2, rw, probs, counts, tokl, gwl);
    finalize_k<<<dim3(1), 256, 0, stream>>>(probs, counts, offs, out + (size_t)Tt * Dd);
    // MoE: gate -> act ; up (in-place silu(g)*u*gw) ; down scatter-add
    gemm_expert_k<0><<<dim3(32 * 32, En), 256, 0, stream>>>(h2b, wgt, act, tokl, gwl, counts, offs);
    gemm_expert_k<1><<<dim3(32 * 32, En), 256, 0, stream>>>(h2b, wut, act, tokl, gwl, counts, offs);
    gemm_down_k<<<dim3(8 * 32, En), 256, 0, stream>>>(act, wdt, out, tokl, counts, offs);
}

// Round 17
// 897.664 us; speedup vs baseline: 1.3147x; 1.3147x over previous
//
#include <hip/hip_runtime.h>

#define Tt 4096
#define Bb 2
#define Ss 2048
#define Dd 1024
#define Hh 16
#define KVHn 4
#define HDn 64
#define En 8
#define Fn 4096

#define BM 128
#define BN 128

typedef unsigned short u16;
typedef __attribute__((ext_vector_type(4))) float f32x4;
typedef __attribute__((ext_vector_type(8))) short bfrag;
typedef __attribute__((ext_vector_type(4))) short s16x4;

#define WAITV(N) asm volatile("s_waitcnt vmcnt(" #N ")" ::: "memory")
#define BARRIER() asm volatile("s_barrier" ::: "memory")

__device__ __forceinline__ u16 f2bf(float f) {
    unsigned u = __builtin_bit_cast(unsigned, f);
    u = (u + 0x7fffu + ((u >> 16) & 1u)) >> 16;
    return (u16)u;
}
__device__ __forceinline__ float bf2f(u16 b) {
    unsigned u = ((unsigned)b) << 16;
    return __builtin_bit_cast(float, u);
}
__device__ __forceinline__ void split8a(const float* va, bfrag* ph, bfrag* pl) {
    bfrag th, tl;
#pragma unroll
    for (int j = 0; j < 8; j++) {
        u16 hu = f2bf(va[j]);
        th[j] = (short)hu;
        tl[j] = (short)f2bf(va[j] - bf2f(hu));
    }
    *ph = th; *pl = tl;
}
// async global->LDS, 16B per lane; LDS dest = wave-uniform base + lane*16, global src per-lane
__device__ __forceinline__ void glds16(const void* g, void* l) {
    __builtin_amdgcn_global_load_lds(
        (const __attribute__((address_space(1))) unsigned int*)g,
        (__attribute__((address_space(3))) unsigned int*)l, 16, 0, 0);
}

// ---------- transpose + bf16 convert (hi/lo split) for QKV/WO weights: [K][N] -> [N][K] ----------
template<bool SPL>
__global__ __launch_bounds__(256)
void tconv_k(const float* __restrict__ src, u16* __restrict__ dhi, u16* __restrict__ dlo,
             const int K, const int N, const int rowOff, const int nTilesN)
{
    const int tid = threadIdx.x;
    const int ty = blockIdx.x / nTilesN, tx = blockIdx.x % nTilesN;
    const int k0 = ty * 64, n0 = tx * 64;
    __shared__ float tl[64][65];
#pragma unroll
    for (int it = 0; it < 16; it++) {
        int idx = tid + it * 256;
        int kk = idx >> 6, nn = idx & 63;
        tl[kk][nn] = src[(size_t)(k0 + kk) * N + n0 + nn];
    }
    __syncthreads();
#pragma unroll
    for (int it = 0; it < 8; it++) {
        int idx = tid + it * 256;
        int n = idx >> 5, k2 = (idx & 31) * 2;
        float v0 = tl[k2][n], v1 = tl[k2 + 1][n];
        u16 h0 = f2bf(v0), h1v = f2bf(v1);
        size_t o = (size_t)(rowOff + n0 + n) * K + k0 + k2;
        *(unsigned*)&dhi[o] = (unsigned)h0 | ((unsigned)h1v << 16);
        if (SPL) {
            u16 l0 = f2bf(v0 - bf2f(h0)), l1 = f2bf(v1 - bf2f(h1v));
            *(unsigned*)&dlo[o] = (unsigned)l0 | ((unsigned)l1 << 16);
        }
    }
}

// ---------- MoE weight prep: f32 [K][N] -> tiled bf16 blocks [nt][kt][128n x TBK k] ----------
template<int TBK, bool SWZ>
__global__ __launch_bounds__(256)
void tprep_k(const float* __restrict__ src, u16* __restrict__ dst,
             const int K, const int N, const int nTilesN)
{
    const int tid = threadIdx.x;
    const int e = blockIdx.y;
    const int ntl = blockIdx.x % nTilesN, kt = blockIdx.x / nTilesN;
    const int nTK = K / TBK;
    src += (size_t)e * K * N + (size_t)(kt * TBK) * N + ntl * 128;
    u16* dblk = dst + (((size_t)e * nTilesN + ntl) * nTK + kt) * (size_t)(128 * TBK);
    __shared__ float tl[TBK][132];
#pragma unroll
    for (int it = 0; it < TBK / 8; it++) {
        int i4 = tid + it * 256;
        int kk = i4 >> 5, n = (i4 & 31) * 4;
        f32x4 v = *(const f32x4*)(src + (size_t)kk * N + n);
        tl[kk][n] = v.x; tl[kk][n + 1] = v.y; tl[kk][n + 2] = v.z; tl[kk][n + 3] = v.w;
    }
    __syncthreads();
#pragma unroll
    for (int it = 0; it < TBK / 16; it++) {
        int idx = tid + it * 256;
        int n = (TBK == 32) ? (idx >> 2) : (idx >> 3);
        int c = (TBK == 32) ? (idx & 3) : (idx & 7);
        bfrag v;
#pragma unroll
        for (int j = 0; j < 8; j++) v[j] = (short)f2bf(tl[c * 8 + j][n]);
        int boff = n * (TBK * 2) + ((c * 16) ^ (SWZ ? ((n & 7) << 4) : 0));
        *(bfrag*)((char*)dblk + boff) = v;
    }
}

// ---------- RMSNorm -> split bf16 (hi/lo) ----------
__global__ __launch_bounds__(256)
void rmsnorm_split_k(const float* __restrict__ x, const float* __restrict__ w,
                     u16* __restrict__ ohi, u16* __restrict__ olo)
{
    const int row = blockIdx.x;
    const int tid = threadIdx.x;
    const int lane = tid & 63, wid = tid >> 6;
    f32x4 t4 = *(const f32x4*)(x + (size_t)row * Dd + tid * 4);
    float s = t4.x*t4.x + t4.y*t4.y + t4.z*t4.z + t4.w*t4.w;
#pragma unroll
    for (int o = 1; o < 64; o <<= 1) s += __shfl_xor(s, o, 64);
    __shared__ float red[4];
    if (lane == 0) red[wid] = s;
    __syncthreads();
    float inv = rsqrtf((red[0] + red[1] + red[2] + red[3]) * (1.0f / Dd) + 1e-6f);
    f32x4 w4 = *(const f32x4*)(w + tid * 4);
    float va[4] = { t4.x*inv*w4.x, t4.y*inv*w4.y, t4.z*inv*w4.z, t4.w*inv*w4.w };
    s16x4 hi, lo;
#pragma unroll
    for (int j = 0; j < 4; j++) {
        u16 hu = f2bf(va[j]);
        hi[j] = (short)hu;
        lo[j] = (short)f2bf(va[j] - bf2f(hu));
    }
    *(s16x4*)&ohi[(size_t)row * Dd + tid * 4] = hi;
    *(s16x4*)&olo[(size_t)row * Dd + tid * 4] = lo;
}

// ---------- RMSNorm -> f32 (router) + rounded bf16 (MoE A) ----------
__global__ __launch_bounds__(256)
void rmsnorm2_k(const float* __restrict__ x, const float* __restrict__ w,
                float* __restrict__ of, u16* __restrict__ ob)
{
    const int row = blockIdx.x;
    const int tid = threadIdx.x;
    const int lane = tid & 63, wid = tid >> 6;
    f32x4 t4 = *(const f32x4*)(x + (size_t)row * Dd + tid * 4);
    float s = t4.x*t4.x + t4.y*t4.y + t4.z*t4.z + t4.w*t4.w;
#pragma unroll
    for (int o = 1; o < 64; o <<= 1) s += __shfl_xor(s, o, 64);
    __shared__ float red[4];
    if (lane == 0) red[wid] = s;
    __syncthreads();
    float inv = rsqrtf((red[0] + red[1] + red[2] + red[3]) * (1.0f / Dd) + 1e-6f);
    f32x4 w4 = *(const f32x4*)(w + tid * 4);
    f32x4 o4;
    o4.x = t4.x*inv*w4.x; o4.y = t4.y*inv*w4.y; o4.z = t4.z*inv*w4.z; o4.w = t4.w*inv*w4.w;
    *(f32x4*)&of[(size_t)row * Dd + tid * 4] = o4;
    s16x4 hb;
    hb[0] = (short)f2bf(o4.x); hb[1] = (short)f2bf(o4.y);
    hb[2] = (short)f2bf(o4.z); hb[3] = (short)f2bf(o4.w);
    *(s16x4*)&ob[(size_t)row * Dd + tid * 4] = hb;
}

// ---------- RoPE tables (f64) ----------
__global__ __launch_bounds__(256)
void rope_tab_k(float* __restrict__ ct, float* __restrict__ st)
{
    int idx = blockIdx.x * 256 + threadIdx.x;
    if (idx < Ss * 32) {
        int s = idx >> 5, i = idx & 31;
        double inv = pow(10000.0, -((double)(2 * i)) / 64.0);
        double a = (double)s * inv;
        double sn, cs;
        sincos(a, &sn, &cs);
        ct[idx] = (float)cs;
        st[idx] = (float)sn;
    }
}

// ---------- RoPE on Q (in-place, qkv stride 1536) ----------
__global__ __launch_bounds__(256)
void rope_q_k(float* __restrict__ qkv, const float* __restrict__ ct, const float* __restrict__ st)
{
    int idx = blockIdx.x * 256 + threadIdx.x;
    int i = idx & 31, hh = (idx >> 5) & (Hh - 1), t = idx >> 9;
    int s = t & (Ss - 1);
    float cs = ct[s * 32 + i], sn = st[s * 32 + i];
    float* base = qkv + (size_t)t * 1536 + hh * 64 + i;
    float x1 = base[0], x2 = base[32];
    base[0]  = x1 * cs - x2 * sn;
    base[32] = x2 * cs + x1 * sn;
}

// ---------- K: RoPE + split bf16 ----------
__global__ __launch_bounds__(256)
void kprep_k(const float* __restrict__ qkv, const float* __restrict__ ct,
             const float* __restrict__ st, u16* __restrict__ khi, u16* __restrict__ klo)
{
    int idx = blockIdx.x * 256 + threadIdx.x;
    int i = idx & 31, hh = (idx >> 5) & (KVHn - 1), t = idx >> 7;
    int s = t & (Ss - 1);
    float cs = ct[s * 32 + i], sn = st[s * 32 + i];
    const float* base = qkv + (size_t)t * 1536 + 1024 + hh * 64 + i;
    float x1 = base[0], x2 = base[32];
    float r1 = x1 * cs - x2 * sn, r2 = x2 * cs + x1 * sn;
    size_t o = (size_t)t * (KVHn * HDn) + hh * 64 + i;
    u16 h1v = f2bf(r1), h2v = f2bf(r2);
    khi[o] = h1v;       khi[o + 32] = h2v;
    klo[o] = f2bf(r1 - bf2f(h1v));
    klo[o + 32] = f2bf(r2 - bf2f(h2v));
}

// ---------- V: transpose + split ----------
__global__ __launch_bounds__(256)
void vprep_k(const float* __restrict__ qkv, u16* __restrict__ vthi, u16* __restrict__ vtlo)
{
    const int st0 = blockIdx.x * 64;
    const int g = blockIdx.y;
    const int b = g >> 2, kvh = g & 3;
    const int tid = threadIdx.x;
    __shared__ float tl[64][65];
#pragma unroll
    for (int it = 0; it < 16; it++) {
        int idx = tid + it * 256;
        int sl = idx >> 6, d = idx & 63;
        tl[sl][d] = qkv[(size_t)(b * Ss + st0 + sl) * 1536 + 1280 + kvh * 64 + d];
    }
    __syncthreads();
#pragma unroll
    for (int it = 0; it < 8; it++) {
        int idx = tid + it * 256;
        int d = idx >> 5, s2 = (idx & 31) * 2;
        float v0 = tl[s2][d], v1 = tl[s2 + 1][d];
        u16 h0 = f2bf(v0), h1v = f2bf(v1);
        size_t o = ((size_t)g * 64 + d) * Ss + st0 + s2;
        *(unsigned*)&vthi[o] = (unsigned)h0 | ((unsigned)h1v << 16);
        u16 l0 = f2bf(v0 - bf2f(h0)), l1 = f2bf(v1 - bf2f(h1v));
        *(unsigned*)&vtlo[o] = (unsigned)l0 | ((unsigned)l1 << 16);
    }
}

// ---------- split-bf16x3 GEMM (glds + dbuf + counted vmcnt): C = A@B^T(+resid) ----------
template<bool RESID>
__global__ __launch_bounds__(256)
void gemm_split_k(const u16* __restrict__ Ahi_g, const u16* __restrict__ Alo_g,
                  const u16* __restrict__ Bhi_g, const u16* __restrict__ Blo_g,
                  float* __restrict__ C, const float* __restrict__ resid,
                  const int M, const int N, const int K, const int ntiles)
{
    const int bid = blockIdx.x;
    const int nt = bid % ntiles, mt = bid / ntiles;
    __shared__ __align__(16) u16 Ah[2][128 * 32], Al[2][128 * 32];
    __shared__ __align__(16) u16 Bh[2][128 * 32], Bl[2][128 * 32];   // 64 KB
    const int tid = threadIdx.x, lane = tid & 63, wid = tid >> 6;
    const int wrow = (wid >> 1) * 64, wcol = (wid & 1) * 64;
    const int l15 = lane & 15, lhi = lane >> 4;
    const int row0 = mt * BM, col0 = nt * BN;

    const u16 *ah_s[2], *al_s[2], *bh_s[2], *bl_s[2];
#pragma unroll
    for (int j = 0; j < 2; j++) {
        int r = (wid * 2 + j) * 16 + (lane >> 2);
        size_t ca = (size_t)(row0 + r) * K + (lane & 3) * 8;
        size_t cb = (size_t)(col0 + r) * K + (lane & 3) * 8;
        ah_s[j] = Ahi_g + ca; al_s[j] = Alo_g + ca;
        bh_s[j] = Bhi_g + cb; bl_s[j] = Blo_g + cb;
    }
    f32x4 acc[4][4];
#pragma unroll
    for (int i = 0; i < 4; i++)
#pragma unroll
        for (int j = 0; j < 4; j++) { acc[i][j].x = 0.f; acc[i][j].y = 0.f; acc[i][j].z = 0.f; acc[i][j].w = 0.f; }

    auto stage = [&](int buf, int k0) {
#pragma unroll
        for (int j = 0; j < 2; j++) {
            int d = (wid * 2 + j) * 512;
            glds16(ah_s[j] + k0, &Ah[buf][d]);
            glds16(al_s[j] + k0, &Al[buf][d]);
            glds16(bh_s[j] + k0, &Bh[buf][d]);
            glds16(bl_s[j] + k0, &Bl[buf][d]);
        }
    };
    auto compute = [&](int cur) {
        bfrag ah[4], al[4], bh[4], bl[4];
#pragma unroll
        for (int mi = 0; mi < 4; mi++) {
            int rb = (wrow + mi * 16 + l15) * 32 + lhi * 8;
            ah[mi] = *(const bfrag*)&Ah[cur][rb];
            al[mi] = *(const bfrag*)&Al[cur][rb];
        }
#pragma unroll
        for (int ni = 0; ni < 4; ni++) {
            int rb = (wcol + ni * 16 + l15) * 32 + lhi * 8;
            bh[ni] = *(const bfrag*)&Bh[cur][rb];
            bl[ni] = *(const bfrag*)&Bl[cur][rb];
        }
#pragma unroll
        for (int mi = 0; mi < 4; mi++)
#pragma unroll
            for (int ni = 0; ni < 4; ni++) {
                acc[mi][ni] = __builtin_amdgcn_mfma_f32_16x16x32_bf16(ah[mi], bh[ni], acc[mi][ni], 0, 0, 0);
                acc[mi][ni] = __builtin_amdgcn_mfma_f32_16x16x32_bf16(ah[mi], bl[ni], acc[mi][ni], 0, 0, 0);
                acc[mi][ni] = __builtin_amdgcn_mfma_f32_16x16x32_bf16(al[mi], bh[ni], acc[mi][ni], 0, 0, 0);
            }
    };
    const int nkt = K / 32;
    stage(0, 0);
    stage(1, 32);
    int cur = 0;
    for (int kt = 0; kt < nkt - 1; kt++) {
        WAITV(8);       // own tile-kt loads done; kt+1 still in flight
        BARRIER();
        compute(cur);
        BARRIER();
        if (kt + 2 < nkt) stage(cur, (kt + 2) * 32);
        cur ^= 1;
    }
    WAITV(0);
    BARRIER();
    compute(cur);
#pragma unroll
    for (int mi = 0; mi < 4; mi++) {
#pragma unroll
        for (int t = 0; t < 4; t++) {
            int pr = row0 + wrow + mi * 16 + lhi * 4 + t;
#pragma unroll
            for (int ni = 0; ni < 4; ni++) {
                int gc = col0 + wcol + ni * 16 + l15;
                float vv = acc[mi][ni][t];
                if (RESID) vv += resid[(size_t)pr * N + gc];
                C[(size_t)pr * N + gc] = vv;
            }
        }
    }
}

// ---------- MoE expert GEMM (single output): glds + dbuf + counted vmcnt, BK=32 ----------
// MODE 0 (gate): act[ix] = bf16(acc)
// MODE 1 (up):   g = act[ix]; act[ix] = bf16(silu(g) * acc * gw)   [in-place, same thread owns ix]
template<int MODE>
__global__ __launch_bounds__(256, 4)
void gemm_expert_k(const u16* __restrict__ A_g, const u16* __restrict__ Bt,
                   u16* __restrict__ act,
                   const int* __restrict__ toklist, const float* __restrict__ gwlist,
                   const int* __restrict__ counts, const int* __restrict__ offsets)
{
    const int e = blockIdx.y;
    const int Meff = counts[e];
    const int nt = blockIdx.x & 31, mt = blockIdx.x >> 5;
    if (mt * BM >= Meff) return;
    const int* tok = toklist + e * Tt;
    const float* gw = gwlist + e * Tt;
    const int rowoff = offsets[e];
    __shared__ __align__(16) u16 As[2][128 * 32], Bs[2][128 * 32];   // 32 KB
    const int tid = threadIdx.x, lane = tid & 63, wid = tid >> 6;
    const int wrow = (wid >> 1) * 64, wcol = (wid & 1) * 64;
    const int l15 = lane & 15, lhi = lane >> 4;
    const int row0 = mt * BM, col0 = nt * BN;

    const u16* asrc[2];
#pragma unroll
    for (int j = 0; j < 2; j++) {
        int row = (wid * 2 + j) * 16 + (lane >> 2);
        int pr = row0 + row;
        int tr = (pr < Meff) ? tok[pr] : tok[0];
        asrc[j] = A_g + (size_t)tr * Dd + (lane & 3) * 8;
    }
    const size_t bblk = (size_t)(e * 32 + nt) * (32 * 4096);
    const u16* bsrc = Bt + bblk + (size_t)(wid * 2) * 512 + lane * 8;

    f32x4 acc[4][4];
#pragma unroll
    for (int i = 0; i < 4; i++)
#pragma unroll
        for (int j = 0; j < 4; j++) { acc[i][j].x = 0.f; acc[i][j].y = 0.f; acc[i][j].z = 0.f; acc[i][j].w = 0.f; }

    auto stage = [&](int buf, int kt) {
#pragma unroll
        for (int j = 0; j < 2; j++) {
            int d = (wid * 2 + j) * 512;
            glds16(asrc[j] + kt * 32,                  &As[buf][d]);
            glds16(bsrc + j * 512 + (size_t)kt * 4096, &Bs[buf][d]);
        }
    };
    auto compute = [&](int cur) {
        bfrag a[4];
#pragma unroll
        for (int mi = 0; mi < 4; mi++)
            a[mi] = *(const bfrag*)&As[cur][(wrow + mi * 16 + l15) * 32 + lhi * 8];
#pragma unroll
        for (int ni = 0; ni < 4; ni++) {
            bfrag b = *(const bfrag*)&Bs[cur][(wcol + ni * 16 + l15) * 32 + lhi * 8];
#pragma unroll
            for (int mi = 0; mi < 4; mi++)
                acc[mi][ni] = __builtin_amdgcn_mfma_f32_16x16x32_bf16(a[mi], b, acc[mi][ni], 0, 0, 0);
        }
    };
    stage(0, 0);
    stage(1, 1);
    int cur = 0;
    for (int kt = 0; kt < 31; kt++) {
        WAITV(4);
        BARRIER();
        compute(cur);
        BARRIER();
        if (kt + 2 < 32) stage(cur, kt + 2);
        cur ^= 1;
    }
    WAITV(0);
    BARRIER();
    compute(cur);
#pragma unroll
    for (int mi = 0; mi < 4; mi++) {
#pragma unroll
        for (int t = 0; t < 4; t++) {
            int pr = row0 + wrow + mi * 16 + lhi * 4 + t;
            if (pr < Meff) {
                float gwv = (MODE == 1) ? gw[pr] : 0.f;
#pragma unroll
                for (int ni = 0; ni < 4; ni++) {
                    int gc = col0 + wcol + ni * 16 + l15;
                    size_t ix = (size_t)(rowoff + pr) * Fn + gc;
                    if (MODE == 0) {
                        act[ix] = f2bf(acc[mi][ni][t]);
                    } else {
                        float g = bf2f(act[ix]);
                        float sg = g / (1.0f + expf(-g));
                        act[ix] = f2bf(sg * acc[mi][ni][t] * gwv);
                    }
                }
            }
        }
    }
}

// ---------- MoE down (glds + dbuf + counted vmcnt, BK=32): out[tok] += act @ Wd^T ----------
__global__ __launch_bounds__(256, 4)
void gemm_down_k(const u16* __restrict__ act, const u16* __restrict__ Bt,
                 float* __restrict__ C, const int* __restrict__ toklist,
                 const int* __restrict__ counts, const int* __restrict__ offsets)
{
    const int e = blockIdx.y;
    const int Meff = counts[e];
    const int nt = blockIdx.x & 7, mt = blockIdx.x >> 3;
    if (mt * BM >= Meff) return;
    const int* tok = toklist + e * Tt;
    const int rowoff = offsets[e];
    __shared__ __align__(16) u16 As[2][128 * 32], Bs[2][128 * 32];   // 32 KB
    const int tid = threadIdx.x, lane = tid & 63, wid = tid >> 6;
    const int wrow = (wid >> 1) * 64, wcol = (wid & 1) * 64;
    const int l15 = lane & 15, lhi = lane >> 4;
    const int row0 = mt * BM;

    const u16* asrc[2];
#pragma unroll
    for (int j = 0; j < 2; j++) {
        int row = (wid * 2 + j) * 16 + (lane >> 2);
        int pr = row0 + row;
        int rr = (pr < Meff) ? pr : 0;
        asrc[j] = act + (size_t)(rowoff + rr) * Fn + (lane & 3) * 8;
    }
    const size_t bblk = (size_t)(e * 8 + nt) * ((size_t)128 * 4096);
    const u16* bsrc = Bt + bblk + (size_t)(wid * 2) * 512 + lane * 8;

    f32x4 acc[4][4];
#pragma unroll
    for (int i = 0; i < 4; i++)
#pragma unroll
        for (int j = 0; j < 4; j++) { acc[i][j].x = 0.f; acc[i][j].y = 0.f; acc[i][j].z = 0.f; acc[i][j].w = 0.f; }

    auto stage = [&](int buf, int kt) {
#pragma unroll
        for (int j = 0; j < 2; j++) {
            int d = (wid * 2 + j) * 512;
            glds16(asrc[j] + kt * 32,                  &As[buf][d]);
            glds16(bsrc + j * 512 + (size_t)kt * 4096, &Bs[buf][d]);
        }
    };
    auto compute = [&](int cur) {
        bfrag a[4];
#pragma unroll
        for (int mi = 0; mi < 4; mi++)
            a[mi] = *(const bfrag*)&As[cur][(wrow + mi * 16 + l15) * 32 + lhi * 8];
#pragma unroll
        for (int ni = 0; ni < 4; ni++) {
            bfrag b = *(const bfrag*)&Bs[cur][(wcol + ni * 16 + l15) * 32 + lhi * 8];
#pragma unroll
            for (int mi = 0; mi < 4; mi++)
                acc[mi][ni] = __builtin_amdgcn_mfma_f32_16x16x32_bf16(a[mi], b, acc[mi][ni], 0, 0, 0);
        }
    };
    stage(0, 0);
    stage(1, 1);
    int cur = 0;
    const int nkt = Fn / 32;   // 128
    for (int kt = 0; kt < nkt - 1; kt++) {
        WAITV(4);
        BARRIER();
        compute(cur);
        BARRIER();
        if (kt + 2 < nkt) stage(cur, kt + 2);
        cur ^= 1;
    }
    WAITV(0);
    BARRIER();
    compute(cur);
#pragma unroll
    for (int mi = 0; mi < 4; mi++) {
#pragma unroll
        for (int t = 0; t < 4; t++) {
            int pr = row0 + wrow + mi * 16 + lhi * 4 + t;
            if (pr < Meff) {
                int trow = tok[pr];
#pragma unroll
                for (int ni = 0; ni < 4; ni++) {
                    int gc = nt * BN + wcol + ni * 16 + l15;
                    atomicAdd(&C[(size_t)trow * Dd + gc], acc[mi][ni][t]);
                }
            }
        }
    }
}

// ---------- Flash attention (causal GQA), split-bf16x3, swapped QK^T + swapped PV ----------
__global__ __launch_bounds__(256)
void attn_k(const float* __restrict__ qkv, const u16* __restrict__ khi,
            const u16* __restrict__ klo, const u16* __restrict__ vthi,
            const u16* __restrict__ vtlo, u16* __restrict__ chi, u16* __restrict__ clo)
{
    const int qt = (int)gridDim.x - 1 - (int)blockIdx.x;
    const int h = blockIdx.y, b = blockIdx.z;
    const int kvh = h >> 2;
    const int g = b * KVHn + kvh;
    const int tid = threadIdx.x;
    const int lane = tid & 63, wid = tid >> 6;
    const int l15 = lane & 15, lhi = lane >> 4;

    __shared__ __align__(16) u16 Khi[64 * 64];
    __shared__ __align__(16) u16 Klo[64 * 64];
    __shared__ __align__(16) u16 Vhi[64 * 72];
    __shared__ __align__(16) u16 Vlo[64 * 72];
    __shared__ __align__(16) u16 Phi[4 * 16 * 72];
    __shared__ __align__(16) u16 Plo[4 * 16 * 72];

    bfrag qh[2], ql[2];
    {
        const int qrow = qt * 64 + wid * 16 + l15;
        const float* qb = qkv + (size_t)(b * Ss + qrow) * 1536 + h * 64;
#pragma unroll
        for (int ks = 0; ks < 2; ks++) {
            const float* p = qb + ks * 32 + lhi * 8;
            f32x4 u0 = *(const f32x4*)p;
            f32x4 u1 = *(const f32x4*)(p + 4);
            float va[8] = { u0.x * 0.125f, u0.y * 0.125f, u0.z * 0.125f, u0.w * 0.125f,
                            u1.x * 0.125f, u1.y * 0.125f, u1.z * 0.125f, u1.w * 0.125f };
            split8a(va, &qh[ks], &ql[ks]);
        }
    }
    // per-thread staging geometry
    size_t kga[2], vga[2];
    int kboff[2], vboff[2];
#pragma unroll
    for (int it = 0; it < 2; it++) {
        int ci = tid + it * 256;
        int kv = ci >> 3, d0 = (ci & 7) << 3;
        kga[it] = (size_t)(b * Ss + kv) * (KVHn * HDn) + kvh * 64 + d0;
        kboff[it] = kv * 128 + ((d0 * 2) ^ ((kv & 7) << 4));
        int d = ci >> 3, kv0 = (ci & 7) << 3;
        vga[it] = ((size_t)g * 64 + d) * Ss + kv0;
        vboff[it] = d * 72 + kv0;
    }
    bfrag rkh[2], rkl[2], rvh[2], rvl[2];
    auto LOADR = [&](int kt) {
#pragma unroll
        for (int it = 0; it < 2; it++) {
            size_t ga = kga[it] + (size_t)kt * (64 * KVHn * HDn);
            rkh[it] = *(const bfrag*)&khi[ga];
            rkl[it] = *(const bfrag*)&klo[ga];
            size_t gv = vga[it] + (size_t)kt * 64;
            rvh[it] = *(const bfrag*)&vthi[gv];
            rvl[it] = *(const bfrag*)&vtlo[gv];
        }
    };
    f32x4 O[4];   // O^T: O[ni][t] = O^T[d = ni*16+lhi*4+t][q = l15]
#pragma unroll
    for (int ni = 0; ni < 4; ni++) { O[ni].x = 0.f; O[ni].y = 0.f; O[ni].z = 0.f; O[ni].w = 0.f; }
    float m_s = -1e30f;   // running max for q-row (wid*16 + l15)
    float l_s = 0.f;      // running denom for q-row (wid*16 + l15)

    LOADR(0);
    for (int kt = 0; kt <= qt; kt++) {
        // ---- write prefetched K/V regs to LDS ----
#pragma unroll
        for (int it = 0; it < 2; it++) {
            *(bfrag*)((char*)Khi + kboff[it]) = rkh[it];
            *(bfrag*)((char*)Klo + kboff[it]) = rkl[it];
            *(bfrag*)&Vhi[vboff[it]] = rvh[it];
            *(bfrag*)&Vlo[vboff[it]] = rvl[it];
        }
        __syncthreads();
        if (kt < qt) LOADR(kt + 1);
        // ---- S^T = K Q^T (3-pass split, swapped operands): sf[ni][t] = S[kv=ni*16+lhi*4+t][q=l15] ----
        f32x4 sf[4];
#pragma unroll
        for (int ni = 0; ni < 4; ni++) { sf[ni].x = 0.f; sf[ni].y = 0.f; sf[ni].z = 0.f; sf[ni].w = 0.f; }
        __builtin_amdgcn_s_setprio(1);
#pragma unroll
        for (int ks = 0; ks < 2; ks++) {
#pragma unroll
            for (int ni = 0; ni < 4; ni++) {
                int kv = ni * 16 + l15;
                int dof = ks * 64 + lhi * 16;
                int boff = kv * 128 + (dof ^ ((kv & 7) << 4));
                bfrag kfh = *(const bfrag*)((const char*)Khi + boff);
                bfrag kfl = *(const bfrag*)((const char*)Klo + boff);
                sf[ni] = __builtin_amdgcn_mfma_f32_16x16x32_bf16(kfh, qh[ks], sf[ni], 0, 0, 0);
                sf[ni] = __builtin_amdgcn_mfma_f32_16x16x32_bf16(kfl, qh[ks], sf[ni], 0, 0, 0);
                sf[ni] = __builtin_amdgcn_mfma_f32_16x16x32_bf16(kfh, ql[ks], sf[ni], 0, 0, 0);
            }
        }
        __builtin_amdgcn_s_setprio(0);
        // ---- causal mask (kv = ni*16+lhi*4+t, q = wid*16+l15) ----
        if (kt == qt) {
#pragma unroll
            for (int ni = 0; ni < 4; ni++)
#pragma unroll
                for (int t = 0; t < 4; t++)
                    if (ni * 16 + lhi * 4 + t > wid * 16 + l15) sf[ni][t] = -1e30f;
        }
        // ---- lane-local softmax: each lane owns q-row l15 (of its wave group) ----
        float mx = -1e30f;
#pragma unroll
        for (int ni = 0; ni < 4; ni++)
#pragma unroll
            for (int t = 0; t < 4; t++) mx = fmaxf(mx, sf[ni][t]);
        mx = fmaxf(mx, __shfl_xor(mx, 16, 64));
        mx = fmaxf(mx, __shfl_xor(mx, 32, 64));
        float mn = fmaxf(m_s, mx);
        float sc = expf(m_s - mn);
        m_s = mn;
        float rs = 0.f;
#pragma unroll
        for (int ni = 0; ni < 4; ni++)
#pragma unroll
            for (int t = 0; t < 4; t++) {
                float p = expf(sf[ni][t] - mn);
                sf[ni][t] = p;
                rs += p;
            }
        rs += __shfl_xor(rs, 16, 64);
        rs += __shfl_xor(rs, 32, 64);
        l_s = l_s * sc + rs;
        // ---- O^T rescale: columns are q = l15 -> sc is lane-local, no broadcast ----
#pragma unroll
        for (int ni = 0; ni < 4; ni++)
#pragma unroll
            for (int t = 0; t < 4; t++) O[ni][t] *= sc;
        // ---- P write: row = q = wid*16+l15, col = kv = ni*16+lhi*4+t (same-wave region) ----
#pragma unroll
        for (int ni = 0; ni < 4; ni++)
#pragma unroll
            for (int t = 0; t < 4; t++) {
                float p = sf[ni][t];
                u16 hu = f2bf(p);
                int ix = (wid * 16 + l15) * 72 + ni * 16 + lhi * 4 + t;
                Phi[ix] = hu;
                Plo[ix] = f2bf(p - bf2f(hu));
            }
        asm volatile("s_waitcnt lgkmcnt(0)" ::: "memory");
        __builtin_amdgcn_sched_barrier(0);
        // ---- O^T += V^T P^T (swapped operands; same LDS reads as before) ----
        __builtin_amdgcn_s_setprio(1);
#pragma unroll
        for (int ks = 0; ks < 2; ks++) {
            int pb = (wid * 16 + l15) * 72 + ks * 32 + lhi * 8;
            bfrag pfh = *(const bfrag*)&Phi[pb];
            bfrag pfl = *(const bfrag*)&Plo[pb];
#pragma unroll
            for (int ni = 0; ni < 4; ni++) {
                int vb = (ni * 16 + l15) * 72 + ks * 32 + lhi * 8;
                bfrag vfh = *(const bfrag*)&Vhi[vb];
                bfrag vfl = *(const bfrag*)&Vlo[vb];
                O[ni] = __builtin_amdgcn_mfma_f32_16x16x32_bf16(vfh, pfh, O[ni], 0, 0, 0);
                O[ni] = __builtin_amdgcn_mfma_f32_16x16x32_bf16(vfl, pfh, O[ni], 0, 0, 0);
                O[ni] = __builtin_amdgcn_mfma_f32_16x16x32_bf16(vfh, pfl, O[ni], 0, 0, 0);
            }
        }
        __builtin_amdgcn_s_setprio(0);
        __syncthreads();
    }
    // ---- epilogue: denom lane-local; write O^T[d][q] -> ctx[q][d] ----
    {
        float inv = 1.0f / l_s;
        int qrow = qt * 64 + wid * 16 + l15;
        size_t base = (size_t)(b * Ss + qrow) * Dd + h * 64;
#pragma unroll
        for (int ni = 0; ni < 4; ni++)
#pragma unroll
            for (int t = 0; t < 4; t++) {
                float val = O[ni][t] * inv;
                u16 hv = f2bf(val);
                int d = ni * 16 + lhi * 4 + t;
                chi[base + d] = hv;
                clo[base + d] = f2bf(val - bf2f(hv));
            }
    }
}

// ---------- Router ----------
__global__ __launch_bounds__(256)
void router_k(const float* __restrict__ h2, const float* __restrict__ rw,
              float* __restrict__ probs, int* __restrict__ counts,
              int* __restrict__ toklist, float* __restrict__ gwlist)
{
    const int t = blockIdx.x;
    const int tid = threadIdx.x;
    const int lane = tid & 63, wid = tid >> 6;
    f32x4 x4 = *(const f32x4*)(h2 + (size_t)t * Dd + tid * 4);
    float part[En];
#pragma unroll
    for (int e = 0; e < En; e++) {
        f32x4 w4 = *(const f32x4*)(rw + (size_t)e * Dd + tid * 4);
        part[e] = x4.x * w4.x + x4.y * w4.y + x4.z * w4.z + x4.w * w4.w;
    }
#pragma unroll
    for (int e = 0; e < En; e++)
#pragma unroll
        for (int o = 1; o < 64; o <<= 1) part[e] += __shfl_xor(part[e], o, 64);
    __shared__ float red[4][En];
    if (lane == 0) {
#pragma unroll
        for (int e = 0; e < En; e++) red[wid][e] = part[e];
    }
    __syncthreads();
    if (tid == 0) {
        float lg[En];
        float mx = -1e30f;
#pragma unroll
        for (int e = 0; e < En; e++) {
            lg[e] = red[0][e] + red[1][e] + red[2][e] + red[3][e];
            mx = fmaxf(mx, lg[e]);
        }
        float pe[En], ssum = 0.f;
#pragma unroll
        for (int e = 0; e < En; e++) { pe[e] = expf(lg[e] - mx); ssum += pe[e]; }
        float inv = 1.0f / ssum;
#pragma unroll
        for (int e = 0; e < En; e++) { pe[e] *= inv; probs[(size_t)t * En + e] = pe[e]; }
        int i0 = 0;
#pragma unroll
        for (int e = 1; e < En; e++) if (pe[e] > pe[i0]) i0 = e;
        int i1 = (i0 == 0) ? 1 : 0;
#pragma unroll
        for (int e = 0; e < En; e++) if (e != i0 && pe[e] > pe[i1]) i1 = e;
        float s2 = pe[i0] + pe[i1];
        int s0 = atomicAdd(&counts[i0], 1);
        toklist[i0 * Tt + s0] = t; gwlist[i0 * Tt + s0] = pe[i0] / s2;
        int s1 = atomicAdd(&counts[i1], 1);
        toklist[i1 * Tt + s1] = t; gwlist[i1 * Tt + s1] = pe[i1] / s2;
    }
}

// ---------- offsets + balance loss ----------
__global__ __launch_bounds__(256)
void finalize_k(const float* __restrict__ probs, const int* __restrict__ counts,
                int* __restrict__ offsets, float* __restrict__ loss_out)
{
    const int tid = threadIdx.x, lane = tid & 63, wid = tid >> 6;
    float ps[En];
#pragma unroll
    for (int e = 0; e < En; e++) ps[e] = 0.f;
    for (int t = tid; t < Tt; t += 256) {
#pragma unroll
        for (int e = 0; e < En; e++) ps[e] += probs[(size_t)t * En + e];
    }
#pragma unroll
    for (int e = 0; e < En; e++)
#pragma unroll
        for (int o = 1; o < 64; o <<= 1) ps[e] += __shfl_xor(ps[e], o, 64);
    __shared__ float red[4][En];
    if (lane == 0) {
#pragma unroll
        for (int e = 0; e < En; e++) red[wid][e] = ps[e];
    }
    __syncthreads();
    if (tid == 0) {
        int o = 0;
        float bl = 0.f;
#pragma unroll
        for (int e = 0; e < En; e++) {
            offsets[e] = o; o += counts[e];
            float pm = (red[0][e] + red[1][e] + red[2][e] + red[3][e]) * (1.0f / Tt);
            float fr = (float)counts[e] * (1.0f / (Tt * 2));
            bl += fr * pm;
        }
        loss_out[0] = 0.01f * (float)En * bl;
    }
}

extern "C" void kernel_launch(void* const* d_in, const int* in_sizes, int n_in,
                              void* d_out, int out_size, void* d_ws, size_t ws_size,
                              hipStream_t stream)
{
    (void)in_sizes; (void)n_in; (void)out_size; (void)ws_size;
    const float* hs  = (const float*)d_in[0];
    const float* ln1 = (const float*)d_in[1];
    const float* wq  = (const float*)d_in[2];
    const float* wk  = (const float*)d_in[3];
    const float* wv  = (const float*)d_in[4];
    const float* wo  = (const float*)d_in[5];
    const float* ln2 = (const float*)d_in[6];
    const float* rw  = (const float*)d_in[7];
    const float* wg  = (const float*)d_in[8];
    const float* wu  = (const float*)d_in[9];
    const float* wd  = (const float*)d_in[10];
    float* out = (float*)d_out;

    char* ws = (char*)d_ws;
    size_t off = 0;
    auto nxt = [&](size_t bytes) { char* p = ws + off; off += (bytes + 255) & ~(size_t)255; return p; };
    // ---- persistent (MoE-era) region ----
    u16* wgt  = (u16*)nxt((size_t)En * Fn * Dd * 2);
    u16* wut  = (u16*)nxt((size_t)En * Fn * Dd * 2);
    u16* wdt  = (u16*)nxt((size_t)En * Dd * Fn * 2);
    float* h2 = (float*)nxt((size_t)Tt * Dd * 4);
    u16* h2b  = (u16*)nxt((size_t)Tt * Dd * 2);
    float* probs = (float*)nxt((size_t)Tt * En * 4);
    int*   tokl  = (int*)nxt((size_t)En * Tt * 4);
    float* gwl   = (float*)nxt((size_t)En * Tt * 4);
    float* ctab  = (float*)nxt((size_t)Ss * 32 * 4);
    float* stab  = (float*)nxt((size_t)Ss * 32 * 4);
    int* counts  = (int*)nxt(256);
    int* offs    = (int*)nxt(256);
    // ---- transient (pre-MoE) region; `act` aliases it ----
    u16* act = (u16*)(ws + off);
    float* qkv = (float*)nxt((size_t)Tt * 1536 * 4);
    u16* h1hi = (u16*)nxt((size_t)Tt * Dd * 2);
    u16* h1lo = (u16*)nxt((size_t)Tt * Dd * 2);
    u16* khi  = (u16*)nxt((size_t)Tt * KVHn * HDn * 2);
    u16* klo  = (u16*)nxt((size_t)Tt * KVHn * HDn * 2);
    u16* vthi = (u16*)nxt((size_t)Tt * KVHn * HDn * 2);
    u16* vtlo = (u16*)nxt((size_t)Tt * KVHn * HDn * 2);
    u16* chi  = (u16*)nxt((size_t)Tt * Dd * 2);
    u16* clo  = (u16*)nxt((size_t)Tt * Dd * 2);
    u16* wqkvthi = (u16*)nxt((size_t)1536 * Dd * 2);
    u16* wqkvtlo = (u16*)nxt((size_t)1536 * Dd * 2);
    u16* wothi = (u16*)nxt((size_t)Dd * Dd * 2);
    u16* wotlo = (u16*)nxt((size_t)Dd * Dd * 2);

    rope_tab_k<<<dim3(256), 256, 0, stream>>>(ctab, stab);
    // weight prep
    tconv_k<true ><<<dim3(16 * 16), 256, 0, stream>>>(wq, wqkvthi, wqkvtlo, 1024, 1024,    0, 16);
    tconv_k<true ><<<dim3(16 *  4), 256, 0, stream>>>(wk, wqkvthi, wqkvtlo, 1024,  256, 1024,  4);
    tconv_k<true ><<<dim3(16 *  4), 256, 0, stream>>>(wv, wqkvthi, wqkvtlo, 1024,  256, 1280,  4);
    tconv_k<true ><<<dim3(16 * 16), 256, 0, stream>>>(wo, wothi, wotlo, 1024, 1024, 0, 16);
    tprep_k<32, false><<<dim3(32 * 32, En), 256, 0, stream>>>(wg, wgt, 1024, 4096, 32);
    tprep_k<32, false><<<dim3(32 * 32, En), 256, 0, stream>>>(wu, wut, 1024, 4096, 32);
    tprep_k<32, false><<<dim3(8 * 128, En), 256, 0, stream>>>(wd, wdt, 4096, 1024, 8);

    rmsnorm_split_k<<<dim3(Tt), 256, 0, stream>>>(hs, ln1, h1hi, h1lo);
    gemm_split_k<false><<<dim3(12 * 32), 256, 0, stream>>>(h1hi, h1lo, wqkvthi, wqkvtlo,
                                                           qkv, nullptr, Tt, 1536, Dd, 12);
    rope_q_k<<<dim3(Tt * Hh * 32 / 256), 256, 0, stream>>>(qkv, ctab, stab);
    kprep_k<<<dim3(Tt * KVHn * 32 / 256), 256, 0, stream>>>(qkv, ctab, stab, khi, klo);
    vprep_k<<<dim3(Ss / 64, Bb * KVHn), 256, 0, stream>>>(qkv, vthi, vtlo);
    attn_k<<<dim3(Ss / 64, Hh, Bb), 256, 0, stream>>>(qkv, khi, klo, vthi, vtlo, chi, clo);
    gemm_split_k<true><<<dim3(8 * 32), 256, 0, stream>>>(chi, clo, wothi, wotlo,
                                                         out, hs, Tt, Dd, Dd, 8);
    rmsnorm2_k<<<dim3(Tt), 256, 0, stream>>>(out, ln2, h2, h2b);
    (void)hipMemsetAsync(counts, 0, 64, stream);
    router_k<<<dim3(Tt), 256, 0, stream>>>(h2, rw, probs, counts, tokl, gwl);
    finalize_k<<<dim3(1), 256, 0, stream>>>(probs, counts, offs, out + (size_t)Tt * Dd);
    // MoE: gate -> act ; up (in-place silu(g)*u*gw) ; down scatter-add
    gemm_expert_k<0><<<dim3(32 * 32, En), 256, 0, stream>>>(h2b, wgt, act, tokl, gwl, counts, offs);
    gemm_expert_k<1><<<dim3(32 * 32, En), 256, 0, stream>>>(h2b, wut, act, tokl, gwl, counts, offs);
    gemm_down_k<<<dim3(8 * 32, En), 256, 0, stream>>>(act, wdt, out, tokl, counts, offs);
}

// Round 18
// 868.589 us; speedup vs baseline: 1.3587x; 1.0335x over previous
//
#include <hip/hip_runtime.h>

#define Tt 4096
#define Bb 2
#define Ss 2048
#define Dd 1024
#define Hh 16
#define KVHn 4
#define HDn 64
#define En 8
#define Fn 4096

#define BM 128
#define BN 128

typedef unsigned short u16;
typedef __attribute__((ext_vector_type(4))) float f32x4;
typedef __attribute__((ext_vector_type(8))) short bfrag;
typedef __attribute__((ext_vector_type(4))) short s16x4;

#define WAITV(N) asm volatile("s_waitcnt vmcnt(" #N ")" ::: "memory")
#define BARRIER() asm volatile("s_barrier" ::: "memory")

__device__ __forceinline__ u16 f2bf(float f) {
    unsigned u = __builtin_bit_cast(unsigned, f);
    u = (u + 0x7fffu + ((u >> 16) & 1u)) >> 16;
    return (u16)u;
}
__device__ __forceinline__ float bf2f(u16 b) {
    unsigned u = ((unsigned)b) << 16;
    return __builtin_bit_cast(float, u);
}
__device__ __forceinline__ void split8a(const float* va, bfrag* ph, bfrag* pl) {
    bfrag th, tl;
#pragma unroll
    for (int j = 0; j < 8; j++) {
        u16 hu = f2bf(va[j]);
        th[j] = (short)hu;
        tl[j] = (short)f2bf(va[j] - bf2f(hu));
    }
    *ph = th; *pl = tl;
}
// async global->LDS, 16B per lane; LDS dest = wave-uniform base + lane*16, global src per-lane
__device__ __forceinline__ void glds16(const void* g, void* l) {
    __builtin_amdgcn_global_load_lds(
        (const __attribute__((address_space(1))) unsigned int*)g,
        (__attribute__((address_space(3))) unsigned int*)l, 16, 0, 0);
}

// ---------- transpose + bf16 convert (hi/lo split) for QKV/WO weights: [K][N] -> [N][K] ----------
template<bool SPL>
__global__ __launch_bounds__(256)
void tconv_k(const float* __restrict__ src, u16* __restrict__ dhi, u16* __restrict__ dlo,
             const int K, const int N, const int rowOff, const int nTilesN)
{
    const int tid = threadIdx.x;
    const int ty = blockIdx.x / nTilesN, tx = blockIdx.x % nTilesN;
    const int k0 = ty * 64, n0 = tx * 64;
    __shared__ float tl[64][65];
#pragma unroll
    for (int it = 0; it < 16; it++) {
        int idx = tid + it * 256;
        int kk = idx >> 6, nn = idx & 63;
        tl[kk][nn] = src[(size_t)(k0 + kk) * N + n0 + nn];
    }
    __syncthreads();
#pragma unroll
    for (int it = 0; it < 8; it++) {
        int idx = tid + it * 256;
        int n = idx >> 5, k2 = (idx & 31) * 2;
        float v0 = tl[k2][n], v1 = tl[k2 + 1][n];
        u16 h0 = f2bf(v0), h1v = f2bf(v1);
        size_t o = (size_t)(rowOff + n0 + n) * K + k0 + k2;
        *(unsigned*)&dhi[o] = (unsigned)h0 | ((unsigned)h1v << 16);
        if (SPL) {
            u16 l0 = f2bf(v0 - bf2f(h0)), l1 = f2bf(v1 - bf2f(h1v));
            *(unsigned*)&dlo[o] = (unsigned)l0 | ((unsigned)l1 << 16);
        }
    }
}

// ---------- MoE weight prep: f32 [K][N] -> tiled bf16 blocks [nt][kt][128n x TBK k] ----------
template<int TBK, bool SWZ>
__global__ __launch_bounds__(256)
void tprep_k(const float* __restrict__ src, u16* __restrict__ dst,
             const int K, const int N, const int nTilesN)
{
    const int tid = threadIdx.x;
    const int e = blockIdx.y;
    const int ntl = blockIdx.x % nTilesN, kt = blockIdx.x / nTilesN;
    const int nTK = K / TBK;
    src += (size_t)e * K * N + (size_t)(kt * TBK) * N + ntl * 128;
    u16* dblk = dst + (((size_t)e * nTilesN + ntl) * nTK + kt) * (size_t)(128 * TBK);
    __shared__ float tl[TBK][132];
#pragma unroll
    for (int it = 0; it < TBK / 8; it++) {
        int i4 = tid + it * 256;
        int kk = i4 >> 5, n = (i4 & 31) * 4;
        f32x4 v = *(const f32x4*)(src + (size_t)kk * N + n);
        tl[kk][n] = v.x; tl[kk][n + 1] = v.y; tl[kk][n + 2] = v.z; tl[kk][n + 3] = v.w;
    }
    __syncthreads();
#pragma unroll
    for (int it = 0; it < TBK / 16; it++) {
        int idx = tid + it * 256;
        int n = (TBK == 32) ? (idx >> 2) : (idx >> 3);
        int c = (TBK == 32) ? (idx & 3) : (idx & 7);
        bfrag v;
#pragma unroll
        for (int j = 0; j < 8; j++) v[j] = (short)f2bf(tl[c * 8 + j][n]);
        int boff = n * (TBK * 2) + ((c * 16) ^ (SWZ ? ((n & 7) << 4) : 0));
        *(bfrag*)((char*)dblk + boff) = v;
    }
}

// ---------- RMSNorm -> split bf16 (hi/lo) ----------
__global__ __launch_bounds__(256)
void rmsnorm_split_k(const float* __restrict__ x, const float* __restrict__ w,
                     u16* __restrict__ ohi, u16* __restrict__ olo)
{
    const int row = blockIdx.x;
    const int tid = threadIdx.x;
    const int lane = tid & 63, wid = tid >> 6;
    f32x4 t4 = *(const f32x4*)(x + (size_t)row * Dd + tid * 4);
    float s = t4.x*t4.x + t4.y*t4.y + t4.z*t4.z + t4.w*t4.w;
#pragma unroll
    for (int o = 1; o < 64; o <<= 1) s += __shfl_xor(s, o, 64);
    __shared__ float red[4];
    if (lane == 0) red[wid] = s;
    __syncthreads();
    float inv = rsqrtf((red[0] + red[1] + red[2] + red[3]) * (1.0f / Dd) + 1e-6f);
    f32x4 w4 = *(const f32x4*)(w + tid * 4);
    float va[4] = { t4.x*inv*w4.x, t4.y*inv*w4.y, t4.z*inv*w4.z, t4.w*inv*w4.w };
    s16x4 hi, lo;
#pragma unroll
    for (int j = 0; j < 4; j++) {
        u16 hu = f2bf(va[j]);
        hi[j] = (short)hu;
        lo[j] = (short)f2bf(va[j] - bf2f(hu));
    }
    *(s16x4*)&ohi[(size_t)row * Dd + tid * 4] = hi;
    *(s16x4*)&olo[(size_t)row * Dd + tid * 4] = lo;
}

// ---------- RMSNorm -> f32 (router) + rounded bf16 (MoE A) ----------
__global__ __launch_bounds__(256)
void rmsnorm2_k(const float* __restrict__ x, const float* __restrict__ w,
                float* __restrict__ of, u16* __restrict__ ob)
{
    const int row = blockIdx.x;
    const int tid = threadIdx.x;
    const int lane = tid & 63, wid = tid >> 6;
    f32x4 t4 = *(const f32x4*)(x + (size_t)row * Dd + tid * 4);
    float s = t4.x*t4.x + t4.y*t4.y + t4.z*t4.z + t4.w*t4.w;
#pragma unroll
    for (int o = 1; o < 64; o <<= 1) s += __shfl_xor(s, o, 64);
    __shared__ float red[4];
    if (lane == 0) red[wid] = s;
    __syncthreads();
    float inv = rsqrtf((red[0] + red[1] + red[2] + red[3]) * (1.0f / Dd) + 1e-6f);
    f32x4 w4 = *(const f32x4*)(w + tid * 4);
    f32x4 o4;
    o4.x = t4.x*inv*w4.x; o4.y = t4.y*inv*w4.y; o4.z = t4.z*inv*w4.z; o4.w = t4.w*inv*w4.w;
    *(f32x4*)&of[(size_t)row * Dd + tid * 4] = o4;
    s16x4 hb;
    hb[0] = (short)f2bf(o4.x); hb[1] = (short)f2bf(o4.y);
    hb[2] = (short)f2bf(o4.z); hb[3] = (short)f2bf(o4.w);
    *(s16x4*)&ob[(size_t)row * Dd + tid * 4] = hb;
}

// ---------- RoPE tables (f64) ----------
__global__ __launch_bounds__(256)
void rope_tab_k(float* __restrict__ ct, float* __restrict__ st)
{
    int idx = blockIdx.x * 256 + threadIdx.x;
    if (idx < Ss * 32) {
        int s = idx >> 5, i = idx & 31;
        double inv = pow(10000.0, -((double)(2 * i)) / 64.0);
        double a = (double)s * inv;
        double sn, cs;
        sincos(a, &sn, &cs);
        ct[idx] = (float)cs;
        st[idx] = (float)sn;
    }
}

// ---------- RoPE on Q (in-place, qkv stride 1536) ----------
__global__ __launch_bounds__(256)
void rope_q_k(float* __restrict__ qkv, const float* __restrict__ ct, const float* __restrict__ st)
{
    int idx = blockIdx.x * 256 + threadIdx.x;
    int i = idx & 31, hh = (idx >> 5) & (Hh - 1), t = idx >> 9;
    int s = t & (Ss - 1);
    float cs = ct[s * 32 + i], sn = st[s * 32 + i];
    float* base = qkv + (size_t)t * 1536 + hh * 64 + i;
    float x1 = base[0], x2 = base[32];
    base[0]  = x1 * cs - x2 * sn;
    base[32] = x2 * cs + x1 * sn;
}

// ---------- K: RoPE + split bf16 ----------
__global__ __launch_bounds__(256)
void kprep_k(const float* __restrict__ qkv, const float* __restrict__ ct,
             const float* __restrict__ st, u16* __restrict__ khi, u16* __restrict__ klo)
{
    int idx = blockIdx.x * 256 + threadIdx.x;
    int i = idx & 31, hh = (idx >> 5) & (KVHn - 1), t = idx >> 7;
    int s = t & (Ss - 1);
    float cs = ct[s * 32 + i], sn = st[s * 32 + i];
    const float* base = qkv + (size_t)t * 1536 + 1024 + hh * 64 + i;
    float x1 = base[0], x2 = base[32];
    float r1 = x1 * cs - x2 * sn, r2 = x2 * cs + x1 * sn;
    size_t o = (size_t)t * (KVHn * HDn) + hh * 64 + i;
    u16 h1v = f2bf(r1), h2v = f2bf(r2);
    khi[o] = h1v;       khi[o + 32] = h2v;
    klo[o] = f2bf(r1 - bf2f(h1v));
    klo[o + 32] = f2bf(r2 - bf2f(h2v));
}

// ---------- V: transpose + split ----------
__global__ __launch_bounds__(256)
void vprep_k(const float* __restrict__ qkv, u16* __restrict__ vthi, u16* __restrict__ vtlo)
{
    const int st0 = blockIdx.x * 64;
    const int g = blockIdx.y;
    const int b = g >> 2, kvh = g & 3;
    const int tid = threadIdx.x;
    __shared__ float tl[64][65];
#pragma unroll
    for (int it = 0; it < 16; it++) {
        int idx = tid + it * 256;
        int sl = idx >> 6, d = idx & 63;
        tl[sl][d] = qkv[(size_t)(b * Ss + st0 + sl) * 1536 + 1280 + kvh * 64 + d];
    }
    __syncthreads();
#pragma unroll
    for (int it = 0; it < 8; it++) {
        int idx = tid + it * 256;
        int d = idx >> 5, s2 = (idx & 31) * 2;
        float v0 = tl[s2][d], v1 = tl[s2 + 1][d];
        u16 h0 = f2bf(v0), h1v = f2bf(v1);
        size_t o = ((size_t)g * 64 + d) * Ss + st0 + s2;
        *(unsigned*)&vthi[o] = (unsigned)h0 | ((unsigned)h1v << 16);
        u16 l0 = f2bf(v0 - bf2f(h0)), l1 = f2bf(v1 - bf2f(h1v));
        *(unsigned*)&vtlo[o] = (unsigned)l0 | ((unsigned)l1 << 16);
    }
}

// ---------- split-bf16x3 GEMM (glds + dbuf + counted vmcnt): C = A@B^T(+resid) ----------
template<bool RESID>
__global__ __launch_bounds__(256)
void gemm_split_k(const u16* __restrict__ Ahi_g, const u16* __restrict__ Alo_g,
                  const u16* __restrict__ Bhi_g, const u16* __restrict__ Blo_g,
                  float* __restrict__ C, const float* __restrict__ resid,
                  const int M, const int N, const int K, const int ntiles)
{
    const int bid = blockIdx.x;
    const int nt = bid % ntiles, mt = bid / ntiles;
    __shared__ __align__(16) u16 Ah[2][128 * 32], Al[2][128 * 32];
    __shared__ __align__(16) u16 Bh[2][128 * 32], Bl[2][128 * 32];   // 64 KB
    const int tid = threadIdx.x, lane = tid & 63, wid = tid >> 6;
    const int wrow = (wid >> 1) * 64, wcol = (wid & 1) * 64;
    const int l15 = lane & 15, lhi = lane >> 4;
    const int row0 = mt * BM, col0 = nt * BN;

    const u16 *ah_s[2], *al_s[2], *bh_s[2], *bl_s[2];
#pragma unroll
    for (int j = 0; j < 2; j++) {
        int r = (wid * 2 + j) * 16 + (lane >> 2);
        size_t ca = (size_t)(row0 + r) * K + (lane & 3) * 8;
        size_t cb = (size_t)(col0 + r) * K + (lane & 3) * 8;
        ah_s[j] = Ahi_g + ca; al_s[j] = Alo_g + ca;
        bh_s[j] = Bhi_g + cb; bl_s[j] = Blo_g + cb;
    }
    f32x4 acc[4][4];
#pragma unroll
    for (int i = 0; i < 4; i++)
#pragma unroll
        for (int j = 0; j < 4; j++) { acc[i][j].x = 0.f; acc[i][j].y = 0.f; acc[i][j].z = 0.f; acc[i][j].w = 0.f; }

    auto stage = [&](int buf, int k0) {
#pragma unroll
        for (int j = 0; j < 2; j++) {
            int d = (wid * 2 + j) * 512;
            glds16(ah_s[j] + k0, &Ah[buf][d]);
            glds16(al_s[j] + k0, &Al[buf][d]);
            glds16(bh_s[j] + k0, &Bh[buf][d]);
            glds16(bl_s[j] + k0, &Bl[buf][d]);
        }
    };
    auto compute = [&](int cur) {
        bfrag ah[4], al[4], bh[4], bl[4];
#pragma unroll
        for (int mi = 0; mi < 4; mi++) {
            int rb = (wrow + mi * 16 + l15) * 32 + lhi * 8;
            ah[mi] = *(const bfrag*)&Ah[cur][rb];
            al[mi] = *(const bfrag*)&Al[cur][rb];
        }
#pragma unroll
        for (int ni = 0; ni < 4; ni++) {
            int rb = (wcol + ni * 16 + l15) * 32 + lhi * 8;
            bh[ni] = *(const bfrag*)&Bh[cur][rb];
            bl[ni] = *(const bfrag*)&Bl[cur][rb];
        }
#pragma unroll
        for (int mi = 0; mi < 4; mi++)
#pragma unroll
            for (int ni = 0; ni < 4; ni++) {
                acc[mi][ni] = __builtin_amdgcn_mfma_f32_16x16x32_bf16(ah[mi], bh[ni], acc[mi][ni], 0, 0, 0);
                acc[mi][ni] = __builtin_amdgcn_mfma_f32_16x16x32_bf16(ah[mi], bl[ni], acc[mi][ni], 0, 0, 0);
                acc[mi][ni] = __builtin_amdgcn_mfma_f32_16x16x32_bf16(al[mi], bh[ni], acc[mi][ni], 0, 0, 0);
            }
    };
    const int nkt = K / 32;
    stage(0, 0);
    stage(1, 32);
    int cur = 0;
    for (int kt = 0; kt < nkt - 1; kt++) {
        WAITV(8);       // own tile-kt loads done; kt+1 still in flight
        BARRIER();
        compute(cur);
        BARRIER();
        if (kt + 2 < nkt) stage(cur, (kt + 2) * 32);
        cur ^= 1;
    }
    WAITV(0);
    BARRIER();
    compute(cur);
#pragma unroll
    for (int mi = 0; mi < 4; mi++) {
#pragma unroll
        for (int t = 0; t < 4; t++) {
            int pr = row0 + wrow + mi * 16 + lhi * 4 + t;
#pragma unroll
            for (int ni = 0; ni < 4; ni++) {
                int gc = col0 + wcol + ni * 16 + l15;
                float vv = acc[mi][ni][t];
                if (RESID) vv += resid[(size_t)pr * N + gc];
                C[(size_t)pr * N + gc] = vv;
            }
        }
    }
}

// ---------- MoE expert GEMM (single output): glds + dbuf + counted vmcnt, BK=32 ----------
// MODE 0 (gate): act[ix] = bf16(acc)
// MODE 1 (up):   g = act[ix]; act[ix] = bf16(silu(g) * acc * gw)   [in-place, same thread owns ix]
template<int MODE>
__global__ __launch_bounds__(256, 4)
void gemm_expert_k(const u16* __restrict__ A_g, const u16* __restrict__ Bt,
                   u16* __restrict__ act,
                   const int* __restrict__ toklist, const float* __restrict__ gwlist,
                   const int* __restrict__ counts, const int* __restrict__ offsets)
{
    const int e = blockIdx.y;
    const int Meff = counts[e];
    const int nt = blockIdx.x & 31, mt = blockIdx.x >> 5;
    if (mt * BM >= Meff) return;
    const int* tok = toklist + e * Tt;
    const float* gw = gwlist + e * Tt;
    const int rowoff = offsets[e];
    __shared__ __align__(16) u16 As[2][128 * 32], Bs[2][128 * 32];   // 32 KB
    const int tid = threadIdx.x, lane = tid & 63, wid = tid >> 6;
    const int wrow = (wid >> 1) * 64, wcol = (wid & 1) * 64;
    const int l15 = lane & 15, lhi = lane >> 4;
    const int row0 = mt * BM, col0 = nt * BN;

    const u16* asrc[2];
#pragma unroll
    for (int j = 0; j < 2; j++) {
        int row = (wid * 2 + j) * 16 + (lane >> 2);
        int pr = row0 + row;
        int tr = (pr < Meff) ? tok[pr] : tok[0];
        asrc[j] = A_g + (size_t)tr * Dd + (lane & 3) * 8;
    }
    const size_t bblk = (size_t)(e * 32 + nt) * (32 * 4096);
    const u16* bsrc = Bt + bblk + (size_t)(wid * 2) * 512 + lane * 8;

    f32x4 acc[4][4];
#pragma unroll
    for (int i = 0; i < 4; i++)
#pragma unroll
        for (int j = 0; j < 4; j++) { acc[i][j].x = 0.f; acc[i][j].y = 0.f; acc[i][j].z = 0.f; acc[i][j].w = 0.f; }

    auto stage = [&](int buf, int kt) {
#pragma unroll
        for (int j = 0; j < 2; j++) {
            int d = (wid * 2 + j) * 512;
            glds16(asrc[j] + kt * 32,                  &As[buf][d]);
            glds16(bsrc + j * 512 + (size_t)kt * 4096, &Bs[buf][d]);
        }
    };
    auto compute = [&](int cur) {
        bfrag a[4];
#pragma unroll
        for (int mi = 0; mi < 4; mi++)
            a[mi] = *(const bfrag*)&As[cur][(wrow + mi * 16 + l15) * 32 + lhi * 8];
#pragma unroll
        for (int ni = 0; ni < 4; ni++) {
            bfrag b = *(const bfrag*)&Bs[cur][(wcol + ni * 16 + l15) * 32 + lhi * 8];
#pragma unroll
            for (int mi = 0; mi < 4; mi++)
                acc[mi][ni] = __builtin_amdgcn_mfma_f32_16x16x32_bf16(a[mi], b, acc[mi][ni], 0, 0, 0);
        }
    };
    stage(0, 0);
    stage(1, 1);
    int cur = 0;
    for (int kt = 0; kt < 31; kt++) {
        WAITV(4);
        BARRIER();
        compute(cur);
        BARRIER();
        if (kt + 2 < 32) stage(cur, kt + 2);
        cur ^= 1;
    }
    WAITV(0);
    BARRIER();
    compute(cur);
#pragma unroll
    for (int mi = 0; mi < 4; mi++) {
#pragma unroll
        for (int t = 0; t < 4; t++) {
            int pr = row0 + wrow + mi * 16 + lhi * 4 + t;
            if (pr < Meff) {
                float gwv = (MODE == 1) ? gw[pr] : 0.f;
#pragma unroll
                for (int ni = 0; ni < 4; ni++) {
                    int gc = col0 + wcol + ni * 16 + l15;
                    size_t ix = (size_t)(rowoff + pr) * Fn + gc;
                    if (MODE == 0) {
                        act[ix] = f2bf(acc[mi][ni][t]);
                    } else {
                        float g = bf2f(act[ix]);
                        float sg = g / (1.0f + expf(-g));
                        act[ix] = f2bf(sg * acc[mi][ni][t] * gwv);
                    }
                }
            }
        }
    }
}

// ---------- MoE down (glds + dbuf + counted vmcnt, BK=32): out[tok] += act @ Wd^T ----------
__global__ __launch_bounds__(256, 4)
void gemm_down_k(const u16* __restrict__ act, const u16* __restrict__ Bt,
                 float* __restrict__ C, const int* __restrict__ toklist,
                 const int* __restrict__ counts, const int* __restrict__ offsets)
{
    const int e = blockIdx.y;
    const int Meff = counts[e];
    const int nt = blockIdx.x & 7, mt = blockIdx.x >> 3;
    if (mt * BM >= Meff) return;
    const int* tok = toklist + e * Tt;
    const int rowoff = offsets[e];
    __shared__ __align__(16) u16 As[2][128 * 32], Bs[2][128 * 32];   // 32 KB
    const int tid = threadIdx.x, lane = tid & 63, wid = tid >> 6;
    const int wrow = (wid >> 1) * 64, wcol = (wid & 1) * 64;
    const int l15 = lane & 15, lhi = lane >> 4;
    const int row0 = mt * BM;

    const u16* asrc[2];
#pragma unroll
    for (int j = 0; j < 2; j++) {
        int row = (wid * 2 + j) * 16 + (lane >> 2);
        int pr = row0 + row;
        int rr = (pr < Meff) ? pr : 0;
        asrc[j] = act + (size_t)(rowoff + rr) * Fn + (lane & 3) * 8;
    }
    const size_t bblk = (size_t)(e * 8 + nt) * ((size_t)128 * 4096);
    const u16* bsrc = Bt + bblk + (size_t)(wid * 2) * 512 + lane * 8;

    f32x4 acc[4][4];
#pragma unroll
    for (int i = 0; i < 4; i++)
#pragma unroll
        for (int j = 0; j < 4; j++) { acc[i][j].x = 0.f; acc[i][j].y = 0.f; acc[i][j].z = 0.f; acc[i][j].w = 0.f; }

    auto stage = [&](int buf, int kt) {
#pragma unroll
        for (int j = 0; j < 2; j++) {
            int d = (wid * 2 + j) * 512;
            glds16(asrc[j] + kt * 32,                  &As[buf][d]);
            glds16(bsrc + j * 512 + (size_t)kt * 4096, &Bs[buf][d]);
        }
    };
    auto compute = [&](int cur) {
        bfrag a[4];
#pragma unroll
        for (int mi = 0; mi < 4; mi++)
            a[mi] = *(const bfrag*)&As[cur][(wrow + mi * 16 + l15) * 32 + lhi * 8];
#pragma unroll
        for (int ni = 0; ni < 4; ni++) {
            bfrag b = *(const bfrag*)&Bs[cur][(wcol + ni * 16 + l15) * 32 + lhi * 8];
#pragma unroll
            for (int mi = 0; mi < 4; mi++)
                acc[mi][ni] = __builtin_amdgcn_mfma_f32_16x16x32_bf16(a[mi], b, acc[mi][ni], 0, 0, 0);
        }
    };
    stage(0, 0);
    stage(1, 1);
    int cur = 0;
    const int nkt = Fn / 32;   // 128
    for (int kt = 0; kt < nkt - 1; kt++) {
        WAITV(4);
        BARRIER();
        compute(cur);
        BARRIER();
        if (kt + 2 < nkt) stage(cur, kt + 2);
        cur ^= 1;
    }
    WAITV(0);
    BARRIER();
    compute(cur);
#pragma unroll
    for (int mi = 0; mi < 4; mi++) {
#pragma unroll
        for (int t = 0; t < 4; t++) {
            int pr = row0 + wrow + mi * 16 + lhi * 4 + t;
            if (pr < Meff) {
                int trow = tok[pr];
#pragma unroll
                for (int ni = 0; ni < 4; ni++) {
                    int gc = nt * BN + wcol + ni * 16 + l15;
                    atomicAdd(&C[(size_t)trow * Dd + gc], acc[mi][ni][t]);
                }
            }
        }
    }
}

// ---------- Flash attention (causal GQA), split-bf16x3, 128-row Q tile, 8 waves ----------
// Swapped QK^T/PV; K,V,P all XOR-swizzled stride-64 LDS (exactly 64 KB total).
__global__ __launch_bounds__(512)
void attn_k(const float* __restrict__ qkv, const u16* __restrict__ khi,
            const u16* __restrict__ klo, const u16* __restrict__ vthi,
            const u16* __restrict__ vtlo, u16* __restrict__ chi, u16* __restrict__ clo)
{
    const int qb = (int)gridDim.x - 1 - (int)blockIdx.x;   // 0..15, longest first
    const int h = blockIdx.y, b = blockIdx.z;
    const int kvh = h >> 2;
    const int g = b * KVHn + kvh;
    const int tid = threadIdx.x;
    const int lane = tid & 63, wid = tid >> 6;             // wid 0..7
    const int l15 = lane & 15, lhi = lane >> 4;

    __shared__ __align__(16) u16 Khi_s[64 * 64];
    __shared__ __align__(16) u16 Klo_s[64 * 64];
    __shared__ __align__(16) u16 Vhi_s[64 * 64];
    __shared__ __align__(16) u16 Vlo_s[64 * 64];
    __shared__ __align__(16) u16 Phi[128 * 64];
    __shared__ __align__(16) u16 Plo[128 * 64];            // total 65536 B

    const int qrow_g = qb * 128 + wid * 16 + l15;          // this lane's q row (swapped layout)
    bfrag qh[2], ql[2];
    {
        const float* qb_p = qkv + (size_t)(b * Ss + qrow_g) * 1536 + h * 64;
#pragma unroll
        for (int ks = 0; ks < 2; ks++) {
            const float* p = qb_p + ks * 32 + lhi * 8;
            f32x4 u0 = *(const f32x4*)p;
            f32x4 u1 = *(const f32x4*)(p + 4);
            float va[8] = { u0.x * 0.125f, u0.y * 0.125f, u0.z * 0.125f, u0.w * 0.125f,
                            u1.x * 0.125f, u1.y * 0.125f, u1.z * 0.125f, u1.w * 0.125f };
            split8a(va, &qh[ks], &ql[ks]);
        }
    }
    // staging geometry: 512 threads, one 16B chunk each; row = tid>>3, col elems = (tid&7)*8
    const int srow = tid >> 3, scol = (tid & 7) << 3;
    const size_t kga0 = (size_t)(b * Ss + srow) * (KVHn * HDn) + kvh * 64 + scol;
    const int kboff = srow * 128 + ((scol * 2) ^ ((srow & 7) << 4));
    const size_t vga0 = ((size_t)g * 64 + srow) * Ss + scol;   // V: row=d, col=kv
    const int vboff = srow * 128 + ((scol * 2) ^ ((srow & 7) << 4));

    bfrag rkh, rkl, rvh, rvl;
    auto LOADR = [&](int kt) {
        size_t ka = kga0 + (size_t)kt * (64 * KVHn * HDn);
        rkh = *(const bfrag*)&khi[ka];
        rkl = *(const bfrag*)&klo[ka];
        size_t va = vga0 + (size_t)kt * 64;
        rvh = *(const bfrag*)&vthi[va];
        rvl = *(const bfrag*)&vtlo[va];
    };
    f32x4 O[4];   // O^T: O[ni][t] = O^T[d = ni*16+lhi*4+t][q = qrow_g]
#pragma unroll
    for (int ni = 0; ni < 4; ni++) { O[ni].x = 0.f; O[ni].y = 0.f; O[ni].z = 0.f; O[ni].w = 0.f; }
    float m_s = -1e30f;
    float l_s = 0.f;

    const int nkt = 2 * qb + 2;
    LOADR(0);
    for (int kt = 0; kt < nkt; kt++) {
        // ---- write prefetched K/V regs to LDS (swizzled) ----
        *(bfrag*)((char*)Khi_s + kboff) = rkh;
        *(bfrag*)((char*)Klo_s + kboff) = rkl;
        *(bfrag*)((char*)Vhi_s + vboff) = rvh;
        *(bfrag*)((char*)Vlo_s + vboff) = rvl;
        __syncthreads();
        if (kt + 1 < nkt) LOADR(kt + 1);
        // ---- S^T = K Q^T (3-pass split): sf[ni][t] = S[kv = ni*16+lhi*4+t][q = qrow_g] ----
        f32x4 sf[4];
#pragma unroll
        for (int ni = 0; ni < 4; ni++) { sf[ni].x = 0.f; sf[ni].y = 0.f; sf[ni].z = 0.f; sf[ni].w = 0.f; }
        __builtin_amdgcn_s_setprio(1);
#pragma unroll
        for (int ks = 0; ks < 2; ks++) {
#pragma unroll
            for (int ni = 0; ni < 4; ni++) {
                int kv = ni * 16 + l15;
                int dof = ks * 64 + lhi * 16;
                int boff = kv * 128 + (dof ^ ((kv & 7) << 4));
                bfrag kfh = *(const bfrag*)((const char*)Khi_s + boff);
                bfrag kfl = *(const bfrag*)((const char*)Klo_s + boff);
                sf[ni] = __builtin_amdgcn_mfma_f32_16x16x32_bf16(kfh, qh[ks], sf[ni], 0, 0, 0);
                sf[ni] = __builtin_amdgcn_mfma_f32_16x16x32_bf16(kfl, qh[ks], sf[ni], 0, 0, 0);
                sf[ni] = __builtin_amdgcn_mfma_f32_16x16x32_bf16(kfh, ql[ks], sf[ni], 0, 0, 0);
            }
        }
        __builtin_amdgcn_s_setprio(0);
        // ---- causal mask (last two kv-tiles), global coords ----
        if (kt >= 2 * qb) {
#pragma unroll
            for (int ni = 0; ni < 4; ni++)
#pragma unroll
                for (int t = 0; t < 4; t++)
                    if (kt * 64 + ni * 16 + lhi * 4 + t > qrow_g) sf[ni][t] = -1e30f;
        }
        // ---- lane-local softmax ----
        float mx = -1e30f;
#pragma unroll
        for (int ni = 0; ni < 4; ni++)
#pragma unroll
            for (int t = 0; t < 4; t++) mx = fmaxf(mx, sf[ni][t]);
        mx = fmaxf(mx, __shfl_xor(mx, 16, 64));
        mx = fmaxf(mx, __shfl_xor(mx, 32, 64));
        float mn = fmaxf(m_s, mx);
        float sc = expf(m_s - mn);
        m_s = mn;
        float rs = 0.f;
#pragma unroll
        for (int ni = 0; ni < 4; ni++)
#pragma unroll
            for (int t = 0; t < 4; t++) {
                float p = expf(sf[ni][t] - mn);
                sf[ni][t] = p;
                rs += p;
            }
        rs += __shfl_xor(rs, 16, 64);
        rs += __shfl_xor(rs, 32, 64);
        l_s = l_s * sc + rs;
        // ---- O^T rescale (lane-local) ----
#pragma unroll
        for (int ni = 0; ni < 4; ni++)
#pragma unroll
            for (int t = 0; t < 4; t++) O[ni][t] *= sc;
        // ---- P write: row = q = wid*16+l15 (0..127), col = kv = ni*16+lhi*4+t, swizzled ----
        {
            int pr = wid * 16 + l15;
            int prx = (pr & 7) << 4;
#pragma unroll
            for (int ni = 0; ni < 4; ni++)
#pragma unroll
                for (int t = 0; t < 4; t++) {
                    float p = sf[ni][t];
                    u16 hu = f2bf(p);
                    int cb = (ni * 32 + lhi * 8 + t * 2) ^ prx;
                    int ixb = pr * 128 + cb;
                    *(u16*)((char*)Phi + ixb) = hu;
                    *(u16*)((char*)Plo + ixb) = f2bf(p - bf2f(hu));
                }
        }
        asm volatile("s_waitcnt lgkmcnt(0)" ::: "memory");
        __builtin_amdgcn_sched_barrier(0);
        // ---- O^T += V^T P^T (swapped operands; swizzled reads) ----
        __builtin_amdgcn_s_setprio(1);
#pragma unroll
        for (int ks = 0; ks < 2; ks++) {
            int pr = wid * 16 + l15;
            int pb = pr * 128 + ((ks * 64 + lhi * 16) ^ ((pr & 7) << 4));
            bfrag pfh = *(const bfrag*)((const char*)Phi + pb);
            bfrag pfl = *(const bfrag*)((const char*)Plo + pb);
#pragma unroll
            for (int ni = 0; ni < 4; ni++) {
                int d = ni * 16 + l15;
                int vb = d * 128 + ((ks * 64 + lhi * 16) ^ ((d & 7) << 4));
                bfrag vfh = *(const bfrag*)((const char*)Vhi_s + vb);
                bfrag vfl = *(const bfrag*)((const char*)Vlo_s + vb);
                O[ni] = __builtin_amdgcn_mfma_f32_16x16x32_bf16(vfh, pfh, O[ni], 0, 0, 0);
                O[ni] = __builtin_amdgcn_mfma_f32_16x16x32_bf16(vfl, pfh, O[ni], 0, 0, 0);
                O[ni] = __builtin_amdgcn_mfma_f32_16x16x32_bf16(vfh, pfl, O[ni], 0, 0, 0);
            }
        }
        __builtin_amdgcn_s_setprio(0);
        __syncthreads();
    }
    // ---- epilogue: denom lane-local; write O^T[d][q] -> ctx[q][d] ----
    {
        float inv = 1.0f / l_s;
        size_t base = (size_t)(b * Ss + qrow_g) * Dd + h * 64;
#pragma unroll
        for (int ni = 0; ni < 4; ni++)
#pragma unroll
            for (int t = 0; t < 4; t++) {
                float val = O[ni][t] * inv;
                u16 hv = f2bf(val);
                int d = ni * 16 + lhi * 4 + t;
                chi[base + d] = hv;
                clo[base + d] = f2bf(val - bf2f(hv));
            }
    }
}

// ---------- Router ----------
__global__ __launch_bounds__(256)
void router_k(const float* __restrict__ h2, const float* __restrict__ rw,
              float* __restrict__ probs, int* __restrict__ counts,
              int* __restrict__ toklist, float* __restrict__ gwlist)
{
    const int t = blockIdx.x;
    const int tid = threadIdx.x;
    const int lane = tid & 63, wid = tid >> 6;
    f32x4 x4 = *(const f32x4*)(h2 + (size_t)t * Dd + tid * 4);
    float part[En];
#pragma unroll
    for (int e = 0; e < En; e++) {
        f32x4 w4 = *(const f32x4*)(rw + (size_t)e * Dd + tid * 4);
        part[e] = x4.x * w4.x + x4.y * w4.y + x4.z * w4.z + x4.w * w4.w;
    }
#pragma unroll
    for (int e = 0; e < En; e++)
#pragma unroll
        for (int o = 1; o < 64; o <<= 1) part[e] += __shfl_xor(part[e], o, 64);
    __shared__ float red[4][En];
    if (lane == 0) {
#pragma unroll
        for (int e = 0; e < En; e++) red[wid][e] = part[e];
    }
    __syncthreads();
    if (tid == 0) {
        float lg[En];
        float mx = -1e30f;
#pragma unroll
        for (int e = 0; e < En; e++) {
            lg[e] = red[0][e] + red[1][e] + red[2][e] + red[3][e];
            mx = fmaxf(mx, lg[e]);
        }
        float pe[En], ssum = 0.f;
#pragma unroll
        for (int e = 0; e < En; e++) { pe[e] = expf(lg[e] - mx); ssum += pe[e]; }
        float inv = 1.0f / ssum;
#pragma unroll
        for (int e = 0; e < En; e++) { pe[e] *= inv; probs[(size_t)t * En + e] = pe[e]; }
        int i0 = 0;
#pragma unroll
        for (int e = 1; e < En; e++) if (pe[e] > pe[i0]) i0 = e;
        int i1 = (i0 == 0) ? 1 : 0;
#pragma unroll
        for (int e = 0; e < En; e++) if (e != i0 && pe[e] > pe[i1]) i1 = e;
        float s2 = pe[i0] + pe[i1];
        int s0 = atomicAdd(&counts[i0], 1);
        toklist[i0 * Tt + s0] = t; gwlist[i0 * Tt + s0] = pe[i0] / s2;
        int s1 = atomicAdd(&counts[i1], 1);
        toklist[i1 * Tt + s1] = t; gwlist[i1 * Tt + s1] = pe[i1] / s2;
    }
}

// ---------- offsets + balance loss ----------
__global__ __launch_bounds__(256)
void finalize_k(const float* __restrict__ probs, const int* __restrict__ counts,
                int* __restrict__ offsets, float* __restrict__ loss_out)
{
    const int tid = threadIdx.x, lane = tid & 63, wid = tid >> 6;
    float ps[En];
#pragma unroll
    for (int e = 0; e < En; e++) ps[e] = 0.f;
    for (int t = tid; t < Tt; t += 256) {
#pragma unroll
        for (int e = 0; e < En; e++) ps[e] += probs[(size_t)t * En + e];
    }
#pragma unroll
    for (int e = 0; e < En; e++)
#pragma unroll
        for (int o = 1; o < 64; o <<= 1) ps[e] += __shfl_xor(ps[e], o, 64);
    __shared__ float red[4][En];
    if (lane == 0) {
#pragma unroll
        for (int e = 0; e < En; e++) red[wid][e] = ps[e];
    }
    __syncthreads();
    if (tid == 0) {
        int o = 0;
        float bl = 0.f;
#pragma unroll
        for (int e = 0; e < En; e++) {
            offsets[e] = o; o += counts[e];
            float pm = (red[0][e] + red[1][e] + red[2][e] + red[3][e]) * (1.0f / Tt);
            float fr = (float)counts[e] * (1.0f / (Tt * 2));
            bl += fr * pm;
        }
        loss_out[0] = 0.01f * (float)En * bl;
    }
}

extern "C" void kernel_launch(void* const* d_in, const int* in_sizes, int n_in,
                              void* d_out, int out_size, void* d_ws, size_t ws_size,
                              hipStream_t stream)
{
    (void)in_sizes; (void)n_in; (void)out_size; (void)ws_size;
    const float* hs  = (const float*)d_in[0];
    const float* ln1 = (const float*)d_in[1];
    const float* wq  = (const float*)d_in[2];
    const float* wk  = (const float*)d_in[3];
    const float* wv  = (const float*)d_in[4];
    const float* wo  = (const float*)d_in[5];
    const float* ln2 = (const float*)d_in[6];
    const float* rw  = (const float*)d_in[7];
    const float* wg  = (const float*)d_in[8];
    const float* wu  = (const float*)d_in[9];
    const float* wd  = (const float*)d_in[10];
    float* out = (float*)d_out;

    char* ws = (char*)d_ws;
    size_t off = 0;
    auto nxt = [&](size_t bytes) { char* p = ws + off; off += (bytes + 255) & ~(size_t)255; return p; };
    // ---- persistent (MoE-era) region ----
    u16* wgt  = (u16*)nxt((size_t)En * Fn * Dd * 2);
    u16* wut  = (u16*)nxt((size_t)En * Fn * Dd * 2);
    u16* wdt  = (u16*)nxt((size_t)En * Dd * Fn * 2);
    float* h2 = (float*)nxt((size_t)Tt * Dd * 4);
    u16* h2b  = (u16*)nxt((size_t)Tt * Dd * 2);
    float* probs = (float*)nxt((size_t)Tt * En * 4);
    int*   tokl  = (int*)nxt((size_t)En * Tt * 4);
    float* gwl   = (float*)nxt((size_t)En * Tt * 4);
    float* ctab  = (float*)nxt((size_t)Ss * 32 * 4);
    float* stab  = (float*)nxt((size_t)Ss * 32 * 4);
    int* counts  = (int*)nxt(256);
    int* offs    = (int*)nxt(256);
    // ---- transient (pre-MoE) region; `act` aliases it ----
    u16* act = (u16*)(ws + off);
    float* qkv = (float*)nxt((size_t)Tt * 1536 * 4);
    u16* h1hi = (u16*)nxt((size_t)Tt * Dd * 2);
    u16* h1lo = (u16*)nxt((size_t)Tt * Dd * 2);
    u16* khi  = (u16*)nxt((size_t)Tt * KVHn * HDn * 2);
    u16* klo  = (u16*)nxt((size_t)Tt * KVHn * HDn * 2);
    u16* vthi = (u16*)nxt((size_t)Tt * KVHn * HDn * 2);
    u16* vtlo = (u16*)nxt((size_t)Tt * KVHn * HDn * 2);
    u16* chi  = (u16*)nxt((size_t)Tt * Dd * 2);
    u16* clo  = (u16*)nxt((size_t)Tt * Dd * 2);
    u16* wqkvthi = (u16*)nxt((size_t)1536 * Dd * 2);
    u16* wqkvtlo = (u16*)nxt((size_t)1536 * Dd * 2);
    u16* wothi = (u16*)nxt((size_t)Dd * Dd * 2);
    u16* wotlo = (u16*)nxt((size_t)Dd * Dd * 2);

    rope_tab_k<<<dim3(256), 256, 0, stream>>>(ctab, stab);
    // weight prep
    tconv_k<true ><<<dim3(16 * 16), 256, 0, stream>>>(wq, wqkvthi, wqkvtlo, 1024, 1024,    0, 16);
    tconv_k<true ><<<dim3(16 *  4), 256, 0, stream>>>(wk, wqkvthi, wqkvtlo, 1024,  256, 1024,  4);
    tconv_k<true ><<<dim3(16 *  4), 256, 0, stream>>>(wv, wqkvthi, wqkvtlo, 1024,  256, 1280,  4);
    tconv_k<true ><<<dim3(16 * 16), 256, 0, stream>>>(wo, wothi, wotlo, 1024, 1024, 0, 16);
    tprep_k<32, false><<<dim3(32 * 32, En), 256, 0, stream>>>(wg, wgt, 1024, 4096, 32);
    tprep_k<32, false><<<dim3(32 * 32, En), 256, 0, stream>>>(wu, wut, 1024, 4096, 32);
    tprep_k<32, false><<<dim3(8 * 128, En), 256, 0, stream>>>(wd, wdt, 4096, 1024, 8);

    rmsnorm_split_k<<<dim3(Tt), 256, 0, stream>>>(hs, ln1, h1hi, h1lo);
    gemm_split_k<false><<<dim3(12 * 32), 256, 0, stream>>>(h1hi, h1lo, wqkvthi, wqkvtlo,
                                                           qkv, nullptr, Tt, 1536, Dd, 12);
    rope_q_k<<<dim3(Tt * Hh * 32 / 256), 256, 0, stream>>>(qkv, ctab, stab);
    kprep_k<<<dim3(Tt * KVHn * 32 / 256), 256, 0, stream>>>(qkv, ctab, stab, khi, klo);
    vprep_k<<<dim3(Ss / 64, Bb * KVHn), 256, 0, stream>>>(qkv, vthi, vtlo);
    attn_k<<<dim3(Ss / 128, Hh, Bb), 512, 0, stream>>>(qkv, khi, klo, vthi, vtlo, chi, clo);
    gemm_split_k<true><<<dim3(8 * 32), 256, 0, stream>>>(chi, clo, wothi, wotlo,
                                                         out, hs, Tt, Dd, Dd, 8);
    rmsnorm2_k<<<dim3(Tt), 256, 0, stream>>>(out, ln2, h2, h2b);
    (void)hipMemsetAsync(counts, 0, 64, stream);
    router_k<<<dim3(Tt), 256, 0, stream>>>(h2, rw, probs, counts, tokl, gwl);
    finalize_k<<<dim3(1), 256, 0, stream>>>(probs, counts, offs, out + (size_t)Tt * Dd);
    // MoE: gate -> act ; up (in-place silu(g)*u*gw) ; down scatter-add
    gemm_expert_k<0><<<dim3(32 * 32, En), 256, 0, stream>>>(h2b, wgt, act, tokl, gwl, counts, offs);
    gemm_expert_k<1><<<dim3(32 * 32, En), 256, 0, stream>>>(h2b, wut, act, tokl, gwl, counts, offs);
    gemm_down_k<<<dim3(8 * 32, En), 256, 0, stream>>>(act, wdt, out, tokl, counts, offs);
}

// Round 19
// 834.827 us; speedup vs baseline: 1.4137x; 1.0404x over previous
//
#include <hip/hip_runtime.h>

#define Tt 4096
#define Bb 2
#define Ss 2048
#define Dd 1024
#define Hh 16
#define KVHn 4
#define HDn 64
#define En 8
#define Fn 4096

#define BM 128
#define BN 128

typedef unsigned short u16;
typedef __attribute__((ext_vector_type(4))) float f32x4;
typedef __attribute__((ext_vector_type(8))) short bfrag;
typedef __attribute__((ext_vector_type(4))) short s16x4;

#define WAITV(N) asm volatile("s_waitcnt vmcnt(" #N ")" ::: "memory")
#define BARRIER() asm volatile("s_barrier" ::: "memory")

__device__ __forceinline__ u16 f2bf(float f) {
    unsigned u = __builtin_bit_cast(unsigned, f);
    u = (u + 0x7fffu + ((u >> 16) & 1u)) >> 16;
    return (u16)u;
}
__device__ __forceinline__ float bf2f(u16 b) {
    unsigned u = ((unsigned)b) << 16;
    return __builtin_bit_cast(float, u);
}
__device__ __forceinline__ void split8a(const float* va, bfrag* ph, bfrag* pl) {
    bfrag th, tl;
#pragma unroll
    for (int j = 0; j < 8; j++) {
        u16 hu = f2bf(va[j]);
        th[j] = (short)hu;
        tl[j] = (short)f2bf(va[j] - bf2f(hu));
    }
    *ph = th; *pl = tl;
}
// async global->LDS, 16B per lane; LDS dest = wave-uniform base + lane*16, global src per-lane
__device__ __forceinline__ void glds16(const void* g, void* l) {
    __builtin_amdgcn_global_load_lds(
        (const __attribute__((address_space(1))) unsigned int*)g,
        (__attribute__((address_space(3))) unsigned int*)l, 16, 0, 0);
}

// ---------- transpose + bf16 convert (hi/lo split) for QKV/WO weights: [K][N] -> [N][K] ----------
template<bool SPL>
__global__ __launch_bounds__(256)
void tconv_k(const float* __restrict__ src, u16* __restrict__ dhi, u16* __restrict__ dlo,
             const int K, const int N, const int rowOff, const int nTilesN)
{
    const int tid = threadIdx.x;
    const int ty = blockIdx.x / nTilesN, tx = blockIdx.x % nTilesN;
    const int k0 = ty * 64, n0 = tx * 64;
    __shared__ float tl[64][65];
#pragma unroll
    for (int it = 0; it < 16; it++) {
        int idx = tid + it * 256;
        int kk = idx >> 6, nn = idx & 63;
        tl[kk][nn] = src[(size_t)(k0 + kk) * N + n0 + nn];
    }
    __syncthreads();
#pragma unroll
    for (int it = 0; it < 8; it++) {
        int idx = tid + it * 256;
        int n = idx >> 5, k2 = (idx & 31) * 2;
        float v0 = tl[k2][n], v1 = tl[k2 + 1][n];
        u16 h0 = f2bf(v0), h1v = f2bf(v1);
        size_t o = (size_t)(rowOff + n0 + n) * K + k0 + k2;
        *(unsigned*)&dhi[o] = (unsigned)h0 | ((unsigned)h1v << 16);
        if (SPL) {
            u16 l0 = f2bf(v0 - bf2f(h0)), l1 = f2bf(v1 - bf2f(h1v));
            *(unsigned*)&dlo[o] = (unsigned)l0 | ((unsigned)l1 << 16);
        }
    }
}

// ---------- MoE weight prep: f32 [K][N] -> tiled bf16 blocks [nt][kt][128n x TBK k] ----------
template<int TBK, bool SWZ>
__global__ __launch_bounds__(256)
void tprep_k(const float* __restrict__ src, u16* __restrict__ dst,
             const int K, const int N, const int nTilesN)
{
    const int tid = threadIdx.x;
    const int e = blockIdx.y;
    const int ntl = blockIdx.x % nTilesN, kt = blockIdx.x / nTilesN;
    const int nTK = K / TBK;
    src += (size_t)e * K * N + (size_t)(kt * TBK) * N + ntl * 128;
    u16* dblk = dst + (((size_t)e * nTilesN + ntl) * nTK + kt) * (size_t)(128 * TBK);
    __shared__ float tl[TBK][132];
#pragma unroll
    for (int it = 0; it < TBK / 8; it++) {
        int i4 = tid + it * 256;
        int kk = i4 >> 5, n = (i4 & 31) * 4;
        f32x4 v = *(const f32x4*)(src + (size_t)kk * N + n);
        tl[kk][n] = v.x; tl[kk][n + 1] = v.y; tl[kk][n + 2] = v.z; tl[kk][n + 3] = v.w;
    }
    __syncthreads();
#pragma unroll
    for (int it = 0; it < TBK / 16; it++) {
        int idx = tid + it * 256;
        int n = (TBK == 32) ? (idx >> 2) : (idx >> 3);
        int c = (TBK == 32) ? (idx & 3) : (idx & 7);
        bfrag v;
#pragma unroll
        for (int j = 0; j < 8; j++) v[j] = (short)f2bf(tl[c * 8 + j][n]);
        int boff = n * (TBK * 2) + ((c * 16) ^ (SWZ ? ((n & 7) << 4) : 0));
        *(bfrag*)((char*)dblk + boff) = v;
    }
}

// ---------- RMSNorm -> split bf16 (hi/lo) ----------
__global__ __launch_bounds__(256)
void rmsnorm_split_k(const float* __restrict__ x, const float* __restrict__ w,
                     u16* __restrict__ ohi, u16* __restrict__ olo)
{
    const int row = blockIdx.x;
    const int tid = threadIdx.x;
    const int lane = tid & 63, wid = tid >> 6;
    f32x4 t4 = *(const f32x4*)(x + (size_t)row * Dd + tid * 4);
    float s = t4.x*t4.x + t4.y*t4.y + t4.z*t4.z + t4.w*t4.w;
#pragma unroll
    for (int o = 1; o < 64; o <<= 1) s += __shfl_xor(s, o, 64);
    __shared__ float red[4];
    if (lane == 0) red[wid] = s;
    __syncthreads();
    float inv = rsqrtf((red[0] + red[1] + red[2] + red[3]) * (1.0f / Dd) + 1e-6f);
    f32x4 w4 = *(const f32x4*)(w + tid * 4);
    float va[4] = { t4.x*inv*w4.x, t4.y*inv*w4.y, t4.z*inv*w4.z, t4.w*inv*w4.w };
    s16x4 hi, lo;
#pragma unroll
    for (int j = 0; j < 4; j++) {
        u16 hu = f2bf(va[j]);
        hi[j] = (short)hu;
        lo[j] = (short)f2bf(va[j] - bf2f(hu));
    }
    *(s16x4*)&ohi[(size_t)row * Dd + tid * 4] = hi;
    *(s16x4*)&olo[(size_t)row * Dd + tid * 4] = lo;
}

// ---------- RMSNorm -> f32 (router) + rounded bf16 (MoE A) ----------
__global__ __launch_bounds__(256)
void rmsnorm2_k(const float* __restrict__ x, const float* __restrict__ w,
                float* __restrict__ of, u16* __restrict__ ob)
{
    const int row = blockIdx.x;
    const int tid = threadIdx.x;
    const int lane = tid & 63, wid = tid >> 6;
    f32x4 t4 = *(const f32x4*)(x + (size_t)row * Dd + tid * 4);
    float s = t4.x*t4.x + t4.y*t4.y + t4.z*t4.z + t4.w*t4.w;
#pragma unroll
    for (int o = 1; o < 64; o <<= 1) s += __shfl_xor(s, o, 64);
    __shared__ float red[4];
    if (lane == 0) red[wid] = s;
    __syncthreads();
    float inv = rsqrtf((red[0] + red[1] + red[2] + red[3]) * (1.0f / Dd) + 1e-6f);
    f32x4 w4 = *(const f32x4*)(w + tid * 4);
    f32x4 o4;
    o4.x = t4.x*inv*w4.x; o4.y = t4.y*inv*w4.y; o4.z = t4.z*inv*w4.z; o4.w = t4.w*inv*w4.w;
    *(f32x4*)&of[(size_t)row * Dd + tid * 4] = o4;
    s16x4 hb;
    hb[0] = (short)f2bf(o4.x); hb[1] = (short)f2bf(o4.y);
    hb[2] = (short)f2bf(o4.z); hb[3] = (short)f2bf(o4.w);
    *(s16x4*)&ob[(size_t)row * Dd + tid * 4] = hb;
}

// ---------- RoPE tables (f64) ----------
__global__ __launch_bounds__(256)
void rope_tab_k(float* __restrict__ ct, float* __restrict__ st)
{
    int idx = blockIdx.x * 256 + threadIdx.x;
    if (idx < Ss * 32) {
        int s = idx >> 5, i = idx & 31;
        double inv = pow(10000.0, -((double)(2 * i)) / 64.0);
        double a = (double)s * inv;
        double sn, cs;
        sincos(a, &sn, &cs);
        ct[idx] = (float)cs;
        st[idx] = (float)sn;
    }
}

// ---------- RoPE on Q (in-place, qkv stride 1536) ----------
__global__ __launch_bounds__(256)
void rope_q_k(float* __restrict__ qkv, const float* __restrict__ ct, const float* __restrict__ st)
{
    int idx = blockIdx.x * 256 + threadIdx.x;
    int i = idx & 31, hh = (idx >> 5) & (Hh - 1), t = idx >> 9;
    int s = t & (Ss - 1);
    float cs = ct[s * 32 + i], sn = st[s * 32 + i];
    float* base = qkv + (size_t)t * 1536 + hh * 64 + i;
    float x1 = base[0], x2 = base[32];
    base[0]  = x1 * cs - x2 * sn;
    base[32] = x2 * cs + x1 * sn;
}

// ---------- K: RoPE + split bf16 ----------
__global__ __launch_bounds__(256)
void kprep_k(const float* __restrict__ qkv, const float* __restrict__ ct,
             const float* __restrict__ st, u16* __restrict__ khi, u16* __restrict__ klo)
{
    int idx = blockIdx.x * 256 + threadIdx.x;
    int i = idx & 31, hh = (idx >> 5) & (KVHn - 1), t = idx >> 7;
    int s = t & (Ss - 1);
    float cs = ct[s * 32 + i], sn = st[s * 32 + i];
    const float* base = qkv + (size_t)t * 1536 + 1024 + hh * 64 + i;
    float x1 = base[0], x2 = base[32];
    float r1 = x1 * cs - x2 * sn, r2 = x2 * cs + x1 * sn;
    size_t o = (size_t)t * (KVHn * HDn) + hh * 64 + i;
    u16 h1v = f2bf(r1), h2v = f2bf(r2);
    khi[o] = h1v;       khi[o + 32] = h2v;
    klo[o] = f2bf(r1 - bf2f(h1v));
    klo[o + 32] = f2bf(r2 - bf2f(h2v));
}

// ---------- V: transpose + split ----------
__global__ __launch_bounds__(256)
void vprep_k(const float* __restrict__ qkv, u16* __restrict__ vthi, u16* __restrict__ vtlo)
{
    const int st0 = blockIdx.x * 64;
    const int g = blockIdx.y;
    const int b = g >> 2, kvh = g & 3;
    const int tid = threadIdx.x;
    __shared__ float tl[64][65];
#pragma unroll
    for (int it = 0; it < 16; it++) {
        int idx = tid + it * 256;
        int sl = idx >> 6, d = idx & 63;
        tl[sl][d] = qkv[(size_t)(b * Ss + st0 + sl) * 1536 + 1280 + kvh * 64 + d];
    }
    __syncthreads();
#pragma unroll
    for (int it = 0; it < 8; it++) {
        int idx = tid + it * 256;
        int d = idx >> 5, s2 = (idx & 31) * 2;
        float v0 = tl[s2][d], v1 = tl[s2 + 1][d];
        u16 h0 = f2bf(v0), h1v = f2bf(v1);
        size_t o = ((size_t)g * 64 + d) * Ss + st0 + s2;
        *(unsigned*)&vthi[o] = (unsigned)h0 | ((unsigned)h1v << 16);
        u16 l0 = f2bf(v0 - bf2f(h0)), l1 = f2bf(v1 - bf2f(h1v));
        *(unsigned*)&vtlo[o] = (unsigned)l0 | ((unsigned)l1 << 16);
    }
}

// ---------- split-bf16x3 GEMM (glds + dbuf + counted vmcnt): C = A@B^T(+resid) ----------
template<bool RESID>
__global__ __launch_bounds__(256)
void gemm_split_k(const u16* __restrict__ Ahi_g, const u16* __restrict__ Alo_g,
                  const u16* __restrict__ Bhi_g, const u16* __restrict__ Blo_g,
                  float* __restrict__ C, const float* __restrict__ resid,
                  const int M, const int N, const int K, const int ntiles)
{
    const int bid = blockIdx.x;
    const int nt = bid % ntiles, mt = bid / ntiles;
    __shared__ __align__(16) u16 Ah[2][128 * 32], Al[2][128 * 32];
    __shared__ __align__(16) u16 Bh[2][128 * 32], Bl[2][128 * 32];   // 64 KB
    const int tid = threadIdx.x, lane = tid & 63, wid = tid >> 6;
    const int wrow = (wid >> 1) * 64, wcol = (wid & 1) * 64;
    const int l15 = lane & 15, lhi = lane >> 4;
    const int row0 = mt * BM, col0 = nt * BN;

    const u16 *ah_s[2], *al_s[2], *bh_s[2], *bl_s[2];
#pragma unroll
    for (int j = 0; j < 2; j++) {
        int r = (wid * 2 + j) * 16 + (lane >> 2);
        size_t ca = (size_t)(row0 + r) * K + (lane & 3) * 8;
        size_t cb = (size_t)(col0 + r) * K + (lane & 3) * 8;
        ah_s[j] = Ahi_g + ca; al_s[j] = Alo_g + ca;
        bh_s[j] = Bhi_g + cb; bl_s[j] = Blo_g + cb;
    }
    f32x4 acc[4][4];
#pragma unroll
    for (int i = 0; i < 4; i++)
#pragma unroll
        for (int j = 0; j < 4; j++) { acc[i][j].x = 0.f; acc[i][j].y = 0.f; acc[i][j].z = 0.f; acc[i][j].w = 0.f; }

    auto stage = [&](int buf, int k0) {
#pragma unroll
        for (int j = 0; j < 2; j++) {
            int d = (wid * 2 + j) * 512;
            glds16(ah_s[j] + k0, &Ah[buf][d]);
            glds16(al_s[j] + k0, &Al[buf][d]);
            glds16(bh_s[j] + k0, &Bh[buf][d]);
            glds16(bl_s[j] + k0, &Bl[buf][d]);
        }
    };
    auto compute = [&](int cur) {
        bfrag ah[4], al[4], bh[4], bl[4];
#pragma unroll
        for (int mi = 0; mi < 4; mi++) {
            int rb = (wrow + mi * 16 + l15) * 32 + lhi * 8;
            ah[mi] = *(const bfrag*)&Ah[cur][rb];
            al[mi] = *(const bfrag*)&Al[cur][rb];
        }
#pragma unroll
        for (int ni = 0; ni < 4; ni++) {
            int rb = (wcol + ni * 16 + l15) * 32 + lhi * 8;
            bh[ni] = *(const bfrag*)&Bh[cur][rb];
            bl[ni] = *(const bfrag*)&Bl[cur][rb];
        }
#pragma unroll
        for (int mi = 0; mi < 4; mi++)
#pragma unroll
            for (int ni = 0; ni < 4; ni++) {
                acc[mi][ni] = __builtin_amdgcn_mfma_f32_16x16x32_bf16(ah[mi], bh[ni], acc[mi][ni], 0, 0, 0);
                acc[mi][ni] = __builtin_amdgcn_mfma_f32_16x16x32_bf16(ah[mi], bl[ni], acc[mi][ni], 0, 0, 0);
                acc[mi][ni] = __builtin_amdgcn_mfma_f32_16x16x32_bf16(al[mi], bh[ni], acc[mi][ni], 0, 0, 0);
            }
    };
    const int nkt = K / 32;
    stage(0, 0);
    stage(1, 32);
    int cur = 0;
    for (int kt = 0; kt < nkt - 1; kt++) {
        WAITV(8);       // own tile-kt loads done; kt+1 still in flight
        BARRIER();
        compute(cur);
        BARRIER();
        if (kt + 2 < nkt) stage(cur, (kt + 2) * 32);
        cur ^= 1;
    }
    WAITV(0);
    BARRIER();
    compute(cur);
#pragma unroll
    for (int mi = 0; mi < 4; mi++) {
#pragma unroll
        for (int t = 0; t < 4; t++) {
            int pr = row0 + wrow + mi * 16 + lhi * 4 + t;
#pragma unroll
            for (int ni = 0; ni < 4; ni++) {
                int gc = col0 + wcol + ni * 16 + l15;
                float vv = acc[mi][ni][t];
                if (RESID) vv += resid[(size_t)pr * N + gc];
                C[(size_t)pr * N + gc] = vv;
            }
        }
    }
}

// ---------- MoE expert GEMM (single output): glds + dbuf + counted vmcnt, BK=32 ----------
// MODE 0 (gate): act[ix] = bf16(acc)
// MODE 1 (up):   g = act[ix]; act[ix] = bf16(silu(g) * acc * gw)   [in-place, same thread owns ix]
template<int MODE>
__global__ __launch_bounds__(256, 4)
void gemm_expert_k(const u16* __restrict__ A_g, const u16* __restrict__ Bt,
                   u16* __restrict__ act,
                   const int* __restrict__ toklist, const float* __restrict__ gwlist,
                   const int* __restrict__ counts, const int* __restrict__ offsets)
{
    const int e = blockIdx.y;
    const int Meff = counts[e];
    const int nt = blockIdx.x & 31, mt = blockIdx.x >> 5;
    if (mt * BM >= Meff) return;
    const int* tok = toklist + e * Tt;
    const float* gw = gwlist + e * Tt;
    const int rowoff = offsets[e];
    __shared__ __align__(16) u16 As[2][128 * 32], Bs[2][128 * 32];   // 32 KB
    const int tid = threadIdx.x, lane = tid & 63, wid = tid >> 6;
    const int wrow = (wid >> 1) * 64, wcol = (wid & 1) * 64;
    const int l15 = lane & 15, lhi = lane >> 4;
    const int row0 = mt * BM, col0 = nt * BN;

    const u16* asrc[2];
#pragma unroll
    for (int j = 0; j < 2; j++) {
        int row = (wid * 2 + j) * 16 + (lane >> 2);
        int pr = row0 + row;
        int tr = (pr < Meff) ? tok[pr] : tok[0];
        asrc[j] = A_g + (size_t)tr * Dd + (lane & 3) * 8;
    }
    const size_t bblk = (size_t)(e * 32 + nt) * (32 * 4096);
    const u16* bsrc = Bt + bblk + (size_t)(wid * 2) * 512 + lane * 8;

    f32x4 acc[4][4];
#pragma unroll
    for (int i = 0; i < 4; i++)
#pragma unroll
        for (int j = 0; j < 4; j++) { acc[i][j].x = 0.f; acc[i][j].y = 0.f; acc[i][j].z = 0.f; acc[i][j].w = 0.f; }

    auto stage = [&](int buf, int kt) {
#pragma unroll
        for (int j = 0; j < 2; j++) {
            int d = (wid * 2 + j) * 512;
            glds16(asrc[j] + kt * 32,                  &As[buf][d]);
            glds16(bsrc + j * 512 + (size_t)kt * 4096, &Bs[buf][d]);
        }
    };
    auto compute = [&](int cur) {
        bfrag a[4];
#pragma unroll
        for (int mi = 0; mi < 4; mi++)
            a[mi] = *(const bfrag*)&As[cur][(wrow + mi * 16 + l15) * 32 + lhi * 8];
#pragma unroll
        for (int ni = 0; ni < 4; ni++) {
            bfrag b = *(const bfrag*)&Bs[cur][(wcol + ni * 16 + l15) * 32 + lhi * 8];
#pragma unroll
            for (int mi = 0; mi < 4; mi++)
                acc[mi][ni] = __builtin_amdgcn_mfma_f32_16x16x32_bf16(a[mi], b, acc[mi][ni], 0, 0, 0);
        }
    };
    stage(0, 0);
    stage(1, 1);
    int cur = 0;
    for (int kt = 0; kt < 31; kt++) {
        WAITV(4);
        BARRIER();
        compute(cur);
        BARRIER();
        if (kt + 2 < 32) stage(cur, kt + 2);
        cur ^= 1;
    }
    WAITV(0);
    BARRIER();
    compute(cur);
#pragma unroll
    for (int mi = 0; mi < 4; mi++) {
#pragma unroll
        for (int t = 0; t < 4; t++) {
            int pr = row0 + wrow + mi * 16 + lhi * 4 + t;
            if (pr < Meff) {
                float gwv = (MODE == 1) ? gw[pr] : 0.f;
#pragma unroll
                for (int ni = 0; ni < 4; ni++) {
                    int gc = col0 + wcol + ni * 16 + l15;
                    size_t ix = (size_t)(rowoff + pr) * Fn + gc;
                    if (MODE == 0) {
                        act[ix] = f2bf(acc[mi][ni][t]);
                    } else {
                        float g = bf2f(act[ix]);
                        float sg = g / (1.0f + expf(-g));
                        act[ix] = f2bf(sg * acc[mi][ni][t] * gwv);
                    }
                }
            }
        }
    }
}

// ---------- MoE down (glds + dbuf + counted vmcnt, BK=32): out[tok] += act @ Wd^T ----------
// 1D grid, expert-per-XCD decode: e = bid&7 (XCD id), nt fastest within (e,mt) for act L2 reuse.
__global__ __launch_bounds__(256, 4)
void gemm_down_k(const u16* __restrict__ act, const u16* __restrict__ Bt,
                 float* __restrict__ C, const int* __restrict__ toklist,
                 const int* __restrict__ counts, const int* __restrict__ offsets)
{
    const int e = blockIdx.x & 7;          // XCD = blockIdx % 8 = expert
    const int rest = blockIdx.x >> 3;
    const int nt = rest & 7;               // nt cycles fastest -> act slice reused in L2
    const int mt = rest >> 3;              // 0..31
    const int Meff = counts[e];
    if (mt * BM >= Meff) return;
    const int* tok = toklist + e * Tt;
    const int rowoff = offsets[e];
    __shared__ __align__(16) u16 As[2][128 * 32], Bs[2][128 * 32];   // 32 KB
    const int tid = threadIdx.x, lane = tid & 63, wid = tid >> 6;
    const int wrow = (wid >> 1) * 64, wcol = (wid & 1) * 64;
    const int l15 = lane & 15, lhi = lane >> 4;
    const int row0 = mt * BM;

    const u16* asrc[2];
#pragma unroll
    for (int j = 0; j < 2; j++) {
        int row = (wid * 2 + j) * 16 + (lane >> 2);
        int pr = row0 + row;
        int rr = (pr < Meff) ? pr : 0;
        asrc[j] = act + (size_t)(rowoff + rr) * Fn + (lane & 3) * 8;
    }
    const size_t bblk = (size_t)(e * 8 + nt) * ((size_t)128 * 4096);
    const u16* bsrc = Bt + bblk + (size_t)(wid * 2) * 512 + lane * 8;

    f32x4 acc[4][4];
#pragma unroll
    for (int i = 0; i < 4; i++)
#pragma unroll
        for (int j = 0; j < 4; j++) { acc[i][j].x = 0.f; acc[i][j].y = 0.f; acc[i][j].z = 0.f; acc[i][j].w = 0.f; }

    auto stage = [&](int buf, int kt) {
#pragma unroll
        for (int j = 0; j < 2; j++) {
            int d = (wid * 2 + j) * 512;
            glds16(asrc[j] + kt * 32,                  &As[buf][d]);
            glds16(bsrc + j * 512 + (size_t)kt * 4096, &Bs[buf][d]);
        }
    };
    auto compute = [&](int cur) {
        bfrag a[4];
#pragma unroll
        for (int mi = 0; mi < 4; mi++)
            a[mi] = *(const bfrag*)&As[cur][(wrow + mi * 16 + l15) * 32 + lhi * 8];
#pragma unroll
        for (int ni = 0; ni < 4; ni++) {
            bfrag b = *(const bfrag*)&Bs[cur][(wcol + ni * 16 + l15) * 32 + lhi * 8];
#pragma unroll
            for (int mi = 0; mi < 4; mi++)
                acc[mi][ni] = __builtin_amdgcn_mfma_f32_16x16x32_bf16(a[mi], b, acc[mi][ni], 0, 0, 0);
        }
    };
    stage(0, 0);
    stage(1, 1);
    int cur = 0;
    const int nkt = Fn / 32;   // 128
    for (int kt = 0; kt < nkt - 1; kt++) {
        WAITV(4);
        BARRIER();
        compute(cur);
        BARRIER();
        if (kt + 2 < nkt) stage(cur, kt + 2);
        cur ^= 1;
    }
    WAITV(0);
    BARRIER();
    compute(cur);
#pragma unroll
    for (int mi = 0; mi < 4; mi++) {
#pragma unroll
        for (int t = 0; t < 4; t++) {
            int pr = row0 + wrow + mi * 16 + lhi * 4 + t;
            if (pr < Meff) {
                int trow = tok[pr];
#pragma unroll
                for (int ni = 0; ni < 4; ni++) {
                    int gc = nt * BN + wcol + ni * 16 + l15;
                    atomicAdd(&C[(size_t)trow * Dd + gc], acc[mi][ni][t]);
                }
            }
        }
    }
}

// ---------- Flash attention (causal GQA), split-bf16x3, 128-row Q tile, 8 waves ----------
// Swapped QK^T/PV; K,V,P all XOR-swizzled stride-64 LDS (exactly 64 KB total).
__global__ __launch_bounds__(512)
void attn_k(const float* __restrict__ qkv, const u16* __restrict__ khi,
            const u16* __restrict__ klo, const u16* __restrict__ vthi,
            const u16* __restrict__ vtlo, u16* __restrict__ chi, u16* __restrict__ clo)
{
    const int qb = (int)gridDim.x - 1 - (int)blockIdx.x;   // 0..15, longest first
    const int h = blockIdx.y, b = blockIdx.z;
    const int kvh = h >> 2;
    const int g = b * KVHn + kvh;
    const int tid = threadIdx.x;
    const int lane = tid & 63, wid = tid >> 6;             // wid 0..7
    const int l15 = lane & 15, lhi = lane >> 4;

    __shared__ __align__(16) u16 Khi_s[64 * 64];
    __shared__ __align__(16) u16 Klo_s[64 * 64];
    __shared__ __align__(16) u16 Vhi_s[64 * 64];
    __shared__ __align__(16) u16 Vlo_s[64 * 64];
    __shared__ __align__(16) u16 Phi[128 * 64];
    __shared__ __align__(16) u16 Plo[128 * 64];            // total 65536 B

    const int qrow_g = qb * 128 + wid * 16 + l15;          // this lane's q row (swapped layout)
    bfrag qh[2], ql[2];
    {
        const float* qb_p = qkv + (size_t)(b * Ss + qrow_g) * 1536 + h * 64;
#pragma unroll
        for (int ks = 0; ks < 2; ks++) {
            const float* p = qb_p + ks * 32 + lhi * 8;
            f32x4 u0 = *(const f32x4*)p;
            f32x4 u1 = *(const f32x4*)(p + 4);
            float va[8] = { u0.x * 0.125f, u0.y * 0.125f, u0.z * 0.125f, u0.w * 0.125f,
                            u1.x * 0.125f, u1.y * 0.125f, u1.z * 0.125f, u1.w * 0.125f };
            split8a(va, &qh[ks], &ql[ks]);
        }
    }
    // staging geometry: 512 threads, one 16B chunk each; row = tid>>3, col elems = (tid&7)*8
    const int srow = tid >> 3, scol = (tid & 7) << 3;
    const size_t kga0 = (size_t)(b * Ss + srow) * (KVHn * HDn) + kvh * 64 + scol;
    const int kboff = srow * 128 + ((scol * 2) ^ ((srow & 7) << 4));
    const size_t vga0 = ((size_t)g * 64 + srow) * Ss + scol;   // V: row=d, col=kv
    const int vboff = srow * 128 + ((scol * 2) ^ ((srow & 7) << 4));

    bfrag rkh, rkl, rvh, rvl;
    auto LOADR = [&](int kt) {
        size_t ka = kga0 + (size_t)kt * (64 * KVHn * HDn);
        rkh = *(const bfrag*)&khi[ka];
        rkl = *(const bfrag*)&klo[ka];
        size_t va = vga0 + (size_t)kt * 64;
        rvh = *(const bfrag*)&vthi[va];
        rvl = *(const bfrag*)&vtlo[va];
    };
    f32x4 O[4];   // O^T: O[ni][t] = O^T[d = ni*16+lhi*4+t][q = qrow_g]
#pragma unroll
    for (int ni = 0; ni < 4; ni++) { O[ni].x = 0.f; O[ni].y = 0.f; O[ni].z = 0.f; O[ni].w = 0.f; }
    float m_s = -1e30f;
    float l_s = 0.f;

    const int nkt = 2 * qb + 2;
    LOADR(0);
    for (int kt = 0; kt < nkt; kt++) {
        // ---- write prefetched K/V regs to LDS (swizzled) ----
        *(bfrag*)((char*)Khi_s + kboff) = rkh;
        *(bfrag*)((char*)Klo_s + kboff) = rkl;
        *(bfrag*)((char*)Vhi_s + vboff) = rvh;
        *(bfrag*)((char*)Vlo_s + vboff) = rvl;
        __syncthreads();
        if (kt + 1 < nkt) LOADR(kt + 1);
        // ---- S^T = K Q^T (3-pass split): sf[ni][t] = S[kv = ni*16+lhi*4+t][q = qrow_g] ----
        f32x4 sf[4];
#pragma unroll
        for (int ni = 0; ni < 4; ni++) { sf[ni].x = 0.f; sf[ni].y = 0.f; sf[ni].z = 0.f; sf[ni].w = 0.f; }
        __builtin_amdgcn_s_setprio(1);
#pragma unroll
        for (int ks = 0; ks < 2; ks++) {
#pragma unroll
            for (int ni = 0; ni < 4; ni++) {
                int kv = ni * 16 + l15;
                int dof = ks * 64 + lhi * 16;
                int boff = kv * 128 + (dof ^ ((kv & 7) << 4));
                bfrag kfh = *(const bfrag*)((const char*)Khi_s + boff);
                bfrag kfl = *(const bfrag*)((const char*)Klo_s + boff);
                sf[ni] = __builtin_amdgcn_mfma_f32_16x16x32_bf16(kfh, qh[ks], sf[ni], 0, 0, 0);
                sf[ni] = __builtin_amdgcn_mfma_f32_16x16x32_bf16(kfl, qh[ks], sf[ni], 0, 0, 0);
                sf[ni] = __builtin_amdgcn_mfma_f32_16x16x32_bf16(kfh, ql[ks], sf[ni], 0, 0, 0);
            }
        }
        __builtin_amdgcn_s_setprio(0);
        // ---- causal mask (last two kv-tiles), global coords ----
        if (kt >= 2 * qb) {
#pragma unroll
            for (int ni = 0; ni < 4; ni++)
#pragma unroll
                for (int t = 0; t < 4; t++)
                    if (kt * 64 + ni * 16 + lhi * 4 + t > qrow_g) sf[ni][t] = -1e30f;
        }
        // ---- lane-local softmax ----
        float mx = -1e30f;
#pragma unroll
        for (int ni = 0; ni < 4; ni++)
#pragma unroll
            for (int t = 0; t < 4; t++) mx = fmaxf(mx, sf[ni][t]);
        mx = fmaxf(mx, __shfl_xor(mx, 16, 64));
        mx = fmaxf(mx, __shfl_xor(mx, 32, 64));
        float mn = fmaxf(m_s, mx);
        float sc = expf(m_s - mn);
        m_s = mn;
        float rs = 0.f;
#pragma unroll
        for (int ni = 0; ni < 4; ni++)
#pragma unroll
            for (int t = 0; t < 4; t++) {
                float p = expf(sf[ni][t] - mn);
                sf[ni][t] = p;
                rs += p;
            }
        rs += __shfl_xor(rs, 16, 64);
        rs += __shfl_xor(rs, 32, 64);
        l_s = l_s * sc + rs;
        // ---- O^T rescale (lane-local) ----
#pragma unroll
        for (int ni = 0; ni < 4; ni++)
#pragma unroll
            for (int t = 0; t < 4; t++) O[ni][t] *= sc;
        // ---- P write: row = q = wid*16+l15 (0..127), col = kv = ni*16+lhi*4+t, swizzled ----
        {
            int pr = wid * 16 + l15;
            int prx = (pr & 7) << 4;
#pragma unroll
            for (int ni = 0; ni < 4; ni++)
#pragma unroll
                for (int t = 0; t < 4; t++) {
                    float p = sf[ni][t];
                    u16 hu = f2bf(p);
                    int cb = (ni * 32 + lhi * 8 + t * 2) ^ prx;
                    int ixb = pr * 128 + cb;
                    *(u16*)((char*)Phi + ixb) = hu;
                    *(u16*)((char*)Plo + ixb) = f2bf(p - bf2f(hu));
                }
        }
        asm volatile("s_waitcnt lgkmcnt(0)" ::: "memory");
        __builtin_amdgcn_sched_barrier(0);
        // ---- O^T += V^T P^T (swapped operands; swizzled reads) ----
        __builtin_amdgcn_s_setprio(1);
#pragma unroll
        for (int ks = 0; ks < 2; ks++) {
            int pr = wid * 16 + l15;
            int pb = pr * 128 + ((ks * 64 + lhi * 16) ^ ((pr & 7) << 4));
            bfrag pfh = *(const bfrag*)((const char*)Phi + pb);
            bfrag pfl = *(const bfrag*)((const char*)Plo + pb);
#pragma unroll
            for (int ni = 0; ni < 4; ni++) {
                int d = ni * 16 + l15;
                int vb = d * 128 + ((ks * 64 + lhi * 16) ^ ((d & 7) << 4));
                bfrag vfh = *(const bfrag*)((const char*)Vhi_s + vb);
                bfrag vfl = *(const bfrag*)((const char*)Vlo_s + vb);
                O[ni] = __builtin_amdgcn_mfma_f32_16x16x32_bf16(vfh, pfh, O[ni], 0, 0, 0);
                O[ni] = __builtin_amdgcn_mfma_f32_16x16x32_bf16(vfl, pfh, O[ni], 0, 0, 0);
                O[ni] = __builtin_amdgcn_mfma_f32_16x16x32_bf16(vfh, pfl, O[ni], 0, 0, 0);
            }
        }
        __builtin_amdgcn_s_setprio(0);
        __syncthreads();
    }
    // ---- epilogue: denom lane-local; write O^T[d][q] -> ctx[q][d] ----
    {
        float inv = 1.0f / l_s;
        size_t base = (size_t)(b * Ss + qrow_g) * Dd + h * 64;
#pragma unroll
        for (int ni = 0; ni < 4; ni++)
#pragma unroll
            for (int t = 0; t < 4; t++) {
                float val = O[ni][t] * inv;
                u16 hv = f2bf(val);
                int d = ni * 16 + lhi * 4 + t;
                chi[base + d] = hv;
                clo[base + d] = f2bf(val - bf2f(hv));
            }
    }
}

// ---------- Router ----------
__global__ __launch_bounds__(256)
void router_k(const float* __restrict__ h2, const float* __restrict__ rw,
              float* __restrict__ probs, int* __restrict__ counts,
              int* __restrict__ toklist, float* __restrict__ gwlist)
{
    const int t = blockIdx.x;
    const int tid = threadIdx.x;
    const int lane = tid & 63, wid = tid >> 6;
    f32x4 x4 = *(const f32x4*)(h2 + (size_t)t * Dd + tid * 4);
    float part[En];
#pragma unroll
    for (int e = 0; e < En; e++) {
        f32x4 w4 = *(const f32x4*)(rw + (size_t)e * Dd + tid * 4);
        part[e] = x4.x * w4.x + x4.y * w4.y + x4.z * w4.z + x4.w * w4.w;
    }
#pragma unroll
    for (int e = 0; e < En; e++)
#pragma unroll
        for (int o = 1; o < 64; o <<= 1) part[e] += __shfl_xor(part[e], o, 64);
    __shared__ float red[4][En];
    if (lane == 0) {
#pragma unroll
        for (int e = 0; e < En; e++) red[wid][e] = part[e];
    }
    __syncthreads();
    if (tid == 0) {
        float lg[En];
        float mx = -1e30f;
#pragma unroll
        for (int e = 0; e < En; e++) {
            lg[e] = red[0][e] + red[1][e] + red[2][e] + red[3][e];
            mx = fmaxf(mx, lg[e]);
        }
        float pe[En], ssum = 0.f;
#pragma unroll
        for (int e = 0; e < En; e++) { pe[e] = expf(lg[e] - mx); ssum += pe[e]; }
        float inv = 1.0f / ssum;
#pragma unroll
        for (int e = 0; e < En; e++) { pe[e] *= inv; probs[(size_t)t * En + e] = pe[e]; }
        int i0 = 0;
#pragma unroll
        for (int e = 1; e < En; e++) if (pe[e] > pe[i0]) i0 = e;
        int i1 = (i0 == 0) ? 1 : 0;
#pragma unroll
        for (int e = 0; e < En; e++) if (e != i0 && pe[e] > pe[i1]) i1 = e;
        float s2 = pe[i0] + pe[i1];
        int s0 = atomicAdd(&counts[i0], 1);
        toklist[i0 * Tt + s0] = t; gwlist[i0 * Tt + s0] = pe[i0] / s2;
        int s1 = atomicAdd(&counts[i1], 1);
        toklist[i1 * Tt + s1] = t; gwlist[i1 * Tt + s1] = pe[i1] / s2;
    }
}

// ---------- offsets + balance loss ----------
__global__ __launch_bounds__(256)
void finalize_k(const float* __restrict__ probs, const int* __restrict__ counts,
                int* __restrict__ offsets, float* __restrict__ loss_out)
{
    const int tid = threadIdx.x, lane = tid & 63, wid = tid >> 6;
    float ps[En];
#pragma unroll
    for (int e = 0; e < En; e++) ps[e] = 0.f;
    for (int t = tid; t < Tt; t += 256) {
#pragma unroll
        for (int e = 0; e < En; e++) ps[e] += probs[(size_t)t * En + e];
    }
#pragma unroll
    for (int e = 0; e < En; e++)
#pragma unroll
        for (int o = 1; o < 64; o <<= 1) ps[e] += __shfl_xor(ps[e], o, 64);
    __shared__ float red[4][En];
    if (lane == 0) {
#pragma unroll
        for (int e = 0; e < En; e++) red[wid][e] = ps[e];
    }
    __syncthreads();
    if (tid == 0) {
        int o = 0;
        float bl = 0.f;
#pragma unroll
        for (int e = 0; e < En; e++) {
            offsets[e] = o; o += counts[e];
            float pm = (red[0][e] + red[1][e] + red[2][e] + red[3][e]) * (1.0f / Tt);
            float fr = (float)counts[e] * (1.0f / (Tt * 2));
            bl += fr * pm;
        }
        loss_out[0] = 0.01f * (float)En * bl;
    }
}

extern "C" void kernel_launch(void* const* d_in, const int* in_sizes, int n_in,
                              void* d_out, int out_size, void* d_ws, size_t ws_size,
                              hipStream_t stream)
{
    (void)in_sizes; (void)n_in; (void)out_size; (void)ws_size;
    const float* hs  = (const float*)d_in[0];
    const float* ln1 = (const float*)d_in[1];
    const float* wq  = (const float*)d_in[2];
    const float* wk  = (const float*)d_in[3];
    const float* wv  = (const float*)d_in[4];
    const float* wo  = (const float*)d_in[5];
    const float* ln2 = (const float*)d_in[6];
    const float* rw  = (const float*)d_in[7];
    const float* wg  = (const float*)d_in[8];
    const float* wu  = (const float*)d_in[9];
    const float* wd  = (const float*)d_in[10];
    float* out = (float*)d_out;

    char* ws = (char*)d_ws;
    size_t off = 0;
    auto nxt = [&](size_t bytes) { char* p = ws + off; off += (bytes + 255) & ~(size_t)255; return p; };
    // ---- persistent (MoE-era) region ----
    u16* wgt  = (u16*)nxt((size_t)En * Fn * Dd * 2);
    u16* wut  = (u16*)nxt((size_t)En * Fn * Dd * 2);
    u16* wdt  = (u16*)nxt((size_t)En * Dd * Fn * 2);
    float* h2 = (float*)nxt((size_t)Tt * Dd * 4);
    u16* h2b  = (u16*)nxt((size_t)Tt * Dd * 2);
    float* probs = (float*)nxt((size_t)Tt * En * 4);
    int*   tokl  = (int*)nxt((size_t)En * Tt * 4);
    float* gwl   = (float*)nxt((size_t)En * Tt * 4);
    float* ctab  = (float*)nxt((size_t)Ss * 32 * 4);
    float* stab  = (float*)nxt((size_t)Ss * 32 * 4);
    int* counts  = (int*)nxt(256);
    int* offs    = (int*)nxt(256);
    // ---- transient (pre-MoE) region; `act` aliases it ----
    u16* act = (u16*)(ws + off);
    float* qkv = (float*)nxt((size_t)Tt * 1536 * 4);
    u16* h1hi = (u16*)nxt((size_t)Tt * Dd * 2);
    u16* h1lo = (u16*)nxt((size_t)Tt * Dd * 2);
    u16* khi  = (u16*)nxt((size_t)Tt * KVHn * HDn * 2);
    u16* klo  = (u16*)nxt((size_t)Tt * KVHn * HDn * 2);
    u16* vthi = (u16*)nxt((size_t)Tt * KVHn * HDn * 2);
    u16* vtlo = (u16*)nxt((size_t)Tt * KVHn * HDn * 2);
    u16* chi  = (u16*)nxt((size_t)Tt * Dd * 2);
    u16* clo  = (u16*)nxt((size_t)Tt * Dd * 2);
    u16* wqkvthi = (u16*)nxt((size_t)1536 * Dd * 2);
    u16* wqkvtlo = (u16*)nxt((size_t)1536 * Dd * 2);
    u16* wothi = (u16*)nxt((size_t)Dd * Dd * 2);
    u16* wotlo = (u16*)nxt((size_t)Dd * Dd * 2);

    rope_tab_k<<<dim3(256), 256, 0, stream>>>(ctab, stab);
    // weight prep
    tconv_k<true ><<<dim3(16 * 16), 256, 0, stream>>>(wq, wqkvthi, wqkvtlo, 1024, 1024,    0, 16);
    tconv_k<true ><<<dim3(16 *  4), 256, 0, stream>>>(wk, wqkvthi, wqkvtlo, 1024,  256, 1024,  4);
    tconv_k<true ><<<dim3(16 *  4), 256, 0, stream>>>(wv, wqkvthi, wqkvtlo, 1024,  256, 1280,  4);
    tconv_k<true ><<<dim3(16 * 16), 256, 0, stream>>>(wo, wothi, wotlo, 1024, 1024, 0, 16);
    tprep_k<32, false><<<dim3(32 * 32, En), 256, 0, stream>>>(wg, wgt, 1024, 4096, 32);
    tprep_k<32, false><<<dim3(32 * 32, En), 256, 0, stream>>>(wu, wut, 1024, 4096, 32);
    tprep_k<32, false><<<dim3(8 * 128, En), 256, 0, stream>>>(wd, wdt, 4096, 1024, 8);

    rmsnorm_split_k<<<dim3(Tt), 256, 0, stream>>>(hs, ln1, h1hi, h1lo);
    gemm_split_k<false><<<dim3(12 * 32), 256, 0, stream>>>(h1hi, h1lo, wqkvthi, wqkvtlo,
                                                           qkv, nullptr, Tt, 1536, Dd, 12);
    rope_q_k<<<dim3(Tt * Hh * 32 / 256), 256, 0, stream>>>(qkv, ctab, stab);
    kprep_k<<<dim3(Tt * KVHn * 32 / 256), 256, 0, stream>>>(qkv, ctab, stab, khi, klo);
    vprep_k<<<dim3(Ss / 64, Bb * KVHn), 256, 0, stream>>>(qkv, vthi, vtlo);
    attn_k<<<dim3(Ss / 128, Hh, Bb), 512, 0, stream>>>(qkv, khi, klo, vthi, vtlo, chi, clo);
    gemm_split_k<true><<<dim3(8 * 32), 256, 0, stream>>>(chi, clo, wothi, wotlo,
                                                         out, hs, Tt, Dd, Dd, 8);
    rmsnorm2_k<<<dim3(Tt), 256, 0, stream>>>(out, ln2, h2, h2b);
    (void)hipMemsetAsync(counts, 0, 64, stream);
    router_k<<<dim3(Tt), 256, 0, stream>>>(h2, rw, probs, counts, tokl, gwl);
    finalize_k<<<dim3(1), 256, 0, stream>>>(probs, counts, offs, out + (size_t)Tt * Dd);
    // MoE: gate -> act ; up (in-place silu(g)*u*gw) ; down scatter-add (expert-per-XCD)
    gemm_expert_k<0><<<dim3(32 * 32, En), 256, 0, stream>>>(h2b, wgt, act, tokl, gwl, counts, offs);
    gemm_expert_k<1><<<dim3(32 * 32, En), 256, 0, stream>>>(h2b, wut, act, tokl, gwl, counts, offs);
    gemm_down_k<<<dim3(8 * 8 * 32), 256, 0, stream>>>(act, wdt, out, tokl, counts, offs);
}

// Round 20
// 818.545 us; speedup vs baseline: 1.4418x; 1.0199x over previous
//
#include <hip/hip_runtime.h>

#define Tt 4096
#define Bb 2
#define Ss 2048
#define Dd 1024
#define Hh 16
#define KVHn 4
#define HDn 64
#define En 8
#define Fn 4096

#define BM 128
#define BN 128

typedef unsigned short u16;
typedef __attribute__((ext_vector_type(4))) float f32x4;
typedef __attribute__((ext_vector_type(8))) short bfrag;
typedef __attribute__((ext_vector_type(4))) short s16x4;

#define WAITV(N) asm volatile("s_waitcnt vmcnt(" #N ")" ::: "memory")
#define BARRIER() asm volatile("s_barrier" ::: "memory")

__device__ __forceinline__ u16 f2bf(float f) {
    unsigned u = __builtin_bit_cast(unsigned, f);
    u = (u + 0x7fffu + ((u >> 16) & 1u)) >> 16;
    return (u16)u;
}
__device__ __forceinline__ float bf2f(u16 b) {
    unsigned u = ((unsigned)b) << 16;
    return __builtin_bit_cast(float, u);
}
__device__ __forceinline__ void split8a(const float* va, bfrag* ph, bfrag* pl) {
    bfrag th, tl;
#pragma unroll
    for (int j = 0; j < 8; j++) {
        u16 hu = f2bf(va[j]);
        th[j] = (short)hu;
        tl[j] = (short)f2bf(va[j] - bf2f(hu));
    }
    *ph = th; *pl = tl;
}
// async global->LDS, 16B per lane; LDS dest = wave-uniform base + lane*16, global src per-lane
__device__ __forceinline__ void glds16(const void* g, void* l) {
    __builtin_amdgcn_global_load_lds(
        (const __attribute__((address_space(1))) unsigned int*)g,
        (__attribute__((address_space(3))) unsigned int*)l, 16, 0, 0);
}

// ---------- transpose + bf16 convert (hi/lo split) for QKV/WO weights: [K][N] -> [N][K] ----------
template<bool SPL>
__global__ __launch_bounds__(256)
void tconv_k(const float* __restrict__ src, u16* __restrict__ dhi, u16* __restrict__ dlo,
             const int K, const int N, const int rowOff, const int nTilesN)
{
    const int tid = threadIdx.x;
    const int ty = blockIdx.x / nTilesN, tx = blockIdx.x % nTilesN;
    const int k0 = ty * 64, n0 = tx * 64;
    __shared__ float tl[64][65];
#pragma unroll
    for (int it = 0; it < 16; it++) {
        int idx = tid + it * 256;
        int kk = idx >> 6, nn = idx & 63;
        tl[kk][nn] = src[(size_t)(k0 + kk) * N + n0 + nn];
    }
    __syncthreads();
#pragma unroll
    for (int it = 0; it < 8; it++) {
        int idx = tid + it * 256;
        int n = idx >> 5, k2 = (idx & 31) * 2;
        float v0 = tl[k2][n], v1 = tl[k2 + 1][n];
        u16 h0 = f2bf(v0), h1v = f2bf(v1);
        size_t o = (size_t)(rowOff + n0 + n) * K + k0 + k2;
        *(unsigned*)&dhi[o] = (unsigned)h0 | ((unsigned)h1v << 16);
        if (SPL) {
            u16 l0 = f2bf(v0 - bf2f(h0)), l1 = f2bf(v1 - bf2f(h1v));
            *(unsigned*)&dlo[o] = (unsigned)l0 | ((unsigned)l1 << 16);
        }
    }
}

// ---------- MoE weight prep: f32 [K][N] -> tiled bf16 blocks [nt][kt][128n x TBK k] ----------
template<int TBK, bool SWZ>
__global__ __launch_bounds__(256)
void tprep_k(const float* __restrict__ src, u16* __restrict__ dst,
             const int K, const int N, const int nTilesN)
{
    const int tid = threadIdx.x;
    const int e = blockIdx.y;
    const int ntl = blockIdx.x % nTilesN, kt = blockIdx.x / nTilesN;
    const int nTK = K / TBK;
    src += (size_t)e * K * N + (size_t)(kt * TBK) * N + ntl * 128;
    u16* dblk = dst + (((size_t)e * nTilesN + ntl) * nTK + kt) * (size_t)(128 * TBK);
    __shared__ float tl[TBK][132];
#pragma unroll
    for (int it = 0; it < TBK / 8; it++) {
        int i4 = tid + it * 256;
        int kk = i4 >> 5, n = (i4 & 31) * 4;
        f32x4 v = *(const f32x4*)(src + (size_t)kk * N + n);
        tl[kk][n] = v.x; tl[kk][n + 1] = v.y; tl[kk][n + 2] = v.z; tl[kk][n + 3] = v.w;
    }
    __syncthreads();
#pragma unroll
    for (int it = 0; it < TBK / 16; it++) {
        int idx = tid + it * 256;
        int n = (TBK == 32) ? (idx >> 2) : (idx >> 3);
        int c = (TBK == 32) ? (idx & 3) : (idx & 7);
        bfrag v;
#pragma unroll
        for (int j = 0; j < 8; j++) v[j] = (short)f2bf(tl[c * 8 + j][n]);
        int boff = n * (TBK * 2) + ((c * 16) ^ (SWZ ? ((n & 7) << 4) : 0));
        *(bfrag*)((char*)dblk + boff) = v;
    }
}

// ---------- RMSNorm -> split bf16 (hi/lo) ----------
__global__ __launch_bounds__(256)
void rmsnorm_split_k(const float* __restrict__ x, const float* __restrict__ w,
                     u16* __restrict__ ohi, u16* __restrict__ olo)
{
    const int row = blockIdx.x;
    const int tid = threadIdx.x;
    const int lane = tid & 63, wid = tid >> 6;
    f32x4 t4 = *(const f32x4*)(x + (size_t)row * Dd + tid * 4);
    float s = t4.x*t4.x + t4.y*t4.y + t4.z*t4.z + t4.w*t4.w;
#pragma unroll
    for (int o = 1; o < 64; o <<= 1) s += __shfl_xor(s, o, 64);
    __shared__ float red[4];
    if (lane == 0) red[wid] = s;
    __syncthreads();
    float inv = rsqrtf((red[0] + red[1] + red[2] + red[3]) * (1.0f / Dd) + 1e-6f);
    f32x4 w4 = *(const f32x4*)(w + tid * 4);
    float va[4] = { t4.x*inv*w4.x, t4.y*inv*w4.y, t4.z*inv*w4.z, t4.w*inv*w4.w };
    s16x4 hi, lo;
#pragma unroll
    for (int j = 0; j < 4; j++) {
        u16 hu = f2bf(va[j]);
        hi[j] = (short)hu;
        lo[j] = (short)f2bf(va[j] - bf2f(hu));
    }
    *(s16x4*)&ohi[(size_t)row * Dd + tid * 4] = hi;
    *(s16x4*)&olo[(size_t)row * Dd + tid * 4] = lo;
}

// ---------- RMSNorm -> f32 (router) + rounded bf16 (MoE A) ----------
__global__ __launch_bounds__(256)
void rmsnorm2_k(const float* __restrict__ x, const float* __restrict__ w,
                float* __restrict__ of, u16* __restrict__ ob)
{
    const int row = blockIdx.x;
    const int tid = threadIdx.x;
    const int lane = tid & 63, wid = tid >> 6;
    f32x4 t4 = *(const f32x4*)(x + (size_t)row * Dd + tid * 4);
    float s = t4.x*t4.x + t4.y*t4.y + t4.z*t4.z + t4.w*t4.w;
#pragma unroll
    for (int o = 1; o < 64; o <<= 1) s += __shfl_xor(s, o, 64);
    __shared__ float red[4];
    if (lane == 0) red[wid] = s;
    __syncthreads();
    float inv = rsqrtf((red[0] + red[1] + red[2] + red[3]) * (1.0f / Dd) + 1e-6f);
    f32x4 w4 = *(const f32x4*)(w + tid * 4);
    f32x4 o4;
    o4.x = t4.x*inv*w4.x; o4.y = t4.y*inv*w4.y; o4.z = t4.z*inv*w4.z; o4.w = t4.w*inv*w4.w;
    *(f32x4*)&of[(size_t)row * Dd + tid * 4] = o4;
    s16x4 hb;
    hb[0] = (short)f2bf(o4.x); hb[1] = (short)f2bf(o4.y);
    hb[2] = (short)f2bf(o4.z); hb[3] = (short)f2bf(o4.w);
    *(s16x4*)&ob[(size_t)row * Dd + tid * 4] = hb;
}

// ---------- RoPE tables (f64) ----------
__global__ __launch_bounds__(256)
void rope_tab_k(float* __restrict__ ct, float* __restrict__ st)
{
    int idx = blockIdx.x * 256 + threadIdx.x;
    if (idx < Ss * 32) {
        int s = idx >> 5, i = idx & 31;
        double inv = pow(10000.0, -((double)(2 * i)) / 64.0);
        double a = (double)s * inv;
        double sn, cs;
        sincos(a, &sn, &cs);
        ct[idx] = (float)cs;
        st[idx] = (float)sn;
    }
}

// ---------- RoPE on Q (in-place, qkv stride 1536) ----------
__global__ __launch_bounds__(256)
void rope_q_k(float* __restrict__ qkv, const float* __restrict__ ct, const float* __restrict__ st)
{
    int idx = blockIdx.x * 256 + threadIdx.x;
    int i = idx & 31, hh = (idx >> 5) & (Hh - 1), t = idx >> 9;
    int s = t & (Ss - 1);
    float cs = ct[s * 32 + i], sn = st[s * 32 + i];
    float* base = qkv + (size_t)t * 1536 + hh * 64 + i;
    float x1 = base[0], x2 = base[32];
    base[0]  = x1 * cs - x2 * sn;
    base[32] = x2 * cs + x1 * sn;
}

// ---------- K: RoPE + split bf16 ----------
__global__ __launch_bounds__(256)
void kprep_k(const float* __restrict__ qkv, const float* __restrict__ ct,
             const float* __restrict__ st, u16* __restrict__ khi, u16* __restrict__ klo)
{
    int idx = blockIdx.x * 256 + threadIdx.x;
    int i = idx & 31, hh = (idx >> 5) & (KVHn - 1), t = idx >> 7;
    int s = t & (Ss - 1);
    float cs = ct[s * 32 + i], sn = st[s * 32 + i];
    const float* base = qkv + (size_t)t * 1536 + 1024 + hh * 64 + i;
    float x1 = base[0], x2 = base[32];
    float r1 = x1 * cs - x2 * sn, r2 = x2 * cs + x1 * sn;
    size_t o = (size_t)t * (KVHn * HDn) + hh * 64 + i;
    u16 h1v = f2bf(r1), h2v = f2bf(r2);
    khi[o] = h1v;       khi[o + 32] = h2v;
    klo[o] = f2bf(r1 - bf2f(h1v));
    klo[o + 32] = f2bf(r2 - bf2f(h2v));
}

// ---------- V: transpose + split ----------
__global__ __launch_bounds__(256)
void vprep_k(const float* __restrict__ qkv, u16* __restrict__ vthi, u16* __restrict__ vtlo)
{
    const int st0 = blockIdx.x * 64;
    const int g = blockIdx.y;
    const int b = g >> 2, kvh = g & 3;
    const int tid = threadIdx.x;
    __shared__ float tl[64][65];
#pragma unroll
    for (int it = 0; it < 16; it++) {
        int idx = tid + it * 256;
        int sl = idx >> 6, d = idx & 63;
        tl[sl][d] = qkv[(size_t)(b * Ss + st0 + sl) * 1536 + 1280 + kvh * 64 + d];
    }
    __syncthreads();
#pragma unroll
    for (int it = 0; it < 8; it++) {
        int idx = tid + it * 256;
        int d = idx >> 5, s2 = (idx & 31) * 2;
        float v0 = tl[s2][d], v1 = tl[s2 + 1][d];
        u16 h0 = f2bf(v0), h1v = f2bf(v1);
        size_t o = ((size_t)g * 64 + d) * Ss + st0 + s2;
        *(unsigned*)&vthi[o] = (unsigned)h0 | ((unsigned)h1v << 16);
        u16 l0 = f2bf(v0 - bf2f(h0)), l1 = f2bf(v1 - bf2f(h1v));
        *(unsigned*)&vtlo[o] = (unsigned)l0 | ((unsigned)l1 << 16);
    }
}

// ---------- split-bf16x3 GEMM (glds + dbuf + counted vmcnt): C = A@B^T(+resid) ----------
template<bool RESID>
__global__ __launch_bounds__(256)
void gemm_split_k(const u16* __restrict__ Ahi_g, const u16* __restrict__ Alo_g,
                  const u16* __restrict__ Bhi_g, const u16* __restrict__ Blo_g,
                  float* __restrict__ C, const float* __restrict__ resid,
                  const int M, const int N, const int K, const int ntiles)
{
    const int bid = blockIdx.x;
    const int nt = bid % ntiles, mt = bid / ntiles;
    __shared__ __align__(16) u16 Ah[2][128 * 32], Al[2][128 * 32];
    __shared__ __align__(16) u16 Bh[2][128 * 32], Bl[2][128 * 32];   // 64 KB
    const int tid = threadIdx.x, lane = tid & 63, wid = tid >> 6;
    const int wrow = (wid >> 1) * 64, wcol = (wid & 1) * 64;
    const int l15 = lane & 15, lhi = lane >> 4;
    const int row0 = mt * BM, col0 = nt * BN;

    const u16 *ah_s[2], *al_s[2], *bh_s[2], *bl_s[2];
#pragma unroll
    for (int j = 0; j < 2; j++) {
        int r = (wid * 2 + j) * 16 + (lane >> 2);
        size_t ca = (size_t)(row0 + r) * K + (lane & 3) * 8;
        size_t cb = (size_t)(col0 + r) * K + (lane & 3) * 8;
        ah_s[j] = Ahi_g + ca; al_s[j] = Alo_g + ca;
        bh_s[j] = Bhi_g + cb; bl_s[j] = Blo_g + cb;
    }
    f32x4 acc[4][4];
#pragma unroll
    for (int i = 0; i < 4; i++)
#pragma unroll
        for (int j = 0; j < 4; j++) { acc[i][j].x = 0.f; acc[i][j].y = 0.f; acc[i][j].z = 0.f; acc[i][j].w = 0.f; }

    auto stage = [&](int buf, int k0) {
#pragma unroll
        for (int j = 0; j < 2; j++) {
            int d = (wid * 2 + j) * 512;
            glds16(ah_s[j] + k0, &Ah[buf][d]);
            glds16(al_s[j] + k0, &Al[buf][d]);
            glds16(bh_s[j] + k0, &Bh[buf][d]);
            glds16(bl_s[j] + k0, &Bl[buf][d]);
        }
    };
    auto compute = [&](int cur) {
        bfrag ah[4], al[4], bh[4], bl[4];
#pragma unroll
        for (int mi = 0; mi < 4; mi++) {
            int rb = (wrow + mi * 16 + l15) * 32 + lhi * 8;
            ah[mi] = *(const bfrag*)&Ah[cur][rb];
            al[mi] = *(const bfrag*)&Al[cur][rb];
        }
#pragma unroll
        for (int ni = 0; ni < 4; ni++) {
            int rb = (wcol + ni * 16 + l15) * 32 + lhi * 8;
            bh[ni] = *(const bfrag*)&Bh[cur][rb];
            bl[ni] = *(const bfrag*)&Bl[cur][rb];
        }
#pragma unroll
        for (int mi = 0; mi < 4; mi++)
#pragma unroll
            for (int ni = 0; ni < 4; ni++) {
                acc[mi][ni] = __builtin_amdgcn_mfma_f32_16x16x32_bf16(ah[mi], bh[ni], acc[mi][ni], 0, 0, 0);
                acc[mi][ni] = __builtin_amdgcn_mfma_f32_16x16x32_bf16(ah[mi], bl[ni], acc[mi][ni], 0, 0, 0);
                acc[mi][ni] = __builtin_amdgcn_mfma_f32_16x16x32_bf16(al[mi], bh[ni], acc[mi][ni], 0, 0, 0);
            }
    };
    const int nkt = K / 32;
    stage(0, 0);
    stage(1, 32);
    int cur = 0;
    for (int kt = 0; kt < nkt - 1; kt++) {
        WAITV(8);       // own tile-kt loads done; kt+1 still in flight
        BARRIER();
        compute(cur);
        BARRIER();
        if (kt + 2 < nkt) stage(cur, (kt + 2) * 32);
        cur ^= 1;
    }
    WAITV(0);
    BARRIER();
    compute(cur);
#pragma unroll
    for (int mi = 0; mi < 4; mi++) {
#pragma unroll
        for (int t = 0; t < 4; t++) {
            int pr = row0 + wrow + mi * 16 + lhi * 4 + t;
#pragma unroll
            for (int ni = 0; ni < 4; ni++) {
                int gc = col0 + wcol + ni * 16 + l15;
                float vv = acc[mi][ni][t];
                if (RESID) vv += resid[(size_t)pr * N + gc];
                C[(size_t)pr * N + gc] = vv;
            }
        }
    }
}

// ---------- MoE expert GEMM (single output): glds + dbuf + counted vmcnt, BK=32 ----------
// 1D grid, expert-per-XCD decode: e = bid&7 (XCD id), nt fastest for A-tile L2 reuse.
// MODE 0 (gate): act[ix] = bf16(acc)
// MODE 1 (up):   g = act[ix]; act[ix] = bf16(silu(g) * acc * gw)   [in-place, same thread owns ix]
template<int MODE>
__global__ __launch_bounds__(256, 4)
void gemm_expert_k(const u16* __restrict__ A_g, const u16* __restrict__ Bt,
                   u16* __restrict__ act,
                   const int* __restrict__ toklist, const float* __restrict__ gwlist,
                   const int* __restrict__ counts, const int* __restrict__ offsets)
{
    const int e = blockIdx.x & 7;          // XCD = blockIdx % 8 = expert
    const int rest = blockIdx.x >> 3;
    const int nt = rest & 31;              // nt cycles fastest -> A tile reused in L2
    const int mt = rest >> 5;
    const int Meff = counts[e];
    if (mt * BM >= Meff) return;
    const int* tok = toklist + e * Tt;
    const float* gw = gwlist + e * Tt;
    const int rowoff = offsets[e];
    __shared__ __align__(16) u16 As[2][128 * 32], Bs[2][128 * 32];   // 32 KB
    const int tid = threadIdx.x, lane = tid & 63, wid = tid >> 6;
    const int wrow = (wid >> 1) * 64, wcol = (wid & 1) * 64;
    const int l15 = lane & 15, lhi = lane >> 4;
    const int row0 = mt * BM, col0 = nt * BN;

    const u16* asrc[2];
#pragma unroll
    for (int j = 0; j < 2; j++) {
        int row = (wid * 2 + j) * 16 + (lane >> 2);
        int pr = row0 + row;
        int tr = (pr < Meff) ? tok[pr] : tok[0];
        asrc[j] = A_g + (size_t)tr * Dd + (lane & 3) * 8;
    }
    const size_t bblk = (size_t)(e * 32 + nt) * (32 * 4096);
    const u16* bsrc = Bt + bblk + (size_t)(wid * 2) * 512 + lane * 8;

    f32x4 acc[4][4];
#pragma unroll
    for (int i = 0; i < 4; i++)
#pragma unroll
        for (int j = 0; j < 4; j++) { acc[i][j].x = 0.f; acc[i][j].y = 0.f; acc[i][j].z = 0.f; acc[i][j].w = 0.f; }

    auto stage = [&](int buf, int kt) {
#pragma unroll
        for (int j = 0; j < 2; j++) {
            int d = (wid * 2 + j) * 512;
            glds16(asrc[j] + kt * 32,                  &As[buf][d]);
            glds16(bsrc + j * 512 + (size_t)kt * 4096, &Bs[buf][d]);
        }
    };
    auto compute = [&](int cur) {
        bfrag a[4];
#pragma unroll
        for (int mi = 0; mi < 4; mi++)
            a[mi] = *(const bfrag*)&As[cur][(wrow + mi * 16 + l15) * 32 + lhi * 8];
#pragma unroll
        for (int ni = 0; ni < 4; ni++) {
            bfrag b = *(const bfrag*)&Bs[cur][(wcol + ni * 16 + l15) * 32 + lhi * 8];
#pragma unroll
            for (int mi = 0; mi < 4; mi++)
                acc[mi][ni] = __builtin_amdgcn_mfma_f32_16x16x32_bf16(a[mi], b, acc[mi][ni], 0, 0, 0);
        }
    };
    stage(0, 0);
    stage(1, 1);
    int cur = 0;
    for (int kt = 0; kt < 31; kt++) {
        WAITV(4);
        BARRIER();
        compute(cur);
        BARRIER();
        if (kt + 2 < 32) stage(cur, kt + 2);
        cur ^= 1;
    }
    WAITV(0);
    BARRIER();
    compute(cur);
#pragma unroll
    for (int mi = 0; mi < 4; mi++) {
#pragma unroll
        for (int t = 0; t < 4; t++) {
            int pr = row0 + wrow + mi * 16 + lhi * 4 + t;
            if (pr < Meff) {
                float gwv = (MODE == 1) ? gw[pr] : 0.f;
#pragma unroll
                for (int ni = 0; ni < 4; ni++) {
                    int gc = col0 + wcol + ni * 16 + l15;
                    size_t ix = (size_t)(rowoff + pr) * Fn + gc;
                    if (MODE == 0) {
                        act[ix] = f2bf(acc[mi][ni][t]);
                    } else {
                        float g = bf2f(act[ix]);
                        float sg = g / (1.0f + expf(-g));
                        act[ix] = f2bf(sg * acc[mi][ni][t] * gwv);
                    }
                }
            }
        }
    }
}

// ---------- MoE down (glds + dbuf + counted vmcnt, BK=32): out[tok] += act @ Wd^T ----------
// 1D grid, expert-per-XCD decode: e = bid&7 (XCD id), nt fastest within (e,mt) for act L2 reuse.
__global__ __launch_bounds__(256, 4)
void gemm_down_k(const u16* __restrict__ act, const u16* __restrict__ Bt,
                 float* __restrict__ C, const int* __restrict__ toklist,
                 const int* __restrict__ counts, const int* __restrict__ offsets)
{
    const int e = blockIdx.x & 7;          // XCD = blockIdx % 8 = expert
    const int rest = blockIdx.x >> 3;
    const int nt = rest & 7;               // nt cycles fastest -> act slice reused in L2
    const int mt = rest >> 3;              // 0..31
    const int Meff = counts[e];
    if (mt * BM >= Meff) return;
    const int* tok = toklist + e * Tt;
    const int rowoff = offsets[e];
    __shared__ __align__(16) u16 As[2][128 * 32], Bs[2][128 * 32];   // 32 KB
    const int tid = threadIdx.x, lane = tid & 63, wid = tid >> 6;
    const int wrow = (wid >> 1) * 64, wcol = (wid & 1) * 64;
    const int l15 = lane & 15, lhi = lane >> 4;
    const int row0 = mt * BM;

    const u16* asrc[2];
#pragma unroll
    for (int j = 0; j < 2; j++) {
        int row = (wid * 2 + j) * 16 + (lane >> 2);
        int pr = row0 + row;
        int rr = (pr < Meff) ? pr : 0;
        asrc[j] = act + (size_t)(rowoff + rr) * Fn + (lane & 3) * 8;
    }
    const size_t bblk = (size_t)(e * 8 + nt) * ((size_t)128 * 4096);
    const u16* bsrc = Bt + bblk + (size_t)(wid * 2) * 512 + lane * 8;

    f32x4 acc[4][4];
#pragma unroll
    for (int i = 0; i < 4; i++)
#pragma unroll
        for (int j = 0; j < 4; j++) { acc[i][j].x = 0.f; acc[i][j].y = 0.f; acc[i][j].z = 0.f; acc[i][j].w = 0.f; }

    auto stage = [&](int buf, int kt) {
#pragma unroll
        for (int j = 0; j < 2; j++) {
            int d = (wid * 2 + j) * 512;
            glds16(asrc[j] + kt * 32,                  &As[buf][d]);
            glds16(bsrc + j * 512 + (size_t)kt * 4096, &Bs[buf][d]);
        }
    };
    auto compute = [&](int cur) {
        bfrag a[4];
#pragma unroll
        for (int mi = 0; mi < 4; mi++)
            a[mi] = *(const bfrag*)&As[cur][(wrow + mi * 16 + l15) * 32 + lhi * 8];
#pragma unroll
        for (int ni = 0; ni < 4; ni++) {
            bfrag b = *(const bfrag*)&Bs[cur][(wcol + ni * 16 + l15) * 32 + lhi * 8];
#pragma unroll
            for (int mi = 0; mi < 4; mi++)
                acc[mi][ni] = __builtin_amdgcn_mfma_f32_16x16x32_bf16(a[mi], b, acc[mi][ni], 0, 0, 0);
        }
    };
    stage(0, 0);
    stage(1, 1);
    int cur = 0;
    const int nkt = Fn / 32;   // 128
    for (int kt = 0; kt < nkt - 1; kt++) {
        WAITV(4);
        BARRIER();
        compute(cur);
        BARRIER();
        if (kt + 2 < nkt) stage(cur, kt + 2);
        cur ^= 1;
    }
    WAITV(0);
    BARRIER();
    compute(cur);
#pragma unroll
    for (int mi = 0; mi < 4; mi++) {
#pragma unroll
        for (int t = 0; t < 4; t++) {
            int pr = row0 + wrow + mi * 16 + lhi * 4 + t;
            if (pr < Meff) {
                int trow = tok[pr];
#pragma unroll
                for (int ni = 0; ni < 4; ni++) {
                    int gc = nt * BN + wcol + ni * 16 + l15;
                    atomicAdd(&C[(size_t)trow * Dd + gc], acc[mi][ni][t]);
                }
            }
        }
    }
}

// ---------- Flash attention (causal GQA), split-bf16x3, 128-row Q tile, 8 waves ----------
// Swapped QK^T/PV; K,V,P all XOR-swizzled stride-64 LDS (exactly 64 KB total).
__global__ __launch_bounds__(512)
void attn_k(const float* __restrict__ qkv, const u16* __restrict__ khi,
            const u16* __restrict__ klo, const u16* __restrict__ vthi,
            const u16* __restrict__ vtlo, u16* __restrict__ chi, u16* __restrict__ clo)
{
    const int qb = (int)gridDim.x - 1 - (int)blockIdx.x;   // 0..15, longest first
    const int h = blockIdx.y, b = blockIdx.z;
    const int kvh = h >> 2;
    const int g = b * KVHn + kvh;
    const int tid = threadIdx.x;
    const int lane = tid & 63, wid = tid >> 6;             // wid 0..7
    const int l15 = lane & 15, lhi = lane >> 4;

    __shared__ __align__(16) u16 Khi_s[64 * 64];
    __shared__ __align__(16) u16 Klo_s[64 * 64];
    __shared__ __align__(16) u16 Vhi_s[64 * 64];
    __shared__ __align__(16) u16 Vlo_s[64 * 64];
    __shared__ __align__(16) u16 Phi[128 * 64];
    __shared__ __align__(16) u16 Plo[128 * 64];            // total 65536 B

    const int qrow_g = qb * 128 + wid * 16 + l15;          // this lane's q row (swapped layout)
    bfrag qh[2], ql[2];
    {
        const float* qb_p = qkv + (size_t)(b * Ss + qrow_g) * 1536 + h * 64;
#pragma unroll
        for (int ks = 0; ks < 2; ks++) {
            const float* p = qb_p + ks * 32 + lhi * 8;
            f32x4 u0 = *(const f32x4*)p;
            f32x4 u1 = *(const f32x4*)(p + 4);
            float va[8] = { u0.x * 0.125f, u0.y * 0.125f, u0.z * 0.125f, u0.w * 0.125f,
                            u1.x * 0.125f, u1.y * 0.125f, u1.z * 0.125f, u1.w * 0.125f };
            split8a(va, &qh[ks], &ql[ks]);
        }
    }
    // staging geometry: 512 threads, one 16B chunk each; row = tid>>3, col elems = (tid&7)*8
    const int srow = tid >> 3, scol = (tid & 7) << 3;
    const size_t kga0 = (size_t)(b * Ss + srow) * (KVHn * HDn) + kvh * 64 + scol;
    const int kboff = srow * 128 + ((scol * 2) ^ ((srow & 7) << 4));
    const size_t vga0 = ((size_t)g * 64 + srow) * Ss + scol;   // V: row=d, col=kv
    const int vboff = srow * 128 + ((scol * 2) ^ ((srow & 7) << 4));

    bfrag rkh, rkl, rvh, rvl;
    auto LOADR = [&](int kt) {
        size_t ka = kga0 + (size_t)kt * (64 * KVHn * HDn);
        rkh = *(const bfrag*)&khi[ka];
        rkl = *(const bfrag*)&klo[ka];
        size_t va = vga0 + (size_t)kt * 64;
        rvh = *(const bfrag*)&vthi[va];
        rvl = *(const bfrag*)&vtlo[va];
    };
    f32x4 O[4];   // O^T: O[ni][t] = O^T[d = ni*16+lhi*4+t][q = qrow_g]
#pragma unroll
    for (int ni = 0; ni < 4; ni++) { O[ni].x = 0.f; O[ni].y = 0.f; O[ni].z = 0.f; O[ni].w = 0.f; }
    float m_s = -1e30f;
    float l_s = 0.f;

    const int nkt = 2 * qb + 2;
    LOADR(0);
    for (int kt = 0; kt < nkt; kt++) {
        // ---- write prefetched K/V regs to LDS (swizzled) ----
        *(bfrag*)((char*)Khi_s + kboff) = rkh;
        *(bfrag*)((char*)Klo_s + kboff) = rkl;
        *(bfrag*)((char*)Vhi_s + vboff) = rvh;
        *(bfrag*)((char*)Vlo_s + vboff) = rvl;
        __syncthreads();
        if (kt + 1 < nkt) LOADR(kt + 1);
        // ---- S^T = K Q^T (3-pass split): sf[ni][t] = S[kv = ni*16+lhi*4+t][q = qrow_g] ----
        f32x4 sf[4];
#pragma unroll
        for (int ni = 0; ni < 4; ni++) { sf[ni].x = 0.f; sf[ni].y = 0.f; sf[ni].z = 0.f; sf[ni].w = 0.f; }
        __builtin_amdgcn_s_setprio(1);
#pragma unroll
        for (int ks = 0; ks < 2; ks++) {
#pragma unroll
            for (int ni = 0; ni < 4; ni++) {
                int kv = ni * 16 + l15;
                int dof = ks * 64 + lhi * 16;
                int boff = kv * 128 + (dof ^ ((kv & 7) << 4));
                bfrag kfh = *(const bfrag*)((const char*)Khi_s + boff);
                bfrag kfl = *(const bfrag*)((const char*)Klo_s + boff);
                sf[ni] = __builtin_amdgcn_mfma_f32_16x16x32_bf16(kfh, qh[ks], sf[ni], 0, 0, 0);
                sf[ni] = __builtin_amdgcn_mfma_f32_16x16x32_bf16(kfl, qh[ks], sf[ni], 0, 0, 0);
                sf[ni] = __builtin_amdgcn_mfma_f32_16x16x32_bf16(kfh, ql[ks], sf[ni], 0, 0, 0);
            }
        }
        __builtin_amdgcn_s_setprio(0);
        // ---- causal mask (last two kv-tiles), global coords ----
        if (kt >= 2 * qb) {
#pragma unroll
            for (int ni = 0; ni < 4; ni++)
#pragma unroll
                for (int t = 0; t < 4; t++)
                    if (kt * 64 + ni * 16 + lhi * 4 + t > qrow_g) sf[ni][t] = -1e30f;
        }
        // ---- lane-local softmax ----
        float mx = -1e30f;
#pragma unroll
        for (int ni = 0; ni < 4; ni++)
#pragma unroll
            for (int t = 0; t < 4; t++) mx = fmaxf(mx, sf[ni][t]);
        mx = fmaxf(mx, __shfl_xor(mx, 16, 64));
        mx = fmaxf(mx, __shfl_xor(mx, 32, 64));
        float mn = fmaxf(m_s, mx);
        float sc = expf(m_s - mn);
        m_s = mn;
        float rs = 0.f;
#pragma unroll
        for (int ni = 0; ni < 4; ni++)
#pragma unroll
            for (int t = 0; t < 4; t++) {
                float p = expf(sf[ni][t] - mn);
                sf[ni][t] = p;
                rs += p;
            }
        rs += __shfl_xor(rs, 16, 64);
        rs += __shfl_xor(rs, 32, 64);
        l_s = l_s * sc + rs;
        // ---- O^T rescale (lane-local) ----
#pragma unroll
        for (int ni = 0; ni < 4; ni++)
#pragma unroll
            for (int t = 0; t < 4; t++) O[ni][t] *= sc;
        // ---- P write: row = q = wid*16+l15 (0..127), col = kv = ni*16+lhi*4+t, swizzled ----
        {
            int pr = wid * 16 + l15;
            int prx = (pr & 7) << 4;
#pragma unroll
            for (int ni = 0; ni < 4; ni++)
#pragma unroll
                for (int t = 0; t < 4; t++) {
                    float p = sf[ni][t];
                    u16 hu = f2bf(p);
                    int cb = (ni * 32 + lhi * 8 + t * 2) ^ prx;
                    int ixb = pr * 128 + cb;
                    *(u16*)((char*)Phi + ixb) = hu;
                    *(u16*)((char*)Plo + ixb) = f2bf(p - bf2f(hu));
                }
        }
        asm volatile("s_waitcnt lgkmcnt(0)" ::: "memory");
        __builtin_amdgcn_sched_barrier(0);
        // ---- O^T += V^T P^T (swapped operands; swizzled reads) ----
        __builtin_amdgcn_s_setprio(1);
#pragma unroll
        for (int ks = 0; ks < 2; ks++) {
            int pr = wid * 16 + l15;
            int pb = pr * 128 + ((ks * 64 + lhi * 16) ^ ((pr & 7) << 4));
            bfrag pfh = *(const bfrag*)((const char*)Phi + pb);
            bfrag pfl = *(const bfrag*)((const char*)Plo + pb);
#pragma unroll
            for (int ni = 0; ni < 4; ni++) {
                int d = ni * 16 + l15;
                int vb = d * 128 + ((ks * 64 + lhi * 16) ^ ((d & 7) << 4));
                bfrag vfh = *(const bfrag*)((const char*)Vhi_s + vb);
                bfrag vfl = *(const bfrag*)((const char*)Vlo_s + vb);
                O[ni] = __builtin_amdgcn_mfma_f32_16x16x32_bf16(vfh, pfh, O[ni], 0, 0, 0);
                O[ni] = __builtin_amdgcn_mfma_f32_16x16x32_bf16(vfl, pfh, O[ni], 0, 0, 0);
                O[ni] = __builtin_amdgcn_mfma_f32_16x16x32_bf16(vfh, pfl, O[ni], 0, 0, 0);
            }
        }
        __builtin_amdgcn_s_setprio(0);
        __syncthreads();
    }
    // ---- epilogue: denom lane-local; write O^T[d][q] -> ctx[q][d] ----
    {
        float inv = 1.0f / l_s;
        size_t base = (size_t)(b * Ss + qrow_g) * Dd + h * 64;
#pragma unroll
        for (int ni = 0; ni < 4; ni++)
#pragma unroll
            for (int t = 0; t < 4; t++) {
                float val = O[ni][t] * inv;
                u16 hv = f2bf(val);
                int d = ni * 16 + lhi * 4 + t;
                chi[base + d] = hv;
                clo[base + d] = f2bf(val - bf2f(hv));
            }
    }
}

// ---------- Router ----------
__global__ __launch_bounds__(256)
void router_k(const float* __restrict__ h2, const float* __restrict__ rw,
              float* __restrict__ probs, int* __restrict__ counts,
              int* __restrict__ toklist, float* __restrict__ gwlist)
{
    const int t = blockIdx.x;
    const int tid = threadIdx.x;
    const int lane = tid & 63, wid = tid >> 6;
    f32x4 x4 = *(const f32x4*)(h2 + (size_t)t * Dd + tid * 4);
    float part[En];
#pragma unroll
    for (int e = 0; e < En; e++) {
        f32x4 w4 = *(const f32x4*)(rw + (size_t)e * Dd + tid * 4);
        part[e] = x4.x * w4.x + x4.y * w4.y + x4.z * w4.z + x4.w * w4.w;
    }
#pragma unroll
    for (int e = 0; e < En; e++)
#pragma unroll
        for (int o = 1; o < 64; o <<= 1) part[e] += __shfl_xor(part[e], o, 64);
    __shared__ float red[4][En];
    if (lane == 0) {
#pragma unroll
        for (int e = 0; e < En; e++) red[wid][e] = part[e];
    }
    __syncthreads();
    if (tid == 0) {
        float lg[En];
        float mx = -1e30f;
#pragma unroll
        for (int e = 0; e < En; e++) {
            lg[e] = red[0][e] + red[1][e] + red[2][e] + red[3][e];
            mx = fmaxf(mx, lg[e]);
        }
        float pe[En], ssum = 0.f;
#pragma unroll
        for (int e = 0; e < En; e++) { pe[e] = expf(lg[e] - mx); ssum += pe[e]; }
        float inv = 1.0f / ssum;
#pragma unroll
        for (int e = 0; e < En; e++) { pe[e] *= inv; probs[(size_t)t * En + e] = pe[e]; }
        int i0 = 0;
#pragma unroll
        for (int e = 1; e < En; e++) if (pe[e] > pe[i0]) i0 = e;
        int i1 = (i0 == 0) ? 1 : 0;
#pragma unroll
        for (int e = 0; e < En; e++) if (e != i0 && pe[e] > pe[i1]) i1 = e;
        float s2 = pe[i0] + pe[i1];
        int s0 = atomicAdd(&counts[i0], 1);
        toklist[i0 * Tt + s0] = t; gwlist[i0 * Tt + s0] = pe[i0] / s2;
        int s1 = atomicAdd(&counts[i1], 1);
        toklist[i1 * Tt + s1] = t; gwlist[i1 * Tt + s1] = pe[i1] / s2;
    }
}

// ---------- offsets + balance loss ----------
__global__ __launch_bounds__(256)
void finalize_k(const float* __restrict__ probs, const int* __restrict__ counts,
                int* __restrict__ offsets, float* __restrict__ loss_out)
{
    const int tid = threadIdx.x, lane = tid & 63, wid = tid >> 6;
    float ps[En];
#pragma unroll
    for (int e = 0; e < En; e++) ps[e] = 0.f;
    for (int t = tid; t < Tt; t += 256) {
#pragma unroll
        for (int e = 0; e < En; e++) ps[e] += probs[(size_t)t * En + e];
    }
#pragma unroll
    for (int e = 0; e < En; e++)
#pragma unroll
        for (int o = 1; o < 64; o <<= 1) ps[e] += __shfl_xor(ps[e], o, 64);
    __shared__ float red[4][En];
    if (lane == 0) {
#pragma unroll
        for (int e = 0; e < En; e++) red[wid][e] = ps[e];
    }
    __syncthreads();
    if (tid == 0) {
        int o = 0;
        float bl = 0.f;
#pragma unroll
        for (int e = 0; e < En; e++) {
            offsets[e] = o; o += counts[e];
            float pm = (red[0][e] + red[1][e] + red[2][e] + red[3][e]) * (1.0f / Tt);
            float fr = (float)counts[e] * (1.0f / (Tt * 2));
            bl += fr * pm;
        }
        loss_out[0] = 0.01f * (float)En * bl;
    }
}

extern "C" void kernel_launch(void* const* d_in, const int* in_sizes, int n_in,
                              void* d_out, int out_size, void* d_ws, size_t ws_size,
                              hipStream_t stream)
{
    (void)in_sizes; (void)n_in; (void)out_size; (void)ws_size;
    const float* hs  = (const float*)d_in[0];
    const float* ln1 = (const float*)d_in[1];
    const float* wq  = (const float*)d_in[2];
    const float* wk  = (const float*)d_in[3];
    const float* wv  = (const float*)d_in[4];
    const float* wo  = (const float*)d_in[5];
    const float* ln2 = (const float*)d_in[6];
    const float* rw  = (const float*)d_in[7];
    const float* wg  = (const float*)d_in[8];
    const float* wu  = (const float*)d_in[9];
    const float* wd  = (const float*)d_in[10];
    float* out = (float*)d_out;

    char* ws = (char*)d_ws;
    size_t off = 0;
    auto nxt = [&](size_t bytes) { char* p = ws + off; off += (bytes + 255) & ~(size_t)255; return p; };
    // ---- persistent (MoE-era) region ----
    u16* wgt  = (u16*)nxt((size_t)En * Fn * Dd * 2);
    u16* wut  = (u16*)nxt((size_t)En * Fn * Dd * 2);
    u16* wdt  = (u16*)nxt((size_t)En * Dd * Fn * 2);
    float* h2 = (float*)nxt((size_t)Tt * Dd * 4);
    u16* h2b  = (u16*)nxt((size_t)Tt * Dd * 2);
    float* probs = (float*)nxt((size_t)Tt * En * 4);
    int*   tokl  = (int*)nxt((size_t)En * Tt * 4);
    float* gwl   = (float*)nxt((size_t)En * Tt * 4);
    float* ctab  = (float*)nxt((size_t)Ss * 32 * 4);
    float* stab  = (float*)nxt((size_t)Ss * 32 * 4);
    int* counts  = (int*)nxt(256);
    int* offs    = (int*)nxt(256);
    // ---- transient (pre-MoE) region; `act` aliases it ----
    u16* act = (u16*)(ws + off);
    float* qkv = (float*)nxt((size_t)Tt * 1536 * 4);
    u16* h1hi = (u16*)nxt((size_t)Tt * Dd * 2);
    u16* h1lo = (u16*)nxt((size_t)Tt * Dd * 2);
    u16* khi  = (u16*)nxt((size_t)Tt * KVHn * HDn * 2);
    u16* klo  = (u16*)nxt((size_t)Tt * KVHn * HDn * 2);
    u16* vthi = (u16*)nxt((size_t)Tt * KVHn * HDn * 2);
    u16* vtlo = (u16*)nxt((size_t)Tt * KVHn * HDn * 2);
    u16* chi  = (u16*)nxt((size_t)Tt * Dd * 2);
    u16* clo  = (u16*)nxt((size_t)Tt * Dd * 2);
    u16* wqkvthi = (u16*)nxt((size_t)1536 * Dd * 2);
    u16* wqkvtlo = (u16*)nxt((size_t)1536 * Dd * 2);
    u16* wothi = (u16*)nxt((size_t)Dd * Dd * 2);
    u16* wotlo = (u16*)nxt((size_t)Dd * Dd * 2);

    rope_tab_k<<<dim3(256), 256, 0, stream>>>(ctab, stab);
    // weight prep
    tconv_k<true ><<<dim3(16 * 16), 256, 0, stream>>>(wq, wqkvthi, wqkvtlo, 1024, 1024,    0, 16);
    tconv_k<true ><<<dim3(16 *  4), 256, 0, stream>>>(wk, wqkvthi, wqkvtlo, 1024,  256, 1024,  4);
    tconv_k<true ><<<dim3(16 *  4), 256, 0, stream>>>(wv, wqkvthi, wqkvtlo, 1024,  256, 1280,  4);
    tconv_k<true ><<<dim3(16 * 16), 256, 0, stream>>>(wo, wothi, wotlo, 1024, 1024, 0, 16);
    tprep_k<32, false><<<dim3(32 * 32, En), 256, 0, stream>>>(wg, wgt, 1024, 4096, 32);
    tprep_k<32, false><<<dim3(32 * 32, En), 256, 0, stream>>>(wu, wut, 1024, 4096, 32);
    tprep_k<32, false><<<dim3(8 * 128, En), 256, 0, stream>>>(wd, wdt, 4096, 1024, 8);

    rmsnorm_split_k<<<dim3(Tt), 256, 0, stream>>>(hs, ln1, h1hi, h1lo);
    gemm_split_k<false><<<dim3(12 * 32), 256, 0, stream>>>(h1hi, h1lo, wqkvthi, wqkvtlo,
                                                           qkv, nullptr, Tt, 1536, Dd, 12);
    rope_q_k<<<dim3(Tt * Hh * 32 / 256), 256, 0, stream>>>(qkv, ctab, stab);
    kprep_k<<<dim3(Tt * KVHn * 32 / 256), 256, 0, stream>>>(qkv, ctab, stab, khi, klo);
    vprep_k<<<dim3(Ss / 64, Bb * KVHn), 256, 0, stream>>>(qkv, vthi, vtlo);
    attn_k<<<dim3(Ss / 128, Hh, Bb), 512, 0, stream>>>(qkv, khi, klo, vthi, vtlo, chi, clo);
    gemm_split_k<true><<<dim3(8 * 32), 256, 0, stream>>>(chi, clo, wothi, wotlo,
                                                         out, hs, Tt, Dd, Dd, 8);
    rmsnorm2_k<<<dim3(Tt), 256, 0, stream>>>(out, ln2, h2, h2b);
    (void)hipMemsetAsync(counts, 0, 64, stream);
    router_k<<<dim3(Tt), 256, 0, stream>>>(h2, rw, probs, counts, tokl, gwl);
    finalize_k<<<dim3(1), 256, 0, stream>>>(probs, counts, offs, out + (size_t)Tt * Dd);
    // MoE: gate -> act ; up (in-place silu(g)*u*gw) ; down scatter-add (all expert-per-XCD)
    gemm_expert_k<0><<<dim3(8 * 32 * 32), 256, 0, stream>>>(h2b, wgt, act, tokl, gwl, counts, offs);
    gemm_expert_k<1><<<dim3(8 * 32 * 32), 256, 0, stream>>>(h2b, wut, act, tokl, gwl, counts, offs);
    gemm_down_k<<<dim3(8 * 8 * 32), 256, 0, stream>>>(act, wdt, out, tokl, counts, offs);
}

// Round 21
// 786.221 us; speedup vs baseline: 1.5011x; 1.0411x over previous
//
#include <hip/hip_runtime.h>

#define Tt 4096
#define Bb 2
#define Ss 2048
#define Dd 1024
#define Hh 16
#define KVHn 4
#define HDn 64
#define En 8
#define Fn 4096

#define BM 128
#define BN 128

typedef unsigned short u16;
typedef __attribute__((ext_vector_type(4))) float f32x4;
typedef __attribute__((ext_vector_type(8))) short bfrag;
typedef __attribute__((ext_vector_type(4))) short s16x4;

#define WAITV(N) asm volatile("s_waitcnt vmcnt(" #N ")" ::: "memory")
#define BARRIER() asm volatile("s_barrier" ::: "memory")

__device__ __forceinline__ u16 f2bf(float f) {
    unsigned u = __builtin_bit_cast(unsigned, f);
    u = (u + 0x7fffu + ((u >> 16) & 1u)) >> 16;
    return (u16)u;
}
__device__ __forceinline__ float bf2f(u16 b) {
    unsigned u = ((unsigned)b) << 16;
    return __builtin_bit_cast(float, u);
}
__device__ __forceinline__ void split8a(const float* va, bfrag* ph, bfrag* pl) {
    bfrag th, tl;
#pragma unroll
    for (int j = 0; j < 8; j++) {
        u16 hu = f2bf(va[j]);
        th[j] = (short)hu;
        tl[j] = (short)f2bf(va[j] - bf2f(hu));
    }
    *ph = th; *pl = tl;
}
// async global->LDS, 16B per lane; LDS dest = wave-uniform base + lane*16, global src per-lane
__device__ __forceinline__ void glds16(const void* g, void* l) {
    __builtin_amdgcn_global_load_lds(
        (const __attribute__((address_space(1))) unsigned int*)g,
        (__attribute__((address_space(3))) unsigned int*)l, 16, 0, 0);
}

// ---------- transpose + bf16 convert (hi/lo split) for QKV/WO weights: [K][N] -> [N][K] ----------
template<bool SPL>
__global__ __launch_bounds__(256)
void tconv_k(const float* __restrict__ src, u16* __restrict__ dhi, u16* __restrict__ dlo,
             const int K, const int N, const int rowOff, const int nTilesN)
{
    const int tid = threadIdx.x;
    const int ty = blockIdx.x / nTilesN, tx = blockIdx.x % nTilesN;
    const int k0 = ty * 64, n0 = tx * 64;
    __shared__ float tl[64][65];
#pragma unroll
    for (int it = 0; it < 16; it++) {
        int idx = tid + it * 256;
        int kk = idx >> 6, nn = idx & 63;
        tl[kk][nn] = src[(size_t)(k0 + kk) * N + n0 + nn];
    }
    __syncthreads();
#pragma unroll
    for (int it = 0; it < 8; it++) {
        int idx = tid + it * 256;
        int n = idx >> 5, k2 = (idx & 31) * 2;
        float v0 = tl[k2][n], v1 = tl[k2 + 1][n];
        u16 h0 = f2bf(v0), h1v = f2bf(v1);
        size_t o = (size_t)(rowOff + n0 + n) * K + k0 + k2;
        *(unsigned*)&dhi[o] = (unsigned)h0 | ((unsigned)h1v << 16);
        if (SPL) {
            u16 l0 = f2bf(v0 - bf2f(h0)), l1 = f2bf(v1 - bf2f(h1v));
            *(unsigned*)&dlo[o] = (unsigned)l0 | ((unsigned)l1 << 16);
        }
    }
}

// ---------- MoE weight prep: f32 [K][N] -> tiled bf16 blocks [nt][kt][128n x TBK k] ----------
template<int TBK, bool SWZ>
__global__ __launch_bounds__(256)
void tprep_k(const float* __restrict__ src, u16* __restrict__ dst,
             const int K, const int N, const int nTilesN)
{
    const int tid = threadIdx.x;
    const int e = blockIdx.y;
    const int ntl = blockIdx.x % nTilesN, kt = blockIdx.x / nTilesN;
    const int nTK = K / TBK;
    src += (size_t)e * K * N + (size_t)(kt * TBK) * N + ntl * 128;
    u16* dblk = dst + (((size_t)e * nTilesN + ntl) * nTK + kt) * (size_t)(128 * TBK);
    __shared__ float tl[TBK][132];
#pragma unroll
    for (int it = 0; it < TBK / 8; it++) {
        int i4 = tid + it * 256;
        int kk = i4 >> 5, n = (i4 & 31) * 4;
        f32x4 v = *(const f32x4*)(src + (size_t)kk * N + n);
        tl[kk][n] = v.x; tl[kk][n + 1] = v.y; tl[kk][n + 2] = v.z; tl[kk][n + 3] = v.w;
    }
    __syncthreads();
#pragma unroll
    for (int it = 0; it < TBK / 16; it++) {
        int idx = tid + it * 256;
        int n = (TBK == 32) ? (idx >> 2) : (idx >> 3);
        int c = (TBK == 32) ? (idx & 3) : (idx & 7);
        bfrag v;
#pragma unroll
        for (int j = 0; j < 8; j++) v[j] = (short)f2bf(tl[c * 8 + j][n]);
        int boff = n * (TBK * 2) + ((c * 16) ^ (SWZ ? ((n & 7) << 4) : 0));
        *(bfrag*)((char*)dblk + boff) = v;
    }
}

// ---------- RMSNorm -> split bf16 (hi/lo) ----------
__global__ __launch_bounds__(256)
void rmsnorm_split_k(const float* __restrict__ x, const float* __restrict__ w,
                     u16* __restrict__ ohi, u16* __restrict__ olo)
{
    const int row = blockIdx.x;
    const int tid = threadIdx.x;
    const int lane = tid & 63, wid = tid >> 6;
    f32x4 t4 = *(const f32x4*)(x + (size_t)row * Dd + tid * 4);
    float s = t4.x*t4.x + t4.y*t4.y + t4.z*t4.z + t4.w*t4.w;
#pragma unroll
    for (int o = 1; o < 64; o <<= 1) s += __shfl_xor(s, o, 64);
    __shared__ float red[4];
    if (lane == 0) red[wid] = s;
    __syncthreads();
    float inv = rsqrtf((red[0] + red[1] + red[2] + red[3]) * (1.0f / Dd) + 1e-6f);
    f32x4 w4 = *(const f32x4*)(w + tid * 4);
    float va[4] = { t4.x*inv*w4.x, t4.y*inv*w4.y, t4.z*inv*w4.z, t4.w*inv*w4.w };
    s16x4 hi, lo;
#pragma unroll
    for (int j = 0; j < 4; j++) {
        u16 hu = f2bf(va[j]);
        hi[j] = (short)hu;
        lo[j] = (short)f2bf(va[j] - bf2f(hu));
    }
    *(s16x4*)&ohi[(size_t)row * Dd + tid * 4] = hi;
    *(s16x4*)&olo[(size_t)row * Dd + tid * 4] = lo;
}

// ---------- RMSNorm -> f32 (router) + rounded bf16 (MoE A) ----------
__global__ __launch_bounds__(256)
void rmsnorm2_k(const float* __restrict__ x, const float* __restrict__ w,
                float* __restrict__ of, u16* __restrict__ ob)
{
    const int row = blockIdx.x;
    const int tid = threadIdx.x;
    const int lane = tid & 63, wid = tid >> 6;
    f32x4 t4 = *(const f32x4*)(x + (size_t)row * Dd + tid * 4);
    float s = t4.x*t4.x + t4.y*t4.y + t4.z*t4.z + t4.w*t4.w;
#pragma unroll
    for (int o = 1; o < 64; o <<= 1) s += __shfl_xor(s, o, 64);
    __shared__ float red[4];
    if (lane == 0) red[wid] = s;
    __syncthreads();
    float inv = rsqrtf((red[0] + red[1] + red[2] + red[3]) * (1.0f / Dd) + 1e-6f);
    f32x4 w4 = *(const f32x4*)(w + tid * 4);
    f32x4 o4;
    o4.x = t4.x*inv*w4.x; o4.y = t4.y*inv*w4.y; o4.z = t4.z*inv*w4.z; o4.w = t4.w*inv*w4.w;
    *(f32x4*)&of[(size_t)row * Dd + tid * 4] = o4;
    s16x4 hb;
    hb[0] = (short)f2bf(o4.x); hb[1] = (short)f2bf(o4.y);
    hb[2] = (short)f2bf(o4.z); hb[3] = (short)f2bf(o4.w);
    *(s16x4*)&ob[(size_t)row * Dd + tid * 4] = hb;
}

// ---------- RoPE tables (f64) ----------
__global__ __launch_bounds__(256)
void rope_tab_k(float* __restrict__ ct, float* __restrict__ st)
{
    int idx = blockIdx.x * 256 + threadIdx.x;
    if (idx < Ss * 32) {
        int s = idx >> 5, i = idx & 31;
        double inv = pow(10000.0, -((double)(2 * i)) / 64.0);
        double a = (double)s * inv;
        double sn, cs;
        sincos(a, &sn, &cs);
        ct[idx] = (float)cs;
        st[idx] = (float)sn;
    }
}

// ---------- RoPE on Q (in-place, qkv stride 1536) ----------
__global__ __launch_bounds__(256)
void rope_q_k(float* __restrict__ qkv, const float* __restrict__ ct, const float* __restrict__ st)
{
    int idx = blockIdx.x * 256 + threadIdx.x;
    int i = idx & 31, hh = (idx >> 5) & (Hh - 1), t = idx >> 9;
    int s = t & (Ss - 1);
    float cs = ct[s * 32 + i], sn = st[s * 32 + i];
    float* base = qkv + (size_t)t * 1536 + hh * 64 + i;
    float x1 = base[0], x2 = base[32];
    base[0]  = x1 * cs - x2 * sn;
    base[32] = x2 * cs + x1 * sn;
}

// ---------- K: RoPE + split bf16 ----------
__global__ __launch_bounds__(256)
void kprep_k(const float* __restrict__ qkv, const float* __restrict__ ct,
             const float* __restrict__ st, u16* __restrict__ khi, u16* __restrict__ klo)
{
    int idx = blockIdx.x * 256 + threadIdx.x;
    int i = idx & 31, hh = (idx >> 5) & (KVHn - 1), t = idx >> 7;
    int s = t & (Ss - 1);
    float cs = ct[s * 32 + i], sn = st[s * 32 + i];
    const float* base = qkv + (size_t)t * 1536 + 1024 + hh * 64 + i;
    float x1 = base[0], x2 = base[32];
    float r1 = x1 * cs - x2 * sn, r2 = x2 * cs + x1 * sn;
    size_t o = (size_t)t * (KVHn * HDn) + hh * 64 + i;
    u16 h1v = f2bf(r1), h2v = f2bf(r2);
    khi[o] = h1v;       khi[o + 32] = h2v;
    klo[o] = f2bf(r1 - bf2f(h1v));
    klo[o + 32] = f2bf(r2 - bf2f(h2v));
}

// ---------- V: transpose + split ----------
__global__ __launch_bounds__(256)
void vprep_k(const float* __restrict__ qkv, u16* __restrict__ vthi, u16* __restrict__ vtlo)
{
    const int st0 = blockIdx.x * 64;
    const int g = blockIdx.y;
    const int b = g >> 2, kvh = g & 3;
    const int tid = threadIdx.x;
    __shared__ float tl[64][65];
#pragma unroll
    for (int it = 0; it < 16; it++) {
        int idx = tid + it * 256;
        int sl = idx >> 6, d = idx & 63;
        tl[sl][d] = qkv[(size_t)(b * Ss + st0 + sl) * 1536 + 1280 + kvh * 64 + d];
    }
    __syncthreads();
#pragma unroll
    for (int it = 0; it < 8; it++) {
        int idx = tid + it * 256;
        int d = idx >> 5, s2 = (idx & 31) * 2;
        float v0 = tl[s2][d], v1 = tl[s2 + 1][d];
        u16 h0 = f2bf(v0), h1v = f2bf(v1);
        size_t o = ((size_t)g * 64 + d) * Ss + st0 + s2;
        *(unsigned*)&vthi[o] = (unsigned)h0 | ((unsigned)h1v << 16);
        u16 l0 = f2bf(v0 - bf2f(h0)), l1 = f2bf(v1 - bf2f(h1v));
        *(unsigned*)&vtlo[o] = (unsigned)l0 | ((unsigned)l1 << 16);
    }
}

// ---------- split-bf16x3 GEMM (glds + dbuf + counted vmcnt): C = A@B^T(+resid) ----------
template<bool RESID>
__global__ __launch_bounds__(256)
void gemm_split_k(const u16* __restrict__ Ahi_g, const u16* __restrict__ Alo_g,
                  const u16* __restrict__ Bhi_g, const u16* __restrict__ Blo_g,
                  float* __restrict__ C, const float* __restrict__ resid,
                  const int M, const int N, const int K, const int ntiles)
{
    const int bid = blockIdx.x;
    const int nt = bid % ntiles, mt = bid / ntiles;
    __shared__ __align__(16) u16 Ah[2][128 * 32], Al[2][128 * 32];
    __shared__ __align__(16) u16 Bh[2][128 * 32], Bl[2][128 * 32];   // 64 KB
    const int tid = threadIdx.x, lane = tid & 63, wid = tid >> 6;
    const int wrow = (wid >> 1) * 64, wcol = (wid & 1) * 64;
    const int l15 = lane & 15, lhi = lane >> 4;
    const int row0 = mt * BM, col0 = nt * BN;

    const u16 *ah_s[2], *al_s[2], *bh_s[2], *bl_s[2];
#pragma unroll
    for (int j = 0; j < 2; j++) {
        int r = (wid * 2 + j) * 16 + (lane >> 2);
        size_t ca = (size_t)(row0 + r) * K + (lane & 3) * 8;
        size_t cb = (size_t)(col0 + r) * K + (lane & 3) * 8;
        ah_s[j] = Ahi_g + ca; al_s[j] = Alo_g + ca;
        bh_s[j] = Bhi_g + cb; bl_s[j] = Blo_g + cb;
    }
    f32x4 acc[4][4];
#pragma unroll
    for (int i = 0; i < 4; i++)
#pragma unroll
        for (int j = 0; j < 4; j++) { acc[i][j].x = 0.f; acc[i][j].y = 0.f; acc[i][j].z = 0.f; acc[i][j].w = 0.f; }

    auto stage = [&](int buf, int k0) {
#pragma unroll
        for (int j = 0; j < 2; j++) {
            int d = (wid * 2 + j) * 512;
            glds16(ah_s[j] + k0, &Ah[buf][d]);
            glds16(al_s[j] + k0, &Al[buf][d]);
            glds16(bh_s[j] + k0, &Bh[buf][d]);
            glds16(bl_s[j] + k0, &Bl[buf][d]);
        }
    };
    auto compute = [&](int cur) {
        bfrag ah[4], al[4], bh[4], bl[4];
#pragma unroll
        for (int mi = 0; mi < 4; mi++) {
            int rb = (wrow + mi * 16 + l15) * 32 + lhi * 8;
            ah[mi] = *(const bfrag*)&Ah[cur][rb];
            al[mi] = *(const bfrag*)&Al[cur][rb];
        }
#pragma unroll
        for (int ni = 0; ni < 4; ni++) {
            int rb = (wcol + ni * 16 + l15) * 32 + lhi * 8;
            bh[ni] = *(const bfrag*)&Bh[cur][rb];
            bl[ni] = *(const bfrag*)&Bl[cur][rb];
        }
#pragma unroll
        for (int mi = 0; mi < 4; mi++)
#pragma unroll
            for (int ni = 0; ni < 4; ni++) {
                acc[mi][ni] = __builtin_amdgcn_mfma_f32_16x16x32_bf16(ah[mi], bh[ni], acc[mi][ni], 0, 0, 0);
                acc[mi][ni] = __builtin_amdgcn_mfma_f32_16x16x32_bf16(ah[mi], bl[ni], acc[mi][ni], 0, 0, 0);
                acc[mi][ni] = __builtin_amdgcn_mfma_f32_16x16x32_bf16(al[mi], bh[ni], acc[mi][ni], 0, 0, 0);
            }
    };
    const int nkt = K / 32;
    stage(0, 0);
    stage(1, 32);
    int cur = 0;
    for (int kt = 0; kt < nkt - 1; kt++) {
        WAITV(8);       // own tile-kt loads done; kt+1 still in flight
        BARRIER();
        compute(cur);
        BARRIER();
        if (kt + 2 < nkt) stage(cur, (kt + 2) * 32);
        cur ^= 1;
    }
    WAITV(0);
    BARRIER();
    compute(cur);
#pragma unroll
    for (int mi = 0; mi < 4; mi++) {
#pragma unroll
        for (int t = 0; t < 4; t++) {
            int pr = row0 + wrow + mi * 16 + lhi * 4 + t;
#pragma unroll
            for (int ni = 0; ni < 4; ni++) {
                int gc = col0 + wcol + ni * 16 + l15;
                float vv = acc[mi][ni][t];
                if (RESID) vv += resid[(size_t)pr * N + gc];
                C[(size_t)pr * N + gc] = vv;
            }
        }
    }
}

// ---------- MoE expert GEMM (single output): glds + dbuf + counted vmcnt, BK=32 ----------
// 1D grid, expert-per-XCD decode: e = bid&7 (XCD id), nt fastest for A-tile L2 reuse.
// MODE 0 (gate): act[ix] = bf16(acc)
// MODE 1 (up):   g = act[ix]; act[ix] = bf16(silu(g) * acc * gw)   [in-place, same thread owns ix]
template<int MODE>
__global__ __launch_bounds__(256, 4)
void gemm_expert_k(const u16* __restrict__ A_g, const u16* __restrict__ Bt,
                   u16* __restrict__ act,
                   const int* __restrict__ toklist, const float* __restrict__ gwlist,
                   const int* __restrict__ counts, const int* __restrict__ offsets)
{
    const int e = blockIdx.x & 7;          // XCD = blockIdx % 8 = expert
    const int rest = blockIdx.x >> 3;
    const int nt = rest & 31;              // nt cycles fastest -> A tile reused in L2
    const int mt = rest >> 5;
    const int Meff = counts[e];
    if (mt * BM >= Meff) return;
    const int* tok = toklist + e * Tt;
    const float* gw = gwlist + e * Tt;
    const int rowoff = offsets[e];
    __shared__ __align__(16) u16 As[2][128 * 32], Bs[2][128 * 32];   // 32 KB
    const int tid = threadIdx.x, lane = tid & 63, wid = tid >> 6;
    const int wrow = (wid >> 1) * 64, wcol = (wid & 1) * 64;
    const int l15 = lane & 15, lhi = lane >> 4;
    const int row0 = mt * BM, col0 = nt * BN;

    const u16* asrc[2];
#pragma unroll
    for (int j = 0; j < 2; j++) {
        int row = (wid * 2 + j) * 16 + (lane >> 2);
        int pr = row0 + row;
        int tr = (pr < Meff) ? tok[pr] : tok[0];
        asrc[j] = A_g + (size_t)tr * Dd + (lane & 3) * 8;
    }
    const size_t bblk = (size_t)(e * 32 + nt) * (32 * 4096);
    const u16* bsrc = Bt + bblk + (size_t)(wid * 2) * 512 + lane * 8;

    f32x4 acc[4][4];
#pragma unroll
    for (int i = 0; i < 4; i++)
#pragma unroll
        for (int j = 0; j < 4; j++) { acc[i][j].x = 0.f; acc[i][j].y = 0.f; acc[i][j].z = 0.f; acc[i][j].w = 0.f; }

    auto stage = [&](int buf, int kt) {
#pragma unroll
        for (int j = 0; j < 2; j++) {
            int d = (wid * 2 + j) * 512;
            glds16(asrc[j] + kt * 32,                  &As[buf][d]);
            glds16(bsrc + j * 512 + (size_t)kt * 4096, &Bs[buf][d]);
        }
    };
    auto compute = [&](int cur) {
        bfrag a[4];
#pragma unroll
        for (int mi = 0; mi < 4; mi++)
            a[mi] = *(const bfrag*)&As[cur][(wrow + mi * 16 + l15) * 32 + lhi * 8];
#pragma unroll
        for (int ni = 0; ni < 4; ni++) {
            bfrag b = *(const bfrag*)&Bs[cur][(wcol + ni * 16 + l15) * 32 + lhi * 8];
#pragma unroll
            for (int mi = 0; mi < 4; mi++)
                acc[mi][ni] = __builtin_amdgcn_mfma_f32_16x16x32_bf16(a[mi], b, acc[mi][ni], 0, 0, 0);
        }
    };
    stage(0, 0);
    stage(1, 1);
    int cur = 0;
    for (int kt = 0; kt < 31; kt++) {
        WAITV(4);
        BARRIER();
        compute(cur);
        BARRIER();
        if (kt + 2 < 32) stage(cur, kt + 2);
        cur ^= 1;
    }
    WAITV(0);
    BARRIER();
    compute(cur);
#pragma unroll
    for (int mi = 0; mi < 4; mi++) {
#pragma unroll
        for (int t = 0; t < 4; t++) {
            int pr = row0 + wrow + mi * 16 + lhi * 4 + t;
            if (pr < Meff) {
                float gwv = (MODE == 1) ? gw[pr] : 0.f;
#pragma unroll
                for (int ni = 0; ni < 4; ni++) {
                    int gc = col0 + wcol + ni * 16 + l15;
                    size_t ix = (size_t)(rowoff + pr) * Fn + gc;
                    if (MODE == 0) {
                        act[ix] = f2bf(acc[mi][ni][t]);
                    } else {
                        float g = bf2f(act[ix]);
                        float sg = g / (1.0f + __expf(-g));
                        act[ix] = f2bf(sg * acc[mi][ni][t] * gwv);
                    }
                }
            }
        }
    }
}

// ---------- MoE down (glds + dbuf + counted vmcnt, BK=32): out[tok] += act @ Wd^T ----------
// 1D grid, expert-per-XCD decode: e = bid&7 (XCD id), nt fastest within (e,mt) for act L2 reuse.
__global__ __launch_bounds__(256, 4)
void gemm_down_k(const u16* __restrict__ act, const u16* __restrict__ Bt,
                 float* __restrict__ C, const int* __restrict__ toklist,
                 const int* __restrict__ counts, const int* __restrict__ offsets)
{
    const int e = blockIdx.x & 7;          // XCD = blockIdx % 8 = expert
    const int rest = blockIdx.x >> 3;
    const int nt = rest & 7;               // nt cycles fastest -> act slice reused in L2
    const int mt = rest >> 3;              // 0..31
    const int Meff = counts[e];
    if (mt * BM >= Meff) return;
    const int* tok = toklist + e * Tt;
    const int rowoff = offsets[e];
    __shared__ __align__(16) u16 As[2][128 * 32], Bs[2][128 * 32];   // 32 KB
    const int tid = threadIdx.x, lane = tid & 63, wid = tid >> 6;
    const int wrow = (wid >> 1) * 64, wcol = (wid & 1) * 64;
    const int l15 = lane & 15, lhi = lane >> 4;
    const int row0 = mt * BM;

    const u16* asrc[2];
#pragma unroll
    for (int j = 0; j < 2; j++) {
        int row = (wid * 2 + j) * 16 + (lane >> 2);
        int pr = row0 + row;
        int rr = (pr < Meff) ? pr : 0;
        asrc[j] = act + (size_t)(rowoff + rr) * Fn + (lane & 3) * 8;
    }
    const size_t bblk = (size_t)(e * 8 + nt) * ((size_t)128 * 4096);
    const u16* bsrc = Bt + bblk + (size_t)(wid * 2) * 512 + lane * 8;

    f32x4 acc[4][4];
#pragma unroll
    for (int i = 0; i < 4; i++)
#pragma unroll
        for (int j = 0; j < 4; j++) { acc[i][j].x = 0.f; acc[i][j].y = 0.f; acc[i][j].z = 0.f; acc[i][j].w = 0.f; }

    auto stage = [&](int buf, int kt) {
#pragma unroll
        for (int j = 0; j < 2; j++) {
            int d = (wid * 2 + j) * 512;
            glds16(asrc[j] + kt * 32,                  &As[buf][d]);
            glds16(bsrc + j * 512 + (size_t)kt * 4096, &Bs[buf][d]);
        }
    };
    auto compute = [&](int cur) {
        bfrag a[4];
#pragma unroll
        for (int mi = 0; mi < 4; mi++)
            a[mi] = *(const bfrag*)&As[cur][(wrow + mi * 16 + l15) * 32 + lhi * 8];
#pragma unroll
        for (int ni = 0; ni < 4; ni++) {
            bfrag b = *(const bfrag*)&Bs[cur][(wcol + ni * 16 + l15) * 32 + lhi * 8];
#pragma unroll
            for (int mi = 0; mi < 4; mi++)
                acc[mi][ni] = __builtin_amdgcn_mfma_f32_16x16x32_bf16(a[mi], b, acc[mi][ni], 0, 0, 0);
        }
    };
    stage(0, 0);
    stage(1, 1);
    int cur = 0;
    const int nkt = Fn / 32;   // 128
    for (int kt = 0; kt < nkt - 1; kt++) {
        WAITV(4);
        BARRIER();
        compute(cur);
        BARRIER();
        if (kt + 2 < nkt) stage(cur, kt + 2);
        cur ^= 1;
    }
    WAITV(0);
    BARRIER();
    compute(cur);
#pragma unroll
    for (int mi = 0; mi < 4; mi++) {
#pragma unroll
        for (int t = 0; t < 4; t++) {
            int pr = row0 + wrow + mi * 16 + lhi * 4 + t;
            if (pr < Meff) {
                int trow = tok[pr];
#pragma unroll
                for (int ni = 0; ni < 4; ni++) {
                    int gc = nt * BN + wcol + ni * 16 + l15;
                    atomicAdd(&C[(size_t)trow * Dd + gc], acc[mi][ni][t]);
                }
            }
        }
    }
}

// ---------- Flash attention (causal GQA), split-bf16x3, 128-row Q tile, 8 waves ----------
// Swapped QK^T/PV; K,V,P all XOR-swizzled stride-64 LDS (exactly 64 KB total).
// VALU diet: __expf softmax (hw v_exp_f32), packed b64 P writes, packed epilogue stores.
__global__ __launch_bounds__(512)
void attn_k(const float* __restrict__ qkv, const u16* __restrict__ khi,
            const u16* __restrict__ klo, const u16* __restrict__ vthi,
            const u16* __restrict__ vtlo, u16* __restrict__ chi, u16* __restrict__ clo)
{
    const int qb = (int)gridDim.x - 1 - (int)blockIdx.x;   // 0..15, longest first
    const int h = blockIdx.y, b = blockIdx.z;
    const int kvh = h >> 2;
    const int g = b * KVHn + kvh;
    const int tid = threadIdx.x;
    const int lane = tid & 63, wid = tid >> 6;             // wid 0..7
    const int l15 = lane & 15, lhi = lane >> 4;

    __shared__ __align__(16) u16 Khi_s[64 * 64];
    __shared__ __align__(16) u16 Klo_s[64 * 64];
    __shared__ __align__(16) u16 Vhi_s[64 * 64];
    __shared__ __align__(16) u16 Vlo_s[64 * 64];
    __shared__ __align__(16) u16 Phi[128 * 64];
    __shared__ __align__(16) u16 Plo[128 * 64];            // total 65536 B

    const int qrow_g = qb * 128 + wid * 16 + l15;          // this lane's q row (swapped layout)
    bfrag qh[2], ql[2];
    {
        const float* qb_p = qkv + (size_t)(b * Ss + qrow_g) * 1536 + h * 64;
#pragma unroll
        for (int ks = 0; ks < 2; ks++) {
            const float* p = qb_p + ks * 32 + lhi * 8;
            f32x4 u0 = *(const f32x4*)p;
            f32x4 u1 = *(const f32x4*)(p + 4);
            float va[8] = { u0.x * 0.125f, u0.y * 0.125f, u0.z * 0.125f, u0.w * 0.125f,
                            u1.x * 0.125f, u1.y * 0.125f, u1.z * 0.125f, u1.w * 0.125f };
            split8a(va, &qh[ks], &ql[ks]);
        }
    }
    // staging geometry: 512 threads, one 16B chunk each; row = tid>>3, col elems = (tid&7)*8
    const int srow = tid >> 3, scol = (tid & 7) << 3;
    const size_t kga0 = (size_t)(b * Ss + srow) * (KVHn * HDn) + kvh * 64 + scol;
    const int kboff = srow * 128 + ((scol * 2) ^ ((srow & 7) << 4));
    const size_t vga0 = ((size_t)g * 64 + srow) * Ss + scol;   // V: row=d, col=kv
    const int vboff = srow * 128 + ((scol * 2) ^ ((srow & 7) << 4));

    bfrag rkh, rkl, rvh, rvl;
    auto LOADR = [&](int kt) {
        size_t ka = kga0 + (size_t)kt * (64 * KVHn * HDn);
        rkh = *(const bfrag*)&khi[ka];
        rkl = *(const bfrag*)&klo[ka];
        size_t va = vga0 + (size_t)kt * 64;
        rvh = *(const bfrag*)&vthi[va];
        rvl = *(const bfrag*)&vtlo[va];
    };
    f32x4 O[4];   // O^T: O[ni][t] = O^T[d = ni*16+lhi*4+t][q = qrow_g]
#pragma unroll
    for (int ni = 0; ni < 4; ni++) { O[ni].x = 0.f; O[ni].y = 0.f; O[ni].z = 0.f; O[ni].w = 0.f; }
    float m_s = -1e30f;
    float l_s = 0.f;

    const int nkt = 2 * qb + 2;
    LOADR(0);
    for (int kt = 0; kt < nkt; kt++) {
        // ---- write prefetched K/V regs to LDS (swizzled) ----
        *(bfrag*)((char*)Khi_s + kboff) = rkh;
        *(bfrag*)((char*)Klo_s + kboff) = rkl;
        *(bfrag*)((char*)Vhi_s + vboff) = rvh;
        *(bfrag*)((char*)Vlo_s + vboff) = rvl;
        __syncthreads();
        if (kt + 1 < nkt) LOADR(kt + 1);
        // ---- S^T = K Q^T (3-pass split): sf[ni][t] = S[kv = ni*16+lhi*4+t][q = qrow_g] ----
        f32x4 sf[4];
#pragma unroll
        for (int ni = 0; ni < 4; ni++) { sf[ni].x = 0.f; sf[ni].y = 0.f; sf[ni].z = 0.f; sf[ni].w = 0.f; }
        __builtin_amdgcn_s_setprio(1);
#pragma unroll
        for (int ks = 0; ks < 2; ks++) {
#pragma unroll
            for (int ni = 0; ni < 4; ni++) {
                int kv = ni * 16 + l15;
                int dof = ks * 64 + lhi * 16;
                int boff = kv * 128 + (dof ^ ((kv & 7) << 4));
                bfrag kfh = *(const bfrag*)((const char*)Khi_s + boff);
                bfrag kfl = *(const bfrag*)((const char*)Klo_s + boff);
                sf[ni] = __builtin_amdgcn_mfma_f32_16x16x32_bf16(kfh, qh[ks], sf[ni], 0, 0, 0);
                sf[ni] = __builtin_amdgcn_mfma_f32_16x16x32_bf16(kfl, qh[ks], sf[ni], 0, 0, 0);
                sf[ni] = __builtin_amdgcn_mfma_f32_16x16x32_bf16(kfh, ql[ks], sf[ni], 0, 0, 0);
            }
        }
        __builtin_amdgcn_s_setprio(0);
        // ---- causal mask (last two kv-tiles), global coords ----
        if (kt >= 2 * qb) {
#pragma unroll
            for (int ni = 0; ni < 4; ni++)
#pragma unroll
                for (int t = 0; t < 4; t++)
                    if (kt * 64 + ni * 16 + lhi * 4 + t > qrow_g) sf[ni][t] = -1e30f;
        }
        // ---- lane-local softmax (fast hw exp) ----
        float mx = -1e30f;
#pragma unroll
        for (int ni = 0; ni < 4; ni++)
#pragma unroll
            for (int t = 0; t < 4; t++) mx = fmaxf(mx, sf[ni][t]);
        mx = fmaxf(mx, __shfl_xor(mx, 16, 64));
        mx = fmaxf(mx, __shfl_xor(mx, 32, 64));
        float mn = fmaxf(m_s, mx);
        float sc = __expf(m_s - mn);
        m_s = mn;
        float rs = 0.f;
#pragma unroll
        for (int ni = 0; ni < 4; ni++)
#pragma unroll
            for (int t = 0; t < 4; t++) {
                float p = __expf(sf[ni][t] - mn);
                sf[ni][t] = p;
                rs += p;
            }
        rs += __shfl_xor(rs, 16, 64);
        rs += __shfl_xor(rs, 32, 64);
        l_s = l_s * sc + rs;
        // ---- O^T rescale (lane-local) ----
#pragma unroll
        for (int ni = 0; ni < 4; ni++)
#pragma unroll
            for (int t = 0; t < 4; t++) O[ni][t] *= sc;
        // ---- P write: packed b64 per (ni); t-slots are 8 contiguous bytes, XOR uniform ----
        {
            int pr = wid * 16 + l15;
            int prx = (pr & 7) << 4;
#pragma unroll
            for (int ni = 0; ni < 4; ni++) {
                s16x4 h4, l4;
#pragma unroll
                for (int t = 0; t < 4; t++) {
                    float p = sf[ni][t];
                    u16 hu = f2bf(p);
                    h4[t] = (short)hu;
                    l4[t] = (short)f2bf(p - bf2f(hu));
                }
                int pb0 = pr * 128 + ((ni * 32 + lhi * 8) ^ prx);
                *(s16x4*)((char*)Phi + pb0) = h4;
                *(s16x4*)((char*)Plo + pb0) = l4;
            }
        }
        asm volatile("s_waitcnt lgkmcnt(0)" ::: "memory");
        __builtin_amdgcn_sched_barrier(0);
        // ---- O^T += V^T P^T (swapped operands; swizzled reads) ----
        __builtin_amdgcn_s_setprio(1);
#pragma unroll
        for (int ks = 0; ks < 2; ks++) {
            int pr = wid * 16 + l15;
            int pb = pr * 128 + ((ks * 64 + lhi * 16) ^ ((pr & 7) << 4));
            bfrag pfh = *(const bfrag*)((const char*)Phi + pb);
            bfrag pfl = *(const bfrag*)((const char*)Plo + pb);
#pragma unroll
            for (int ni = 0; ni < 4; ni++) {
                int d = ni * 16 + l15;
                int vb = d * 128 + ((ks * 64 + lhi * 16) ^ ((d & 7) << 4));
                bfrag vfh = *(const bfrag*)((const char*)Vhi_s + vb);
                bfrag vfl = *(const bfrag*)((const char*)Vlo_s + vb);
                O[ni] = __builtin_amdgcn_mfma_f32_16x16x32_bf16(vfh, pfh, O[ni], 0, 0, 0);
                O[ni] = __builtin_amdgcn_mfma_f32_16x16x32_bf16(vfl, pfh, O[ni], 0, 0, 0);
                O[ni] = __builtin_amdgcn_mfma_f32_16x16x32_bf16(vfh, pfl, O[ni], 0, 0, 0);
            }
        }
        __builtin_amdgcn_s_setprio(0);
        __syncthreads();
    }
    // ---- epilogue: denom lane-local; write O^T[d][q] -> ctx[q][d], packed 4-wide ----
    {
        float inv = 1.0f / l_s;
        size_t base = (size_t)(b * Ss + qrow_g) * Dd + h * 64;
#pragma unroll
        for (int ni = 0; ni < 4; ni++) {
            s16x4 h4, l4;
#pragma unroll
            for (int t = 0; t < 4; t++) {
                float val = O[ni][t] * inv;
                u16 hv = f2bf(val);
                h4[t] = (short)hv;
                l4[t] = (short)f2bf(val - bf2f(hv));
            }
            size_t d0 = base + ni * 16 + lhi * 4;
            *(s16x4*)&chi[d0] = h4;
            *(s16x4*)&clo[d0] = l4;
        }
    }
}

// ---------- Router ----------
__global__ __launch_bounds__(256)
void router_k(const float* __restrict__ h2, const float* __restrict__ rw,
              float* __restrict__ probs, int* __restrict__ counts,
              int* __restrict__ toklist, float* __restrict__ gwlist)
{
    const int t = blockIdx.x;
    const int tid = threadIdx.x;
    const int lane = tid & 63, wid = tid >> 6;
    f32x4 x4 = *(const f32x4*)(h2 + (size_t)t * Dd + tid * 4);
    float part[En];
#pragma unroll
    for (int e = 0; e < En; e++) {
        f32x4 w4 = *(const f32x4*)(rw + (size_t)e * Dd + tid * 4);
        part[e] = x4.x * w4.x + x4.y * w4.y + x4.z * w4.z + x4.w * w4.w;
    }
#pragma unroll
    for (int e = 0; e < En; e++)
#pragma unroll
        for (int o = 1; o < 64; o <<= 1) part[e] += __shfl_xor(part[e], o, 64);
    __shared__ float red[4][En];
    if (lane == 0) {
#pragma unroll
        for (int e = 0; e < En; e++) red[wid][e] = part[e];
    }
    __syncthreads();
    if (tid == 0) {
        float lg[En];
        float mx = -1e30f;
#pragma unroll
        for (int e = 0; e < En; e++) {
            lg[e] = red[0][e] + red[1][e] + red[2][e] + red[3][e];
            mx = fmaxf(mx, lg[e]);
        }
        float pe[En], ssum = 0.f;
#pragma unroll
        for (int e = 0; e < En; e++) { pe[e] = expf(lg[e] - mx); ssum += pe[e]; }
        float inv = 1.0f / ssum;
#pragma unroll
        for (int e = 0; e < En; e++) { pe[e] *= inv; probs[(size_t)t * En + e] = pe[e]; }
        int i0 = 0;
#pragma unroll
        for (int e = 1; e < En; e++) if (pe[e] > pe[i0]) i0 = e;
        int i1 = (i0 == 0) ? 1 : 0;
#pragma unroll
        for (int e = 0; e < En; e++) if (e != i0 && pe[e] > pe[i1]) i1 = e;
        float s2 = pe[i0] + pe[i1];
        int s0 = atomicAdd(&counts[i0], 1);
        toklist[i0 * Tt + s0] = t; gwlist[i0 * Tt + s0] = pe[i0] / s2;
        int s1 = atomicAdd(&counts[i1], 1);
        toklist[i1 * Tt + s1] = t; gwlist[i1 * Tt + s1] = pe[i1] / s2;
    }
}

// ---------- offsets + balance loss ----------
__global__ __launch_bounds__(256)
void finalize_k(const float* __restrict__ probs, const int* __restrict__ counts,
                int* __restrict__ offsets, float* __restrict__ loss_out)
{
    const int tid = threadIdx.x, lane = tid & 63, wid = tid >> 6;
    float ps[En];
#pragma unroll
    for (int e = 0; e < En; e++) ps[e] = 0.f;
    for (int t = tid; t < Tt; t += 256) {
#pragma unroll
        for (int e = 0; e < En; e++) ps[e] += probs[(size_t)t * En + e];
    }
#pragma unroll
    for (int e = 0; e < En; e++)
#pragma unroll
        for (int o = 1; o < 64; o <<= 1) ps[e] += __shfl_xor(ps[e], o, 64);
    __shared__ float red[4][En];
    if (lane == 0) {
#pragma unroll
        for (int e = 0; e < En; e++) red[wid][e] = ps[e];
    }
    __syncthreads();
    if (tid == 0) {
        int o = 0;
        float bl = 0.f;
#pragma unroll
        for (int e = 0; e < En; e++) {
            offsets[e] = o; o += counts[e];
            float pm = (red[0][e] + red[1][e] + red[2][e] + red[3][e]) * (1.0f / Tt);
            float fr = (float)counts[e] * (1.0f / (Tt * 2));
            bl += fr * pm;
        }
        loss_out[0] = 0.01f * (float)En * bl;
    }
}

extern "C" void kernel_launch(void* const* d_in, const int* in_sizes, int n_in,
                              void* d_out, int out_size, void* d_ws, size_t ws_size,
                              hipStream_t stream)
{
    (void)in_sizes; (void)n_in; (void)out_size; (void)ws_size;
    const float* hs  = (const float*)d_in[0];
    const float* ln1 = (const float*)d_in[1];
    const float* wq  = (const float*)d_in[2];
    const float* wk  = (const float*)d_in[3];
    const float* wv  = (const float*)d_in[4];
    const float* wo  = (const float*)d_in[5];
    const float* ln2 = (const float*)d_in[6];
    const float* rw  = (const float*)d_in[7];
    const float* wg  = (const float*)d_in[8];
    const float* wu  = (const float*)d_in[9];
    const float* wd  = (const float*)d_in[10];
    float* out = (float*)d_out;

    char* ws = (char*)d_ws;
    size_t off = 0;
    auto nxt = [&](size_t bytes) { char* p = ws + off; off += (bytes + 255) & ~(size_t)255; return p; };
    // ---- persistent (MoE-era) region ----
    u16* wgt  = (u16*)nxt((size_t)En * Fn * Dd * 2);
    u16* wut  = (u16*)nxt((size_t)En * Fn * Dd * 2);
    u16* wdt  = (u16*)nxt((size_t)En * Dd * Fn * 2);
    float* h2 = (float*)nxt((size_t)Tt * Dd * 4);
    u16* h2b  = (u16*)nxt((size_t)Tt * Dd * 2);
    float* probs = (float*)nxt((size_t)Tt * En * 4);
    int*   tokl  = (int*)nxt((size_t)En * Tt * 4);
    float* gwl   = (float*)nxt((size_t)En * Tt * 4);
    float* ctab  = (float*)nxt((size_t)Ss * 32 * 4);
    float* stab  = (float*)nxt((size_t)Ss * 32 * 4);
    int* counts  = (int*)nxt(256);
    int* offs    = (int*)nxt(256);
    // ---- transient (pre-MoE) region; `act` aliases it ----
    u16* act = (u16*)(ws + off);
    float* qkv = (float*)nxt((size_t)Tt * 1536 * 4);
    u16* h1hi = (u16*)nxt((size_t)Tt * Dd * 2);
    u16* h1lo = (u16*)nxt((size_t)Tt * Dd * 2);
    u16* khi  = (u16*)nxt((size_t)Tt * KVHn * HDn * 2);
    u16* klo  = (u16*)nxt((size_t)Tt * KVHn * HDn * 2);
    u16* vthi = (u16*)nxt((size_t)Tt * KVHn * HDn * 2);
    u16* vtlo = (u16*)nxt((size_t)Tt * KVHn * HDn * 2);
    u16* chi  = (u16*)nxt((size_t)Tt * Dd * 2);
    u16* clo  = (u16*)nxt((size_t)Tt * Dd * 2);
    u16* wqkvthi = (u16*)nxt((size_t)1536 * Dd * 2);
    u16* wqkvtlo = (u16*)nxt((size_t)1536 * Dd * 2);
    u16* wothi = (u16*)nxt((size_t)Dd * Dd * 2);
    u16* wotlo = (u16*)nxt((size_t)Dd * Dd * 2);

    rope_tab_k<<<dim3(256), 256, 0, stream>>>(ctab, stab);
    // weight prep
    tconv_k<true ><<<dim3(16 * 16), 256, 0, stream>>>(wq, wqkvthi, wqkvtlo, 1024, 1024,    0, 16);
    tconv_k<true ><<<dim3(16 *  4), 256, 0, stream>>>(wk, wqkvthi, wqkvtlo, 1024,  256, 1024,  4);
    tconv_k<true ><<<dim3(16 *  4), 256, 0, stream>>>(wv, wqkvthi, wqkvtlo, 1024,  256, 1280,  4);
    tconv_k<true ><<<dim3(16 * 16), 256, 0, stream>>>(wo, wothi, wotlo, 1024, 1024, 0, 16);
    tprep_k<32, false><<<dim3(32 * 32, En), 256, 0, stream>>>(wg, wgt, 1024, 4096, 32);
    tprep_k<32, false><<<dim3(32 * 32, En), 256, 0, stream>>>(wu, wut, 1024, 4096, 32);
    tprep_k<32, false><<<dim3(8 * 128, En), 256, 0, stream>>>(wd, wdt, 4096, 1024, 8);

    rmsnorm_split_k<<<dim3(Tt), 256, 0, stream>>>(hs, ln1, h1hi, h1lo);
    gemm_split_k<false><<<dim3(12 * 32), 256, 0, stream>>>(h1hi, h1lo, wqkvthi, wqkvtlo,
                                                           qkv, nullptr, Tt, 1536, Dd, 12);
    rope_q_k<<<dim3(Tt * Hh * 32 / 256), 256, 0, stream>>>(qkv, ctab, stab);
    kprep_k<<<dim3(Tt * KVHn * 32 / 256), 256, 0, stream>>>(qkv, ctab, stab, khi, klo);
    vprep_k<<<dim3(Ss / 64, Bb * KVHn), 256, 0, stream>>>(qkv, vthi, vtlo);
    attn_k<<<dim3(Ss / 128, Hh, Bb), 512, 0, stream>>>(qkv, khi, klo, vthi, vtlo, chi, clo);
    gemm_split_k<true><<<dim3(8 * 32), 256, 0, stream>>>(chi, clo, wothi, wotlo,
                                                         out, hs, Tt, Dd, Dd, 8);
    rmsnorm2_k<<<dim3(Tt), 256, 0, stream>>>(out, ln2, h2, h2b);
    (void)hipMemsetAsync(counts, 0, 64, stream);
    router_k<<<dim3(Tt), 256, 0, stream>>>(h2, rw, probs, counts, tokl, gwl);
    finalize_k<<<dim3(1), 256, 0, stream>>>(probs, counts, offs, out + (size_t)Tt * Dd);
    // MoE: gate -> act ; up (in-place silu(g)*u*gw) ; down scatter-add (all expert-per-XCD)
    gemm_expert_k<0><<<dim3(8 * 32 * 32), 256, 0, stream>>>(h2b, wgt, act, tokl, gwl, counts, offs);
    gemm_expert_k<1><<<dim3(8 * 32 * 32), 256, 0, stream>>>(h2b, wut, act, tokl, gwl, counts, offs);
    gemm_down_k<<<dim3(8 * 8 * 32), 256, 0, stream>>>(act, wdt, out, tokl, counts, offs);
}